// Round 3
// baseline (448.379 us; speedup 1.0000x reference)
//
#include <hip/hip_runtime.h>
#include <hip/hip_bf16.h>
#include <math.h>

#define B_ 2
#define T_ 2048
#define D_ 1024
#define H_ 16
#define DH_ 64
#define M_ (B_*T_)   // 4096 rows
#define NC_ 32       // chunks per sequence (T/64)
#define CS_ 64       // chunk size
#define NCH_ (B_*H_*NC_)  // 1024 chunk-heads
#define QKVN_ 3072   // fused QKV gemm N

typedef __attribute__((ext_vector_type(4))) float floatx4;
typedef __attribute__((ext_vector_type(8))) short short8;

__device__ __forceinline__ ushort f2bf(float f) {
  union { float f; unsigned u; } c; c.f = f;
  unsigned r = (c.u + 0x7FFFu + ((c.u >> 16) & 1u)) >> 16;  // RNE
  return (ushort)r;
}
__device__ __forceinline__ float siluf(float u) {
  return u / (1.f + __expf(-u));
}
__device__ __forceinline__ float f4get(const float4& v, int j) {
  return j == 0 ? v.x : j == 1 ? v.y : j == 2 ? v.z : v.w;
}
__device__ __forceinline__ float rdlane(float v, int l) {
  return __int_as_float(__builtin_amdgcn_readlane(__float_as_int(v), l));
}
// swizzled chunk index for K tiles: chunk c (0..15) of row r stored at c ^ (r>>4)
__device__ __forceinline__ int ksw(int r, int c) { return ((c ^ (r >> 4)) << 2); }

// ---------- cast f32 -> bf16, n4 = n/4 ----------
__global__ void cast_kernel(const float* __restrict__ in, ushort* __restrict__ out, int n4) {
  int i = blockIdx.x * blockDim.x + threadIdx.x;
  if (i >= n4) return;
  float4 v = ((const float4*)in)[i];
  ushort4 o;
  o.x = f2bf(v.x); o.y = f2bf(v.y); o.z = f2bf(v.z); o.w = f2bf(v.w);
  ((ushort4*)out)[i] = o;
}

// ---------- transpose + cast: W[K][N] f32 -> Wt[N][K] bf16 ----------
__global__ void transpose_cast_kernel(const float* __restrict__ W, ushort* __restrict__ Wt,
                                      int K, int N) {
  __shared__ float tile[32][33];
  int tx = threadIdx.x, ty = threadIdx.y;
  int n0 = blockIdx.x * 32, k0 = blockIdx.y * 32;
  #pragma unroll
  for (int i = 0; i < 32; i += 8)
    tile[ty + i][tx] = W[(size_t)(k0 + ty + i) * N + n0 + tx];
  __syncthreads();
  #pragma unroll
  for (int i = 0; i < 32; i += 8)
    Wt[(size_t)(n0 + ty + i) * K + k0 + tx] = f2bf(tile[tx][ty + i]);
}

// ---------- transpose Wb[1024][16] -> WbT[16][1024] (fp32) ----------
__global__ void transpose_wb_kernel(const float* __restrict__ Wb, float* __restrict__ WbT) {
  int bk = blockIdx.x;
  int tid = threadIdx.x;
  int kl = tid >> 4, h = tid & 15;
  int k = bk * 16 + kl;
  WbT[(size_t)h * D_ + k] = Wb[(size_t)k * H_ + h];
}

// ---------- m97-style bf16 MFMA GEMM: C[M][N] = A[M][K]*B[K][N], Bt = B^T [N][K] ----------
__global__ __launch_bounds__(256) void gemm128_kernel(
    const ushort* __restrict__ A, const ushort* __restrict__ Bt,
    float* __restrict__ C, int M, int N, int K) {
  __shared__ ushort lA[128 * 32];
  __shared__ ushort lB[128 * 32];
  int tid = threadIdx.x;
  int wave = tid >> 6, lane = tid & 63;
  int wm = wave >> 1, wn = wave & 1;
  int m16 = lane & 15, q4 = lane >> 4;
  int bm = blockIdx.x, bn = blockIdx.y;
  floatx4 acc[4][4] = {};
  int srow = tid >> 2;
  int sk8 = tid & 3;
  const ushort* Ag = A + (size_t)(bm * 128 + srow) * K + sk8 * 8;
  const ushort* Bg = Bt + (size_t)(bn * 128 + srow) * K + sk8 * 8;
  ushort* lAp = lA + tid * 8;
  ushort* lBp = lB + tid * 8;
  for (int k0 = 0; k0 < K; k0 += 32) {
    __builtin_amdgcn_global_load_lds(
        (const __attribute__((address_space(1))) void*)(Ag + k0),
        (__attribute__((address_space(3))) void*)lAp, 16, 0, 0);
    __builtin_amdgcn_global_load_lds(
        (const __attribute__((address_space(1))) void*)(Ag + (size_t)64 * K + k0),
        (__attribute__((address_space(3))) void*)(lAp + 2048), 16, 0, 0);
    __builtin_amdgcn_global_load_lds(
        (const __attribute__((address_space(1))) void*)(Bg + k0),
        (__attribute__((address_space(3))) void*)lBp, 16, 0, 0);
    __builtin_amdgcn_global_load_lds(
        (const __attribute__((address_space(1))) void*)(Bg + (size_t)64 * K + k0),
        (__attribute__((address_space(3))) void*)(lBp + 2048), 16, 0, 0);
    __syncthreads();
    short8 af[4], bf[4];
    #pragma unroll
    for (int i = 0; i < 4; i++) {
      af[i] = *(short8*)&lA[(wm * 64 + i * 16 + m16) * 32 + q4 * 8];
      bf[i] = *(short8*)&lB[(wn * 64 + i * 16 + m16) * 32 + q4 * 8];
    }
    #pragma unroll
    for (int mi = 0; mi < 4; mi++)
      #pragma unroll
      for (int nj = 0; nj < 4; nj++)
        acc[mi][nj] = __builtin_amdgcn_mfma_f32_16x16x32_bf16(af[mi], bf[nj], acc[mi][nj], 0, 0, 0);
    __syncthreads();
  }
  float* Cb = C + (size_t)(bm * 128) * N + bn * 128;
  #pragma unroll
  for (int mi = 0; mi < 4; mi++) {
    #pragma unroll
    for (int nj = 0; nj < 4; nj++) {
      #pragma unroll
      for (int i = 0; i < 4; i++) {
        int row = wm * 64 + mi * 16 + q4 * 4 + i;
        int col = wn * 64 + nj * 16 + m16;
        Cb[(size_t)row * N + col] = acc[mi][nj][i];
      }
    }
  }
}

// ---------- beta = sigmoid(x @ Wb), WbT[16][1024], conflict-free ----------
__global__ __launch_bounds__(256) void beta_kernel(const float* __restrict__ x,
                                                   const float* __restrict__ WbT,
                                                   float* __restrict__ beta) {
  __shared__ __align__(16) float xs[D_];
  int row = blockIdx.x;
  int tid = threadIdx.x;
  ((float4*)xs)[tid] = ((const float4*)(x + (size_t)row * D_))[tid];
  __syncthreads();
  int h = tid >> 4;
  int seg = tid & 15;
  const float4* wrow = (const float4*)(WbT + (size_t)h * D_) + seg * 16;
  const float4* xsrow = (const float4*)xs + seg * 16;
  float s = 0.f;
  #pragma unroll
  for (int j = 0; j < 16; j++) {
    int jj = (j + seg) & 15;
    float4 xv = xsrow[jj];
    float4 wv = wrow[jj];
    s += xv.x * wv.x + xv.y * wv.y + xv.z * wv.z + xv.w * wv.w;
  }
  #pragma unroll
  for (int off = 8; off; off >>= 1) s += __shfl_down(s, off, 16);
  if (seg == 0) beta[(size_t)row * H_ + h] = 1.f / (1.f + __expf(-s));
}

// ---------- causal depthwise conv(K=4) + silu, l2norm for q,k ----------
__global__ __launch_bounds__(256) void conv_kernel(
    const float* __restrict__ qkv,
    const float* __restrict__ cq, const float* __restrict__ ck, const float* __restrict__ cv,
    float* __restrict__ qo, float* __restrict__ ko, float* __restrict__ vo) {
  int row = blockIdx.x;
  int t = row & (T_ - 1);
  int tid = threadIdx.x;
  int c0 = tid * 4;
  float4 zf = {0.f, 0.f, 0.f, 0.f};
  float4 xq[4], xk[4], xv[4];
  #pragma unroll
  for (int i = 0; i < 4; i++) {
    int tt = t - 3 + i;
    if (tt >= 0) {
      const float* rp = qkv + (size_t)(row - 3 + i) * QKVN_;
      xq[i] = *(const float4*)(rp + c0);
      xk[i] = *(const float4*)(rp + 1024 + c0);
      xv[i] = *(const float4*)(rp + 2048 + c0);
    } else { xq[i] = zf; xk[i] = zf; xv[i] = zf; }
  }
  float yq[4], yk[4], yv[4];
  float pq = 0.f, pk = 0.f;
  #pragma unroll
  for (int j = 0; j < 4; j++) {
    float4 wq = ((const float4*)cq)[c0 + j];
    float4 wk = ((const float4*)ck)[c0 + j];
    float4 wv = ((const float4*)cv)[c0 + j];
    float sq = 0.f, sk = 0.f, sv = 0.f;
    #pragma unroll
    for (int i = 0; i < 4; i++) {
      sq += f4get(wq, i) * f4get(xq[i], j);
      sk += f4get(wk, i) * f4get(xk[i], j);
      sv += f4get(wv, i) * f4get(xv[i], j);
    }
    yq[j] = siluf(sq); yk[j] = siluf(sk); yv[j] = siluf(sv);
    pq += yq[j] * yq[j]; pk += yk[j] * yk[j];
  }
  #pragma unroll
  for (int off = 1; off < 16; off <<= 1) {
    pq += __shfl_xor(pq, off, 16);
    pk += __shfl_xor(pk, off, 16);
  }
  float rq = rsqrtf(pq + 1e-6f), rk = rsqrtf(pk + 1e-6f);
  float4 oq = {yq[0]*rq, yq[1]*rq, yq[2]*rq, yq[3]*rq};
  float4 okk = {yk[0]*rk, yk[1]*rk, yk[2]*rk, yk[3]*rk};
  float4 ov = {yv[0], yv[1], yv[2], yv[3]};
  *(float4*)(qo + (size_t)row * D_ + c0) = oq;
  *(float4*)(ko + (size_t)row * D_ + c0) = okk;
  *(float4*)(vo + (size_t)row * D_ + c0) = ov;
}

// ================= chunked delta rule =================
// prep1: A = strict_tril(diag(b)KK^T); solve (I+A)Wk = diag(b)K and (I+A)U0 = diag(b)V
// Blocked forward substitution:
//   Phase A: each wave w inverts its 16x16 diag block T_ww = (I+A_ww)^-1  (parallel)
//   Phase B: wave w precomputes M_wk = A_wk * T_kk for k<w  (off critical path)
//   k-loop (4 steps): wave k publishes residual Y_k once; wave k applies T_kk*Y_k
//   (final output -> global), waves i>k apply Y_i -= M_ik*Y_k, all concurrently.
__global__ __launch_bounds__(256) void prep1_kernel(
    const float* __restrict__ kn, const float* __restrict__ vn,
    const float* __restrict__ beta,
    float* __restrict__ Wkbuf, float* __restrict__ U0buf) {
  __shared__ __align__(16) float Ash[64 * 68];   // A[t][s] row-major, stride 68
  __shared__ float bsh[64];
  // union region: Ksh (during A compute) aliased with Tsh/Msh/Xsh (after)
  __shared__ __align__(16) float uni[5312];
  float (*Ksh)[68] = (float (*)[68])uni;                    // 64x68 = 4352 floats
  float (*Tsh)[16][20] = (float (*)[16][20])uni;            // [4][16][20] = 1280
  float (*Msh)[16][20] = (float (*)[16][20])(uni + 1280);   // [6][16][20] = 1920
  float (*Xsh)[132] = (float (*)[132])(uni + 3200);         // [16][132]  = 2112

  int ch = blockIdx.x;
  int b = ch >> 9, h = (ch >> 5) & 15, c = ch & 31;
  int tid = threadIdx.x;
  int t = tid >> 2, seg = tid & 3;
  int wave = tid >> 6, lane = tid & 63;
  int r = lane >> 2, q = lane & 3;   // r == t&15, q == seg
  const float* krow = kn + ((size_t)(b * T_ + c * 64 + t)) * D_ + h * 64;
  #pragma unroll
  for (int g = 0; g < 4; g++)
    *(float4*)&Ksh[t][ksw(t, seg * 4 + g)] = *(const float4*)&krow[seg * 16 + 4 * g];
  if (tid < 64) bsh[tid] = beta[((size_t)(b * T_ + c * 64 + tid)) * H_ + h];
  __syncthreads();
  // A[t][s] = (t>s) ? b_t * (k_t . k_s) : 0
  {
    int s0 = seg * 16;
    float acc[16];
    #pragma unroll
    for (int rr = 0; rr < 16; rr++) acc[rr] = 0.f;
    for (int d4 = 0; d4 < 16; d4++) {
      float4 kt = *(float4*)&Ksh[t][ksw(t, d4)];
      #pragma unroll
      for (int rr = 0; rr < 16; rr++) {
        float4 ks = *(float4*)&Ksh[s0 + rr][((d4 ^ seg) << 2)];   // (s0+rr)>>4 == seg
        acc[rr] += kt.x * ks.x + kt.y * ks.y + kt.z * ks.z + kt.w * ks.w;
      }
    }
    float bt = bsh[t];
    #pragma unroll
    for (int g = 0; g < 4; g++) {
      float4 a4;
      a4.x = (t > s0 + 4*g + 0) ? bt * acc[4*g+0] : 0.f;
      a4.y = (t > s0 + 4*g + 1) ? bt * acc[4*g+1] : 0.f;
      a4.z = (t > s0 + 4*g + 2) ? bt * acc[4*g+2] : 0.f;
      a4.w = (t > s0 + 4*g + 3) ? bt * acc[4*g+3] : 0.f;
      *(float4*)&Ash[t * 68 + s0 + 4 * g] = a4;
    }
  }
  // RHS (residual Y) in registers: row t, 16 K-cols + 16 V-cols
  float xk[16], xv[16];
  {
    float bt = bsh[t];
    const float* vrow = vn + ((size_t)(b * T_ + c * 64 + t)) * D_ + h * 64;
    #pragma unroll
    for (int g = 0; g < 4; g++) {
      float4 kv = *(float4*)&Ksh[t][ksw(t, seg * 4 + g)];
      float4 vv = *(const float4*)&vrow[seg * 16 + 4 * g];
      xk[4*g+0] = bt * kv.x; xk[4*g+1] = bt * kv.y; xk[4*g+2] = bt * kv.z; xk[4*g+3] = bt * kv.w;
      xv[4*g+0] = bt * vv.x; xv[4*g+1] = bt * vv.y; xv[4*g+2] = bt * vv.z; xv[4*g+3] = bt * vv.w;
    }
  }
  __syncthreads();   // Ash ready; Ksh dead -> Tsh/Msh/Xsh region live
  // Phase A: wave-parallel 16x16 diagonal-block inverse via fwd substitution on I
  {
    float a[16];
    #pragma unroll
    for (int i = 0; i < 16; i++) a[i] = Ash[(wave * 16 + r) * 68 + wave * 16 + i];
    float4 w4 = {0.f, 0.f, 0.f, 0.f};
    if ((r >> 2) == q) ((float*)&w4)[r & 3] = 1.f;
    #pragma unroll
    for (int i = 0; i < 15; i++) {
      int src = i * 4 + q;
      float4 wi;
      wi.x = __shfl(w4.x, src, 64);
      wi.y = __shfl(w4.y, src, 64);
      wi.z = __shfl(w4.z, src, 64);
      wi.w = __shfl(w4.w, src, 64);
      if (r > i) {
        w4.x -= a[i] * wi.x; w4.y -= a[i] * wi.y;
        w4.z -= a[i] * wi.z; w4.w -= a[i] * wi.w;
      }
    }
    *(float4*)&Tsh[wave][r][q * 4] = w4;
  }
  __syncthreads();   // Tsh visible to all waves
  // Phase B: M_wk = A_wk * T_kk (wave-local write, wave-local read)
  for (int k = 0; k < wave; k++) {
    float4 m4 = {0.f, 0.f, 0.f, 0.f};
    #pragma unroll
    for (int i = 0; i < 16; i++) {
      float aik = Ash[(wave * 16 + r) * 68 + k * 16 + i];
      float4 tk = *(float4*)&Tsh[k][i][q * 4];
      m4.x += aik * tk.x; m4.y += aik * tk.y;
      m4.z += aik * tk.z; m4.w += aik * tk.w;
    }
    int mi = wave * (wave - 1) / 2 + k;
    *(float4*)&Msh[mi][r][q * 4] = m4;
  }
  // Block substitution k-loop
  float* wkout = &Wkbuf[(size_t)ch * 4096 + t * 64];
  float* u0out = &U0buf[(size_t)ch * 4096 + t * 64];
  for (int k = 0; k < 4; k++) {
    if (wave == k) {   // publish residual Y_k
      #pragma unroll
      for (int g = 0; g < 4; g++) {
        float4 k4 = {xk[4*g+0], xk[4*g+1], xk[4*g+2], xk[4*g+3]};
        float4 v4 = {xv[4*g+0], xv[4*g+1], xv[4*g+2], xv[4*g+3]};
        *(float4*)&Xsh[r][seg * 16 + 4 * g] = k4;
        *(float4*)&Xsh[r][64 + seg * 16 + 4 * g] = v4;
      }
    }
    __syncthreads();
    if (wave == k) {
      // X_k = T_kk * Y_k -> final output, straight to global
      float nk[16], nv[16];
      #pragma unroll
      for (int i2 = 0; i2 < 16; i2++) { nk[i2] = 0.f; nv[i2] = 0.f; }
      #pragma unroll
      for (int i = 0; i < 16; i++) {
        float tc = Tsh[k][r][i];
        #pragma unroll
        for (int g = 0; g < 4; g++) {
          float4 yk = *(float4*)&Xsh[i][seg * 16 + 4 * g];
          float4 yv = *(float4*)&Xsh[i][64 + seg * 16 + 4 * g];
          nk[4*g+0] += tc * yk.x; nk[4*g+1] += tc * yk.y;
          nk[4*g+2] += tc * yk.z; nk[4*g+3] += tc * yk.w;
          nv[4*g+0] += tc * yv.x; nv[4*g+1] += tc * yv.y;
          nv[4*g+2] += tc * yv.z; nv[4*g+3] += tc * yv.w;
        }
      }
      #pragma unroll
      for (int g = 0; g < 4; g++) {
        float4 k4 = {nk[4*g+0], nk[4*g+1], nk[4*g+2], nk[4*g+3]};
        float4 v4 = {nv[4*g+0], nv[4*g+1], nv[4*g+2], nv[4*g+3]};
        *(float4*)&wkout[seg * 16 + 4 * g] = k4;
        *(float4*)&u0out[seg * 16 + 4 * g] = v4;
      }
    } else if (wave > k) {
      // Y_i -= M_ik * Y_k   (== A_ik * X_k)
      int mi = wave * (wave - 1) / 2 + k;
      #pragma unroll
      for (int i = 0; i < 16; i++) {
        float mc = Msh[mi][r][i];
        #pragma unroll
        for (int g = 0; g < 4; g++) {
          float4 yk = *(float4*)&Xsh[i][seg * 16 + 4 * g];
          float4 yv = *(float4*)&Xsh[i][64 + seg * 16 + 4 * g];
          xk[4*g+0] -= mc * yk.x; xk[4*g+1] -= mc * yk.y;
          xk[4*g+2] -= mc * yk.z; xk[4*g+3] -= mc * yk.w;
          xv[4*g+0] -= mc * yv.x; xv[4*g+1] -= mc * yv.y;
          xv[4*g+2] -= mc * yv.z; xv[4*g+3] -= mc * yv.w;
        }
      }
    }
    __syncthreads();
  }
}

// prep2a: L = tril(Q K^T) (incl diagonal); Ksh chunk-swizzled like prep1
__global__ __launch_bounds__(256) void prep2a_kernel(
    const float* __restrict__ qn, const float* __restrict__ kn,
    float* __restrict__ Lbuf) {
  __shared__ float Qsh[64][68];
  __shared__ float Ksh[64][68];   // swizzled
  int ch = blockIdx.x;
  int b = ch >> 9, h = (ch >> 5) & 15, c = ch & 31;
  int tid = threadIdx.x;
  int t = tid >> 2, seg = tid & 3;
  const float* qrow = qn + ((size_t)(b * T_ + c * 64 + t)) * D_ + h * 64;
  const float* krow = kn + ((size_t)(b * T_ + c * 64 + t)) * D_ + h * 64;
  #pragma unroll
  for (int g = 0; g < 4; g++) {
    *(float4*)&Qsh[t][seg * 16 + 4 * g] = *(const float4*)&qrow[seg * 16 + 4 * g];
    *(float4*)&Ksh[t][ksw(t, seg * 4 + g)] = *(const float4*)&krow[seg * 16 + 4 * g];
  }
  __syncthreads();
  int s0 = seg * 16;
  float acc[16];
  #pragma unroll
  for (int r = 0; r < 16; r++) acc[r] = 0.f;
  for (int d4 = 0; d4 < 16; d4++) {
    float4 qt = *(float4*)&Qsh[t][d4 * 4];
    #pragma unroll
    for (int r = 0; r < 16; r++) {
      float4 ks = *(float4*)&Ksh[s0 + r][((d4 ^ seg) << 2)];
      acc[r] += qt.x * ks.x + qt.y * ks.y + qt.z * ks.z + qt.w * ks.w;
    }
  }
  #pragma unroll
  for (int g = 0; g < 4; g++) {
    float4 ov;
    ov.x = (s0 + 4*g + 0 <= t) ? acc[4*g+0] : 0.f;
    ov.y = (s0 + 4*g + 1 <= t) ? acc[4*g+1] : 0.f;
    ov.z = (s0 + 4*g + 2 <= t) ? acc[4*g+2] : 0.f;
    ov.w = (s0 + 4*g + 3 <= t) ? acc[4*g+3] : 0.f;
    *(float4*)&Lbuf[(size_t)ch * 4096 + t * 64 + s0 + 4 * g] = ov;
  }
}

// prep2b: O0 = L U0 ; Qeff = Q - L Wk (in-place over qn)
__global__ __launch_bounds__(256) void prep2b_kernel(
    const float* __restrict__ Lbuf, const float* __restrict__ Wkbuf,
    const float* __restrict__ U0buf, float* qn,
    float* __restrict__ O0buf) {
  __shared__ float Lsh[64][68];
  __shared__ float Wksh[64][68];
  __shared__ float U0sh[64][68];
  int ch = blockIdx.x;
  int b = ch >> 9, h = (ch >> 5) & 15, c = ch & 31;
  int tid = threadIdx.x;
  int t = tid >> 2, seg = tid & 3;
  #pragma unroll
  for (int g = 0; g < 4; g++) {
    int o = t * 64 + seg * 16 + 4 * g;
    *(float4*)&Lsh[t][seg * 16 + 4 * g]  = *(const float4*)&Lbuf[(size_t)ch * 4096 + o];
    *(float4*)&Wksh[t][seg * 16 + 4 * g] = *(const float4*)&Wkbuf[(size_t)ch * 4096 + o];
    *(float4*)&U0sh[t][seg * 16 + 4 * g] = *(const float4*)&U0buf[(size_t)ch * 4096 + o];
  }
  __syncthreads();
  int j0 = seg * 16;
  float o0[16], lw[16];
  #pragma unroll
  for (int r = 0; r < 16; r++) { o0[r] = 0.f; lw[r] = 0.f; }
  for (int s = 0; s <= t; s++) {
    float l = Lsh[t][s];
    #pragma unroll
    for (int g = 0; g < 4; g++) {
      float4 u = *(float4*)&U0sh[s][j0 + 4 * g];
      float4 w = *(float4*)&Wksh[s][j0 + 4 * g];
      o0[4*g+0] += l * u.x; o0[4*g+1] += l * u.y; o0[4*g+2] += l * u.z; o0[4*g+3] += l * u.w;
      lw[4*g+0] += l * w.x; lw[4*g+1] += l * w.y; lw[4*g+2] += l * w.z; lw[4*g+3] += l * w.w;
    }
  }
  float* qrow = qn + ((size_t)(b * T_ + c * 64 + t)) * D_ + h * 64;
  #pragma unroll
  for (int g = 0; g < 4; g++) {
    float4 qv = *(const float4*)&qrow[j0 + 4 * g];
    qv.x -= lw[4*g+0]; qv.y -= lw[4*g+1]; qv.z -= lw[4*g+2]; qv.w -= lw[4*g+3];
    *(float4*)&qrow[j0 + 4 * g] = qv;
    float4 ov = {o0[4*g+0], o0[4*g+1], o0[4*g+2], o0[4*g+3]};
    *(float4*)&O0buf[(size_t)ch * 4096 + t * 64 + j0 + 4 * g] = ov;
  }
}

// prep2c: P[d][e] = I - (K^T Wk)[d][e], stored SLOT-MAJOR for state_kernel:
//         float4 #(f*64+d) of chunk = P[d][4f..4f+3]  (so a wave reading slot f,
//         all rows d, is one contiguous 1KB block).
//         Zt[j][d] = (U0^T K)[j][d] -> kn rows j (coalesced), unchanged.
__global__ __launch_bounds__(256) void prep2c_kernel(
    float* kn, const float* __restrict__ Wkbuf,
    const float* __restrict__ U0buf, float* __restrict__ Pbuf) {
  __shared__ float Ksh[64][68];
  __shared__ float Wksh[64][68];
  __shared__ float U0sh[64][68];
  int ch = blockIdx.x;
  int b = ch >> 9, h = (ch >> 5) & 15, c = ch & 31;
  int tid = threadIdx.x;
  int t = tid >> 2, seg = tid & 3;   // t = output row (d for P, j for Zt)
  const float* krow = kn + ((size_t)(b * T_ + c * 64 + t)) * D_ + h * 64;
  #pragma unroll
  for (int g = 0; g < 4; g++) {
    int o = t * 64 + seg * 16 + 4 * g;
    *(float4*)&Ksh[t][seg * 16 + 4 * g]  = *(const float4*)&krow[seg * 16 + 4 * g];
    *(float4*)&Wksh[t][seg * 16 + 4 * g] = *(const float4*)&Wkbuf[(size_t)ch * 4096 + o];
    *(float4*)&U0sh[t][seg * 16 + 4 * g] = *(const float4*)&U0buf[(size_t)ch * 4096 + o];
  }
  __syncthreads();
  int d0 = seg * 16;
  float accP[16], accZ[16];
  #pragma unroll
  for (int r = 0; r < 16; r++) { accP[r] = 0.f; accZ[r] = 0.f; }
  for (int s = 0; s < 64; s++) {
    float kt = Ksh[s][t];    // scalar for P row d=t
    float u  = U0sh[s][t];   // scalar for Z row j=t
    #pragma unroll
    for (int g = 0; g < 4; g++) {
      float4 w4 = *(float4*)&Wksh[s][d0 + 4 * g];
      float4 k4 = *(float4*)&Ksh[s][d0 + 4 * g];
      accP[4*g+0] += kt * w4.x; accP[4*g+1] += kt * w4.y; accP[4*g+2] += kt * w4.z; accP[4*g+3] += kt * w4.w;
      accZ[4*g+0] += u * k4.x;  accZ[4*g+1] += u * k4.y;  accZ[4*g+2] += u * k4.z;  accZ[4*g+3] += u * k4.w;
    }
  }
  float* zrow = kn + ((size_t)(b * T_ + c * 64 + t)) * D_ + h * 64;
  #pragma unroll
  for (int g = 0; g < 4; g++) {
    float4 pv;
    pv.x = ((d0 + 4*g + 0) == t ? 1.f : 0.f) - accP[4*g+0];
    pv.y = ((d0 + 4*g + 1) == t ? 1.f : 0.f) - accP[4*g+1];
    pv.z = ((d0 + 4*g + 2) == t ? 1.f : 0.f) - accP[4*g+2];
    pv.w = ((d0 + 4*g + 3) == t ? 1.f : 0.f) - accP[4*g+3];
    // slot-major: slot f = seg*4+g, row d = t
    *(float4*)&Pbuf[(size_t)ch * 4096 + (size_t)(seg * 4 + g) * 256 + (size_t)t * 4] = pv;
    float4 zv = {accZ[4*g+0], accZ[4*g+1], accZ[4*g+2], accZ[4*g+3]};
    *(float4*)&zrow[d0 + 4 * g] = zv;
  }
}

// ---------- state scan: S_{c+1} = P_c S_c + Z_c; Sbuf transposed [ch][j][d] ----------
// One wave per block, 512 blocks = (bh, js); lane = d holds S[j0..j0+3][d] in regs.
// P_c lives in REGISTERS (pA/pB double buffer, 64+64 VGPR), prefetched one chunk
// ahead with inline-asm global_load_dwordx4 (unsinkable by regalloc); Z via asm
// loads. Single vmcnt(0)+sched_barrier per chunk; compute phase is pure
// readlane+FMA on registers -> no memory stall inside the chunk.
// bh = bid&31 so the 16 js-sharers of a (b,h) land on the same XCD (P from L2).
__global__ __launch_bounds__(64, 1) void state_kernel(
    const float* __restrict__ kn /*Zt*/, const float* __restrict__ Pbuf /*slot-major*/,
    float* __restrict__ Sbuf) {
  int bid = blockIdx.x;
  int bh = bid & 31, js = bid >> 5;
  int h = bh & 15, b = bh >> 4;
  int lane = threadIdx.x;   // d
  int j0 = js * 4;
  float s[4] = {0.f, 0.f, 0.f, 0.f};
  floatx4 pA[16], pB[16];
  float zA[4], zB[4];
  const size_t bhNC = (size_t)bh * NC_;
  const float* Plane = Pbuf + bhNC * 4096 + (size_t)lane * 4;
  const float* zbase = kn + (size_t)(b * T_) * D_ + h * 64 + lane;

  // prologue: issue P_0 -> pA, Z_0 -> zA (asm; waited at first step)
  #pragma unroll
  for (int g = 0; g < 16; g++)
    asm volatile("global_load_dwordx4 %0, %1, off"
                 : "=v"(pA[g]) : "v"(Plane + g * 256) : "memory");
  #pragma unroll
  for (int i = 0; i < 4; i++)
    asm volatile("global_load_dword %0, %1, off"
                 : "=v"(zA[i]) : "v"(zbase + (size_t)(j0 + i) * D_) : "memory");

#define SCAN_STEP(cc, pcur, pnxt, zcur, znxt)                                  \
  {                                                                            \
    asm volatile("s_waitcnt vmcnt(0)" ::: "memory");                           \
    __builtin_amdgcn_sched_barrier(0);                                         \
    if ((cc) + 1 < NC_) {                                                      \
      const float* Pg = Pbuf + (bhNC + (cc) + 1) * 4096 + (size_t)lane * 4;    \
      _Pragma("unroll")                                                        \
      for (int g = 0; g < 16; g++)                                             \
        asm volatile("global_load_dwordx4 %0, %1, off"                         \
                     : "=v"(pnxt[g]) : "v"(Pg + g * 256) : "memory");          \
      _Pragma("unroll")                                                        \
      for (int i = 0; i < 4; i++)                                              \
        asm volatile("global_load_dword %0, %1, off"                           \
                     : "=v"(znxt[i])                                           \
                     : "v"(zbase + (size_t)(((cc) + 1) * 64 + j0 + i) * D_)    \
                     : "memory");                                              \
    }                                                                          \
    float* Sout = Sbuf + (bhNC + (cc)) * 4096 + (size_t)j0 * 64 + lane;        \
    _Pragma("unroll")                                                          \
    for (int i = 0; i < 4; i++) Sout[(size_t)i * 64] = s[i];                   \
    float a0 = zcur[0], a1 = zcur[1], a2 = zcur[2], a3 = zcur[3];              \
    _Pragma("unroll")                                                          \
    for (int f = 0; f < 16; f++) {                                             \
      floatx4 pv = pcur[f];                                                    \
      _Pragma("unroll")                                                        \
      for (int e = 0; e < 4; e++) {                                            \
        float b0 = rdlane(s[0], f * 4 + e);                                    \
        float b1 = rdlane(s[1], f * 4 + e);                                    \
        float b2 = rdlane(s[2], f * 4 + e);                                    \
        float b3 = rdlane(s[3], f * 4 + e);                                    \
        a0 += pv[e] * b0; a1 += pv[e] * b1;                                    \
        a2 += pv[e] * b2; a3 += pv[e] * b3;                                    \
      }                                                                        \
    }                                                                          \
    s[0] = a0; s[1] = a1; s[2] = a2; s[3] = a3;                                \
  }

  #pragma unroll 1
  for (int c = 0; c < NC_; c += 2) {
    SCAN_STEP(c, pA, pB, zA, zB);
    SCAN_STEP(c + 1, pB, pA, zB, zA);
  }
#undef SCAN_STEP
}

// ---------- O = O0 + Qeff*S_c (S transposed layout), fused RMSNorm + bf16 cast ----------
__global__ __launch_bounds__(256) void ophase_kernel(
    const float* __restrict__ qn /*Qeff*/, const float* __restrict__ Sbuf,
    const float* __restrict__ O0buf, const float* __restrict__ rms_g,
    ushort* __restrict__ ob) {
  __shared__ float Ssht[64][68];
  __shared__ float QshT[64][65];
  __shared__ float part[64][4];
  int ch = blockIdx.x;
  int b = ch >> 9, h = (ch >> 5) & 15, c = ch & 31;
  int tid = threadIdx.x;
  int t = tid & 63, jg = tid >> 6;
  #pragma unroll
  for (int g = 0; g < 4; g++) {
    int idx = tid + g * 256;
    *(float4*)&Ssht[idx >> 4][(idx & 15) * 4] =
        *(const float4*)&Sbuf[(size_t)ch * 4096 + (size_t)idx * 4];
  }
  #pragma unroll
  for (int g = 0; g < 4; g++) {
    int idx = tid + g * 256;
    int row = idx >> 4, c4 = idx & 15;
    float4 qv = *(const float4*)&qn[((size_t)(b * T_ + c * 64 + row)) * D_ + h * 64 + c4 * 4];
    QshT[c4 * 4 + 0][row] = qv.x;
    QshT[c4 * 4 + 1][row] = qv.y;
    QshT[c4 * 4 + 2][row] = qv.z;
    QshT[c4 * 4 + 3][row] = qv.w;
  }
  float o[16];
  #pragma unroll
  for (int g = 0; g < 4; g++) {
    float4 o4 = *(const float4*)&O0buf[(size_t)ch * 4096 + t * 64 + jg * 16 + g * 4];
    o[4*g+0] = o4.x; o[4*g+1] = o4.y; o[4*g+2] = o4.z; o[4*g+3] = o4.w;
  }
  __syncthreads();
  for (int d4 = 0; d4 < 16; d4++) {
    float q0 = QshT[d4 * 4 + 0][t];
    float q1 = QshT[d4 * 4 + 1][t];
    float q2 = QshT[d4 * 4 + 2][t];
    float q3 = QshT[d4 * 4 + 3][t];
    #pragma unroll
    for (int r = 0; r < 16; r++) {
      float4 s4 = *(float4*)&Ssht[jg * 16 + r][d4 * 4];
      o[r] += q0 * s4.x + q1 * s4.y + q2 * s4.z + q3 * s4.w;
    }
  }
  float ss = 0.f;
  #pragma unroll
  for (int r = 0; r < 16; r++) ss += o[r] * o[r];
  part[t][jg] = ss;
  __syncthreads();
  float tot = part[t][0] + part[t][1] + part[t][2] + part[t][3];
  float sc = rsqrtf(tot * (1.f / 64.f) + 1e-6f);
  ushort* orow = &ob[((size_t)(b * T_ + c * 64 + t)) * D_ + h * 64];
  #pragma unroll
  for (int g = 0; g < 4; g++) {
    float4 g4 = *(const float4*)&rms_g[jg * 16 + g * 4];
    ushort4 r4;
    r4.x = f2bf(o[4*g+0] * sc * g4.x); r4.y = f2bf(o[4*g+1] * sc * g4.y);
    r4.z = f2bf(o[4*g+2] * sc * g4.z); r4.w = f2bf(o[4*g+3] * sc * g4.w);
    *(ushort4*)&orow[jg * 16 + g * 4] = r4;
  }
}

extern "C" void kernel_launch(void* const* d_in, const int* in_sizes, int n_in,
                              void* d_out, int out_size, void* d_ws, size_t ws_size,
                              hipStream_t stream) {
  const float* x  = (const float*)d_in[0];
  const float* Wq = (const float*)d_in[1];
  const float* Wk = (const float*)d_in[2];
  const float* Wv = (const float*)d_in[3];
  const float* Wb = (const float*)d_in[4];
  const float* cq = (const float*)d_in[5];
  const float* ck = (const float*)d_in[6];
  const float* cv = (const float*)d_in[7];
  const float* rg = (const float*)d_in[8];
  const float* Wo = (const float*)d_in[9];
  float* out = (float*)d_out;
  char* ws = (char*)d_ws;
  const size_t MiB = 1ull << 20;
  ushort* xb   = (ushort*)(ws + 0);         // dead after QKV gemm
  ushort* Wqt  = (ushort*)(ws + 8 * MiB);   // Wqt/Wkt/Wvt contiguous = [3072][1024] bf16
  ushort* Wkt  = (ushort*)(ws + 10 * MiB);
  ushort* Wvt  = (ushort*)(ws + 12 * MiB);
  ushort* Wot  = (ushort*)(ws + 14 * MiB);  // live to end
  float* qkv   = (float*)(ws + 16 * MiB);   // [4096][3072] fp32, dead after conv
  float* qn    = (float*)(ws + 64 * MiB);   // then Qeff in-place
  float* kn    = (float*)(ws + 80 * MiB);   // then Zt in-place
  float* vn    = (float*)(ws + 96 * MiB);   // dead after prep1
  float* beta  = (float*)(ws + 112 * MiB);  // 256 KiB
  float* WbT   = (float*)(ws + 112 * MiB + 256 * 1024);  // 64 KiB
  float* Wkbuf = (float*)(ws + 16 * MiB);   // over qkv (dead after conv)
  float* U0buf = (float*)(ws + 32 * MiB);
  float* Lbuf  = (float*)(ws + 48 * MiB);   // later P
  float* O0buf = (float*)(ws + 96 * MiB);   // over vn (after prep1)
  float* Sbuf  = (float*)(ws + 16 * MiB);   // over Wkbuf (dead after prep2c)
  ushort* ob   = (ushort*)(ws + 0);         // over xb (after QKV gemm)

  hipLaunchKernelGGL(cast_kernel, dim3(M_ * D_ / 4 / 256), dim3(256), 0, stream,
                     x, xb, M_ * D_ / 4);
  dim3 tb(32, 8);
  hipLaunchKernelGGL(transpose_cast_kernel, dim3(32, 32), tb, 0, stream, Wq, Wqt, D_, D_);
  hipLaunchKernelGGL(transpose_cast_kernel, dim3(32, 32), tb, 0, stream, Wk, Wkt, D_, D_);
  hipLaunchKernelGGL(transpose_cast_kernel, dim3(32, 32), tb, 0, stream, Wv, Wvt, D_, D_);
  hipLaunchKernelGGL(transpose_cast_kernel, dim3(32, 32), tb, 0, stream, Wo, Wot, D_, D_);
  hipLaunchKernelGGL(transpose_wb_kernel, dim3(64), dim3(256), 0, stream, Wb, WbT);

  hipLaunchKernelGGL(gemm128_kernel, dim3(M_ / 128, QKVN_ / 128), dim3(256), 0, stream,
                     xb, Wqt, qkv, M_, QKVN_, D_);

  hipLaunchKernelGGL(beta_kernel, dim3(M_), dim3(256), 0, stream, x, WbT, beta);
  hipLaunchKernelGGL(conv_kernel, dim3(M_), dim3(256), 0, stream,
                     qkv, cq, ck, cv, qn, kn, vn);

  hipLaunchKernelGGL(prep1_kernel, dim3(NCH_), dim3(256), 0, stream,
                     kn, vn, beta, Wkbuf, U0buf);
  hipLaunchKernelGGL(prep2a_kernel, dim3(NCH_), dim3(256), 0, stream, qn, kn, Lbuf);
  hipLaunchKernelGGL(prep2b_kernel, dim3(NCH_), dim3(256), 0, stream,
                     Lbuf, Wkbuf, U0buf, qn, O0buf);
  hipLaunchKernelGGL(prep2c_kernel, dim3(NCH_), dim3(256), 0, stream,
                     kn, Wkbuf, U0buf, Lbuf);
  hipLaunchKernelGGL(state_kernel, dim3(512), dim3(64), 0, stream,
                     kn, Lbuf, Sbuf);
  hipLaunchKernelGGL(ophase_kernel, dim3(NCH_), dim3(256), 0, stream,
                     qn, Sbuf, O0buf, rg, ob);
  hipLaunchKernelGGL(gemm128_kernel, dim3(M_ / 128, D_ / 128), dim3(256), 0, stream,
                     ob, Wot, out, M_, D_, D_);
}

// Round 4
// 406.465 us; speedup vs baseline: 1.1031x; 1.1031x over previous
//
#include <hip/hip_runtime.h>
#include <hip/hip_bf16.h>
#include <math.h>

#define B_ 2
#define T_ 2048
#define D_ 1024
#define H_ 16
#define DH_ 64
#define M_ (B_*T_)   // 4096 rows
#define NC_ 32       // chunks per sequence (T/64)
#define CS_ 64       // chunk size
#define NCH_ (B_*H_*NC_)  // 1024 chunk-heads
#define QKVN_ 3072   // fused QKV gemm N

typedef __attribute__((ext_vector_type(4))) float floatx4;
typedef __attribute__((ext_vector_type(8))) short short8;

__device__ __forceinline__ ushort f2bf(float f) {
  union { float f; unsigned u; } c; c.f = f;
  unsigned r = (c.u + 0x7FFFu + ((c.u >> 16) & 1u)) >> 16;  // RNE
  return (ushort)r;
}
__device__ __forceinline__ float siluf(float u) {
  return u / (1.f + __expf(-u));
}
__device__ __forceinline__ float f4get(const float4& v, int j) {
  return j == 0 ? v.x : j == 1 ? v.y : j == 2 ? v.z : v.w;
}
__device__ __forceinline__ float rdlane(float v, int l) {
  return __int_as_float(__builtin_amdgcn_readlane(__float_as_int(v), l));
}
// swizzled chunk index for K tiles: chunk c (0..15) of row r stored at c ^ (r>>4)
__device__ __forceinline__ int ksw(int r, int c) { return ((c ^ (r >> 4)) << 2); }

// ---------- cast f32 -> bf16, n4 = n/4 ----------
__global__ void cast_kernel(const float* __restrict__ in, ushort* __restrict__ out, int n4) {
  int i = blockIdx.x * blockDim.x + threadIdx.x;
  if (i >= n4) return;
  float4 v = ((const float4*)in)[i];
  ushort4 o;
  o.x = f2bf(v.x); o.y = f2bf(v.y); o.z = f2bf(v.z); o.w = f2bf(v.w);
  ((ushort4*)out)[i] = o;
}

// ---------- transpose + cast: W[K][N] f32 -> Wt[N][K] bf16 ----------
__global__ void transpose_cast_kernel(const float* __restrict__ W, ushort* __restrict__ Wt,
                                      int K, int N) {
  __shared__ float tile[32][33];
  int tx = threadIdx.x, ty = threadIdx.y;
  int n0 = blockIdx.x * 32, k0 = blockIdx.y * 32;
  #pragma unroll
  for (int i = 0; i < 32; i += 8)
    tile[ty + i][tx] = W[(size_t)(k0 + ty + i) * N + n0 + tx];
  __syncthreads();
  #pragma unroll
  for (int i = 0; i < 32; i += 8)
    Wt[(size_t)(n0 + ty + i) * K + k0 + tx] = f2bf(tile[tx][ty + i]);
}

// ---------- transpose Wb[1024][16] -> WbT[16][1024] (fp32) ----------
__global__ void transpose_wb_kernel(const float* __restrict__ Wb, float* __restrict__ WbT) {
  int bk = blockIdx.x;
  int tid = threadIdx.x;
  int kl = tid >> 4, h = tid & 15;
  int k = bk * 16 + kl;
  WbT[(size_t)h * D_ + k] = Wb[(size_t)k * H_ + h];
}

// ---------- m97-style bf16 MFMA GEMM: C[M][N] = A[M][K]*B[K][N], Bt = B^T [N][K] ----------
__global__ __launch_bounds__(256) void gemm128_kernel(
    const ushort* __restrict__ A, const ushort* __restrict__ Bt,
    float* __restrict__ C, int M, int N, int K) {
  __shared__ ushort lA[128 * 32];
  __shared__ ushort lB[128 * 32];
  int tid = threadIdx.x;
  int wave = tid >> 6, lane = tid & 63;
  int wm = wave >> 1, wn = wave & 1;
  int m16 = lane & 15, q4 = lane >> 4;
  int bm = blockIdx.x, bn = blockIdx.y;
  floatx4 acc[4][4] = {};
  int srow = tid >> 2;
  int sk8 = tid & 3;
  const ushort* Ag = A + (size_t)(bm * 128 + srow) * K + sk8 * 8;
  const ushort* Bg = Bt + (size_t)(bn * 128 + srow) * K + sk8 * 8;
  ushort* lAp = lA + tid * 8;
  ushort* lBp = lB + tid * 8;
  for (int k0 = 0; k0 < K; k0 += 32) {
    __builtin_amdgcn_global_load_lds(
        (const __attribute__((address_space(1))) void*)(Ag + k0),
        (__attribute__((address_space(3))) void*)lAp, 16, 0, 0);
    __builtin_amdgcn_global_load_lds(
        (const __attribute__((address_space(1))) void*)(Ag + (size_t)64 * K + k0),
        (__attribute__((address_space(3))) void*)(lAp + 2048), 16, 0, 0);
    __builtin_amdgcn_global_load_lds(
        (const __attribute__((address_space(1))) void*)(Bg + k0),
        (__attribute__((address_space(3))) void*)lBp, 16, 0, 0);
    __builtin_amdgcn_global_load_lds(
        (const __attribute__((address_space(1))) void*)(Bg + (size_t)64 * K + k0),
        (__attribute__((address_space(3))) void*)(lBp + 2048), 16, 0, 0);
    __syncthreads();
    short8 af[4], bf[4];
    #pragma unroll
    for (int i = 0; i < 4; i++) {
      af[i] = *(short8*)&lA[(wm * 64 + i * 16 + m16) * 32 + q4 * 8];
      bf[i] = *(short8*)&lB[(wn * 64 + i * 16 + m16) * 32 + q4 * 8];
    }
    #pragma unroll
    for (int mi = 0; mi < 4; mi++)
      #pragma unroll
      for (int nj = 0; nj < 4; nj++)
        acc[mi][nj] = __builtin_amdgcn_mfma_f32_16x16x32_bf16(af[mi], bf[nj], acc[mi][nj], 0, 0, 0);
    __syncthreads();
  }
  float* Cb = C + (size_t)(bm * 128) * N + bn * 128;
  #pragma unroll
  for (int mi = 0; mi < 4; mi++) {
    #pragma unroll
    for (int nj = 0; nj < 4; nj++) {
      #pragma unroll
      for (int i = 0; i < 4; i++) {
        int row = wm * 64 + mi * 16 + q4 * 4 + i;
        int col = wn * 64 + nj * 16 + m16;
        Cb[(size_t)row * N + col] = acc[mi][nj][i];
      }
    }
  }
}

// ---------- beta = sigmoid(x @ Wb), WbT[16][1024], conflict-free ----------
__global__ __launch_bounds__(256) void beta_kernel(const float* __restrict__ x,
                                                   const float* __restrict__ WbT,
                                                   float* __restrict__ beta) {
  __shared__ __align__(16) float xs[D_];
  int row = blockIdx.x;
  int tid = threadIdx.x;
  ((float4*)xs)[tid] = ((const float4*)(x + (size_t)row * D_))[tid];
  __syncthreads();
  int h = tid >> 4;
  int seg = tid & 15;
  const float4* wrow = (const float4*)(WbT + (size_t)h * D_) + seg * 16;
  const float4* xsrow = (const float4*)xs + seg * 16;
  float s = 0.f;
  #pragma unroll
  for (int j = 0; j < 16; j++) {
    int jj = (j + seg) & 15;
    float4 xv = xsrow[jj];
    float4 wv = wrow[jj];
    s += xv.x * wv.x + xv.y * wv.y + xv.z * wv.z + xv.w * wv.w;
  }
  #pragma unroll
  for (int off = 8; off; off >>= 1) s += __shfl_down(s, off, 16);
  if (seg == 0) beta[(size_t)row * H_ + h] = 1.f / (1.f + __expf(-s));
}

// ---------- causal depthwise conv(K=4) + silu, l2norm for q,k ----------
__global__ __launch_bounds__(256) void conv_kernel(
    const float* __restrict__ qkv,
    const float* __restrict__ cq, const float* __restrict__ ck, const float* __restrict__ cv,
    float* __restrict__ qo, float* __restrict__ ko, float* __restrict__ vo) {
  int row = blockIdx.x;
  int t = row & (T_ - 1);
  int tid = threadIdx.x;
  int c0 = tid * 4;
  float4 zf = {0.f, 0.f, 0.f, 0.f};
  float4 xq[4], xk[4], xv[4];
  #pragma unroll
  for (int i = 0; i < 4; i++) {
    int tt = t - 3 + i;
    if (tt >= 0) {
      const float* rp = qkv + (size_t)(row - 3 + i) * QKVN_;
      xq[i] = *(const float4*)(rp + c0);
      xk[i] = *(const float4*)(rp + 1024 + c0);
      xv[i] = *(const float4*)(rp + 2048 + c0);
    } else { xq[i] = zf; xk[i] = zf; xv[i] = zf; }
  }
  float yq[4], yk[4], yv[4];
  float pq = 0.f, pk = 0.f;
  #pragma unroll
  for (int j = 0; j < 4; j++) {
    float4 wq = ((const float4*)cq)[c0 + j];
    float4 wk = ((const float4*)ck)[c0 + j];
    float4 wv = ((const float4*)cv)[c0 + j];
    float sq = 0.f, sk = 0.f, sv = 0.f;
    #pragma unroll
    for (int i = 0; i < 4; i++) {
      sq += f4get(wq, i) * f4get(xq[i], j);
      sk += f4get(wk, i) * f4get(xk[i], j);
      sv += f4get(wv, i) * f4get(xv[i], j);
    }
    yq[j] = siluf(sq); yk[j] = siluf(sk); yv[j] = siluf(sv);
    pq += yq[j] * yq[j]; pk += yk[j] * yk[j];
  }
  #pragma unroll
  for (int off = 1; off < 16; off <<= 1) {
    pq += __shfl_xor(pq, off, 16);
    pk += __shfl_xor(pk, off, 16);
  }
  float rq = rsqrtf(pq + 1e-6f), rk = rsqrtf(pk + 1e-6f);
  float4 oq = {yq[0]*rq, yq[1]*rq, yq[2]*rq, yq[3]*rq};
  float4 okk = {yk[0]*rk, yk[1]*rk, yk[2]*rk, yk[3]*rk};
  float4 ov = {yv[0], yv[1], yv[2], yv[3]};
  *(float4*)(qo + (size_t)row * D_ + c0) = oq;
  *(float4*)(ko + (size_t)row * D_ + c0) = okk;
  *(float4*)(vo + (size_t)row * D_ + c0) = ov;
}

// ================= chunked delta rule =================
// prep1: A = strict_tril(diag(b)KK^T); solve (I+A)Wk = diag(b)K and (I+A)U0 = diag(b)V
// Blocked forward substitution:
//   Phase A: each wave w inverts its 16x16 diag block T_ww = (I+A_ww)^-1  (parallel)
//   Phase B: wave w precomputes M_wk = A_wk * T_kk for k<w  (off critical path)
//   k-loop (4 steps): wave k publishes residual Y_k once; wave k applies T_kk*Y_k
//   (final output -> global), waves i>k apply Y_i -= M_ik*Y_k, all concurrently.
__global__ __launch_bounds__(256) void prep1_kernel(
    const float* __restrict__ kn, const float* __restrict__ vn,
    const float* __restrict__ beta,
    float* __restrict__ Wkbuf, float* __restrict__ U0buf) {
  __shared__ __align__(16) float Ash[64 * 68];   // A[t][s] row-major, stride 68
  __shared__ float bsh[64];
  // union region: Ksh (during A compute) aliased with Tsh/Msh/Xsh (after)
  __shared__ __align__(16) float uni[5312];
  float (*Ksh)[68] = (float (*)[68])uni;                    // 64x68 = 4352 floats
  float (*Tsh)[16][20] = (float (*)[16][20])uni;            // [4][16][20] = 1280
  float (*Msh)[16][20] = (float (*)[16][20])(uni + 1280);   // [6][16][20] = 1920
  float (*Xsh)[132] = (float (*)[132])(uni + 3200);         // [16][132]  = 2112

  int ch = blockIdx.x;
  int b = ch >> 9, h = (ch >> 5) & 15, c = ch & 31;
  int tid = threadIdx.x;
  int t = tid >> 2, seg = tid & 3;
  int wave = tid >> 6, lane = tid & 63;
  int r = lane >> 2, q = lane & 3;   // r == t&15, q == seg
  const float* krow = kn + ((size_t)(b * T_ + c * 64 + t)) * D_ + h * 64;
  #pragma unroll
  for (int g = 0; g < 4; g++)
    *(float4*)&Ksh[t][ksw(t, seg * 4 + g)] = *(const float4*)&krow[seg * 16 + 4 * g];
  if (tid < 64) bsh[tid] = beta[((size_t)(b * T_ + c * 64 + tid)) * H_ + h];
  __syncthreads();
  // A[t][s] = (t>s) ? b_t * (k_t . k_s) : 0
  {
    int s0 = seg * 16;
    float acc[16];
    #pragma unroll
    for (int rr = 0; rr < 16; rr++) acc[rr] = 0.f;
    for (int d4 = 0; d4 < 16; d4++) {
      float4 kt = *(float4*)&Ksh[t][ksw(t, d4)];
      #pragma unroll
      for (int rr = 0; rr < 16; rr++) {
        float4 ks = *(float4*)&Ksh[s0 + rr][((d4 ^ seg) << 2)];   // (s0+rr)>>4 == seg
        acc[rr] += kt.x * ks.x + kt.y * ks.y + kt.z * ks.z + kt.w * ks.w;
      }
    }
    float bt = bsh[t];
    #pragma unroll
    for (int g = 0; g < 4; g++) {
      float4 a4;
      a4.x = (t > s0 + 4*g + 0) ? bt * acc[4*g+0] : 0.f;
      a4.y = (t > s0 + 4*g + 1) ? bt * acc[4*g+1] : 0.f;
      a4.z = (t > s0 + 4*g + 2) ? bt * acc[4*g+2] : 0.f;
      a4.w = (t > s0 + 4*g + 3) ? bt * acc[4*g+3] : 0.f;
      *(float4*)&Ash[t * 68 + s0 + 4 * g] = a4;
    }
  }
  // RHS (residual Y) in registers: row t, 16 K-cols + 16 V-cols
  float xk[16], xv[16];
  {
    float bt = bsh[t];
    const float* vrow = vn + ((size_t)(b * T_ + c * 64 + t)) * D_ + h * 64;
    #pragma unroll
    for (int g = 0; g < 4; g++) {
      float4 kv = *(float4*)&Ksh[t][ksw(t, seg * 4 + g)];
      float4 vv = *(const float4*)&vrow[seg * 16 + 4 * g];
      xk[4*g+0] = bt * kv.x; xk[4*g+1] = bt * kv.y; xk[4*g+2] = bt * kv.z; xk[4*g+3] = bt * kv.w;
      xv[4*g+0] = bt * vv.x; xv[4*g+1] = bt * vv.y; xv[4*g+2] = bt * vv.z; xv[4*g+3] = bt * vv.w;
    }
  }
  __syncthreads();   // Ash ready; Ksh dead -> Tsh/Msh/Xsh region live
  // Phase A: wave-parallel 16x16 diagonal-block inverse via fwd substitution on I
  {
    float a[16];
    #pragma unroll
    for (int i = 0; i < 16; i++) a[i] = Ash[(wave * 16 + r) * 68 + wave * 16 + i];
    float4 w4 = {0.f, 0.f, 0.f, 0.f};
    if ((r >> 2) == q) ((float*)&w4)[r & 3] = 1.f;
    #pragma unroll
    for (int i = 0; i < 15; i++) {
      int src = i * 4 + q;
      float4 wi;
      wi.x = __shfl(w4.x, src, 64);
      wi.y = __shfl(w4.y, src, 64);
      wi.z = __shfl(w4.z, src, 64);
      wi.w = __shfl(w4.w, src, 64);
      if (r > i) {
        w4.x -= a[i] * wi.x; w4.y -= a[i] * wi.y;
        w4.z -= a[i] * wi.z; w4.w -= a[i] * wi.w;
      }
    }
    *(float4*)&Tsh[wave][r][q * 4] = w4;
  }
  __syncthreads();   // Tsh visible to all waves
  // Phase B: M_wk = A_wk * T_kk (wave-local write, wave-local read)
  for (int k = 0; k < wave; k++) {
    float4 m4 = {0.f, 0.f, 0.f, 0.f};
    #pragma unroll
    for (int i = 0; i < 16; i++) {
      float aik = Ash[(wave * 16 + r) * 68 + k * 16 + i];
      float4 tk = *(float4*)&Tsh[k][i][q * 4];
      m4.x += aik * tk.x; m4.y += aik * tk.y;
      m4.z += aik * tk.z; m4.w += aik * tk.w;
    }
    int mi = wave * (wave - 1) / 2 + k;
    *(float4*)&Msh[mi][r][q * 4] = m4;
  }
  // Block substitution k-loop
  float* wkout = &Wkbuf[(size_t)ch * 4096 + t * 64];
  float* u0out = &U0buf[(size_t)ch * 4096 + t * 64];
  for (int k = 0; k < 4; k++) {
    if (wave == k) {   // publish residual Y_k
      #pragma unroll
      for (int g = 0; g < 4; g++) {
        float4 k4 = {xk[4*g+0], xk[4*g+1], xk[4*g+2], xk[4*g+3]};
        float4 v4 = {xv[4*g+0], xv[4*g+1], xv[4*g+2], xv[4*g+3]};
        *(float4*)&Xsh[r][seg * 16 + 4 * g] = k4;
        *(float4*)&Xsh[r][64 + seg * 16 + 4 * g] = v4;
      }
    }
    __syncthreads();
    if (wave == k) {
      // X_k = T_kk * Y_k -> final output, straight to global
      float nk[16], nv[16];
      #pragma unroll
      for (int i2 = 0; i2 < 16; i2++) { nk[i2] = 0.f; nv[i2] = 0.f; }
      #pragma unroll
      for (int i = 0; i < 16; i++) {
        float tc = Tsh[k][r][i];
        #pragma unroll
        for (int g = 0; g < 4; g++) {
          float4 yk = *(float4*)&Xsh[i][seg * 16 + 4 * g];
          float4 yv = *(float4*)&Xsh[i][64 + seg * 16 + 4 * g];
          nk[4*g+0] += tc * yk.x; nk[4*g+1] += tc * yk.y;
          nk[4*g+2] += tc * yk.z; nk[4*g+3] += tc * yk.w;
          nv[4*g+0] += tc * yv.x; nv[4*g+1] += tc * yv.y;
          nv[4*g+2] += tc * yv.z; nv[4*g+3] += tc * yv.w;
        }
      }
      #pragma unroll
      for (int g = 0; g < 4; g++) {
        float4 k4 = {nk[4*g+0], nk[4*g+1], nk[4*g+2], nk[4*g+3]};
        float4 v4 = {nv[4*g+0], nv[4*g+1], nv[4*g+2], nv[4*g+3]};
        *(float4*)&wkout[seg * 16 + 4 * g] = k4;
        *(float4*)&u0out[seg * 16 + 4 * g] = v4;
      }
    } else if (wave > k) {
      // Y_i -= M_ik * Y_k   (== A_ik * X_k)
      int mi = wave * (wave - 1) / 2 + k;
      #pragma unroll
      for (int i = 0; i < 16; i++) {
        float mc = Msh[mi][r][i];
        #pragma unroll
        for (int g = 0; g < 4; g++) {
          float4 yk = *(float4*)&Xsh[i][seg * 16 + 4 * g];
          float4 yv = *(float4*)&Xsh[i][64 + seg * 16 + 4 * g];
          xk[4*g+0] -= mc * yk.x; xk[4*g+1] -= mc * yk.y;
          xk[4*g+2] -= mc * yk.z; xk[4*g+3] -= mc * yk.w;
          xv[4*g+0] -= mc * yv.x; xv[4*g+1] -= mc * yv.y;
          xv[4*g+2] -= mc * yv.z; xv[4*g+3] -= mc * yv.w;
        }
      }
    }
    __syncthreads();
  }
}

// prep2a: L = tril(Q K^T) (incl diagonal); Ksh chunk-swizzled like prep1
__global__ __launch_bounds__(256) void prep2a_kernel(
    const float* __restrict__ qn, const float* __restrict__ kn,
    float* __restrict__ Lbuf) {
  __shared__ float Qsh[64][68];
  __shared__ float Ksh[64][68];   // swizzled
  int ch = blockIdx.x;
  int b = ch >> 9, h = (ch >> 5) & 15, c = ch & 31;
  int tid = threadIdx.x;
  int t = tid >> 2, seg = tid & 3;
  const float* qrow = qn + ((size_t)(b * T_ + c * 64 + t)) * D_ + h * 64;
  const float* krow = kn + ((size_t)(b * T_ + c * 64 + t)) * D_ + h * 64;
  #pragma unroll
  for (int g = 0; g < 4; g++) {
    *(float4*)&Qsh[t][seg * 16 + 4 * g] = *(const float4*)&qrow[seg * 16 + 4 * g];
    *(float4*)&Ksh[t][ksw(t, seg * 4 + g)] = *(const float4*)&krow[seg * 16 + 4 * g];
  }
  __syncthreads();
  int s0 = seg * 16;
  float acc[16];
  #pragma unroll
  for (int r = 0; r < 16; r++) acc[r] = 0.f;
  for (int d4 = 0; d4 < 16; d4++) {
    float4 qt = *(float4*)&Qsh[t][d4 * 4];
    #pragma unroll
    for (int r = 0; r < 16; r++) {
      float4 ks = *(float4*)&Ksh[s0 + r][((d4 ^ seg) << 2)];
      acc[r] += qt.x * ks.x + qt.y * ks.y + qt.z * ks.z + qt.w * ks.w;
    }
  }
  #pragma unroll
  for (int g = 0; g < 4; g++) {
    float4 ov;
    ov.x = (s0 + 4*g + 0 <= t) ? acc[4*g+0] : 0.f;
    ov.y = (s0 + 4*g + 1 <= t) ? acc[4*g+1] : 0.f;
    ov.z = (s0 + 4*g + 2 <= t) ? acc[4*g+2] : 0.f;
    ov.w = (s0 + 4*g + 3 <= t) ? acc[4*g+3] : 0.f;
    *(float4*)&Lbuf[(size_t)ch * 4096 + t * 64 + s0 + 4 * g] = ov;
  }
}

// prep2b: O0 = L U0 ; Qeff = Q - L Wk (in-place over qn)
__global__ __launch_bounds__(256) void prep2b_kernel(
    const float* __restrict__ Lbuf, const float* __restrict__ Wkbuf,
    const float* __restrict__ U0buf, float* qn,
    float* __restrict__ O0buf) {
  __shared__ float Lsh[64][68];
  __shared__ float Wksh[64][68];
  __shared__ float U0sh[64][68];
  int ch = blockIdx.x;
  int b = ch >> 9, h = (ch >> 5) & 15, c = ch & 31;
  int tid = threadIdx.x;
  int t = tid >> 2, seg = tid & 3;
  #pragma unroll
  for (int g = 0; g < 4; g++) {
    int o = t * 64 + seg * 16 + 4 * g;
    *(float4*)&Lsh[t][seg * 16 + 4 * g]  = *(const float4*)&Lbuf[(size_t)ch * 4096 + o];
    *(float4*)&Wksh[t][seg * 16 + 4 * g] = *(const float4*)&Wkbuf[(size_t)ch * 4096 + o];
    *(float4*)&U0sh[t][seg * 16 + 4 * g] = *(const float4*)&U0buf[(size_t)ch * 4096 + o];
  }
  __syncthreads();
  int j0 = seg * 16;
  float o0[16], lw[16];
  #pragma unroll
  for (int r = 0; r < 16; r++) { o0[r] = 0.f; lw[r] = 0.f; }
  for (int s = 0; s <= t; s++) {
    float l = Lsh[t][s];
    #pragma unroll
    for (int g = 0; g < 4; g++) {
      float4 u = *(float4*)&U0sh[s][j0 + 4 * g];
      float4 w = *(float4*)&Wksh[s][j0 + 4 * g];
      o0[4*g+0] += l * u.x; o0[4*g+1] += l * u.y; o0[4*g+2] += l * u.z; o0[4*g+3] += l * u.w;
      lw[4*g+0] += l * w.x; lw[4*g+1] += l * w.y; lw[4*g+2] += l * w.z; lw[4*g+3] += l * w.w;
    }
  }
  float* qrow = qn + ((size_t)(b * T_ + c * 64 + t)) * D_ + h * 64;
  #pragma unroll
  for (int g = 0; g < 4; g++) {
    float4 qv = *(const float4*)&qrow[j0 + 4 * g];
    qv.x -= lw[4*g+0]; qv.y -= lw[4*g+1]; qv.z -= lw[4*g+2]; qv.w -= lw[4*g+3];
    *(float4*)&qrow[j0 + 4 * g] = qv;
    float4 ov = {o0[4*g+0], o0[4*g+1], o0[4*g+2], o0[4*g+3]};
    *(float4*)&O0buf[(size_t)ch * 4096 + t * 64 + j0 + 4 * g] = ov;
  }
}

// prep2c: P[d][e] = I - (K^T Wk)[d][e], stored SLOT-MAJOR for state_kernel:
//         float4 #(f*64+d) of chunk = P[d][4f..4f+3]  (so a wave reading slot f,
//         all rows d, is one contiguous 1KB block).
//         Zt[j][d] = (U0^T K)[j][d] -> kn rows j (coalesced), unchanged.
__global__ __launch_bounds__(256) void prep2c_kernel(
    float* kn, const float* __restrict__ Wkbuf,
    const float* __restrict__ U0buf, float* __restrict__ Pbuf) {
  __shared__ float Ksh[64][68];
  __shared__ float Wksh[64][68];
  __shared__ float U0sh[64][68];
  int ch = blockIdx.x;
  int b = ch >> 9, h = (ch >> 5) & 15, c = ch & 31;
  int tid = threadIdx.x;
  int t = tid >> 2, seg = tid & 3;   // t = output row (d for P, j for Zt)
  const float* krow = kn + ((size_t)(b * T_ + c * 64 + t)) * D_ + h * 64;
  #pragma unroll
  for (int g = 0; g < 4; g++) {
    int o = t * 64 + seg * 16 + 4 * g;
    *(float4*)&Ksh[t][seg * 16 + 4 * g]  = *(const float4*)&krow[seg * 16 + 4 * g];
    *(float4*)&Wksh[t][seg * 16 + 4 * g] = *(const float4*)&Wkbuf[(size_t)ch * 4096 + o];
    *(float4*)&U0sh[t][seg * 16 + 4 * g] = *(const float4*)&U0buf[(size_t)ch * 4096 + o];
  }
  __syncthreads();
  int d0 = seg * 16;
  float accP[16], accZ[16];
  #pragma unroll
  for (int r = 0; r < 16; r++) { accP[r] = 0.f; accZ[r] = 0.f; }
  for (int s = 0; s < 64; s++) {
    float kt = Ksh[s][t];    // scalar for P row d=t
    float u  = U0sh[s][t];   // scalar for Z row j=t
    #pragma unroll
    for (int g = 0; g < 4; g++) {
      float4 w4 = *(float4*)&Wksh[s][d0 + 4 * g];
      float4 k4 = *(float4*)&Ksh[s][d0 + 4 * g];
      accP[4*g+0] += kt * w4.x; accP[4*g+1] += kt * w4.y; accP[4*g+2] += kt * w4.z; accP[4*g+3] += kt * w4.w;
      accZ[4*g+0] += u * k4.x;  accZ[4*g+1] += u * k4.y;  accZ[4*g+2] += u * k4.z;  accZ[4*g+3] += u * k4.w;
    }
  }
  float* zrow = kn + ((size_t)(b * T_ + c * 64 + t)) * D_ + h * 64;
  #pragma unroll
  for (int g = 0; g < 4; g++) {
    float4 pv;
    pv.x = ((d0 + 4*g + 0) == t ? 1.f : 0.f) - accP[4*g+0];
    pv.y = ((d0 + 4*g + 1) == t ? 1.f : 0.f) - accP[4*g+1];
    pv.z = ((d0 + 4*g + 2) == t ? 1.f : 0.f) - accP[4*g+2];
    pv.w = ((d0 + 4*g + 3) == t ? 1.f : 0.f) - accP[4*g+3];
    // slot-major: slot f = seg*4+g, row d = t
    *(float4*)&Pbuf[(size_t)ch * 4096 + (size_t)(seg * 4 + g) * 256 + (size_t)t * 4] = pv;
    float4 zv = {accZ[4*g+0], accZ[4*g+1], accZ[4*g+2], accZ[4*g+3]};
    *(float4*)&zrow[d0 + 4 * g] = zv;
  }
}

// ---------- state scan: S_{c+1} = P_c S_c + Z_c; Sbuf transposed [ch][j][d] ----------
// 512 blocks = (bh, js), 256 threads = 4 waves; wave wv owns single column
// j0 = js*4 + wv; lane = d holds S[j0][d]. P_c staged ONCE per block into LDS
// (slot-major -> conflict-free contiguous b128 reads), double-buffered; the 4
// waves share it -> same L2 traffic as the 1-wave version but 2048 waves total
// (2 waves/SIMD) so ds_read/barrier stalls overlap across waves. One
// __syncthreads per chunk (its implicit vmcnt drain covers staging visibility).
// bh = bid&31 so the 16 block-sharers of a (b,h) land on the same XCD.
__global__ __launch_bounds__(256) void state_kernel(
    const float* __restrict__ kn /*Zt*/, const float* __restrict__ Pbuf /*slot-major*/,
    float* __restrict__ Sbuf) {
  __shared__ __align__(16) float Pl[2][4096];
  int bid = blockIdx.x;
  int bh = bid & 31, js = bid >> 5;
  int h = bh & 15, b = bh >> 4;
  int tid = threadIdx.x;
  int wv = tid >> 6, lane = tid & 63;   // lane = d
  int j0 = js * 4 + wv;                 // this wave's column
  float s0 = 0.f;
  const size_t bhNC = (size_t)bh * NC_;
  // prologue: stage P_0 into buf0 (256 threads x 16B x 4 passes = 16KB), load Z_0
  const float* Pg0 = Pbuf + bhNC * 4096;
  #pragma unroll
  for (int g = 0; g < 4; g++)
    __builtin_amdgcn_global_load_lds(
        (const __attribute__((address_space(1))) void*)(Pg0 + (g * 256 + tid) * 4),
        (__attribute__((address_space(3))) void*)&Pl[0][(g * 256 + tid) * 4], 16, 0, 0);
  float zn = kn[((size_t)(b * T_ + j0)) * D_ + h * 64 + lane];
  int cur = 0;
  #pragma unroll 1
  for (int c = 0; c < NC_; c++) {
    __syncthreads();            // implies vmcnt(0) drain: buf[cur] ready for all waves
    float z = zn;
    size_t ch = bhNC + c;
    // issue next-chunk staging into the other buffer + Z prefetch
    if (c + 1 < NC_) {
      const float* Pg = Pbuf + (ch + 1) * 4096;
      #pragma unroll
      for (int g = 0; g < 4; g++)
        __builtin_amdgcn_global_load_lds(
            (const __attribute__((address_space(1))) void*)(Pg + (g * 256 + tid) * 4),
            (__attribute__((address_space(3))) void*)&Pl[cur ^ 1][(g * 256 + tid) * 4], 16, 0, 0);
      zn = kn[((size_t)(b * T_ + (c + 1) * 64 + j0)) * D_ + h * 64 + lane];
    }
    // store S_c (pre-update), coalesced 256B per wave
    Sbuf[ch * 4096 + (size_t)j0 * 64 + lane] = s0;
    // S_{c+1}[j0][d=lane] = Z[j0][d] + sum_e P[d][e] * S_c[j0][e]
    float acc = z;
    #pragma unroll
    for (int f = 0; f < 16; f++) {
      floatx4 pv = *(floatx4*)&Pl[cur][f * 256 + lane * 4];
      acc += pv.x * rdlane(s0, f * 4 + 0);
      acc += pv.y * rdlane(s0, f * 4 + 1);
      acc += pv.z * rdlane(s0, f * 4 + 2);
      acc += pv.w * rdlane(s0, f * 4 + 3);
    }
    s0 = acc;
    cur ^= 1;
  }
}

// ---------- O = O0 + Qeff*S_c (S transposed layout), fused RMSNorm + bf16 cast ----------
__global__ __launch_bounds__(256) void ophase_kernel(
    const float* __restrict__ qn /*Qeff*/, const float* __restrict__ Sbuf,
    const float* __restrict__ O0buf, const float* __restrict__ rms_g,
    ushort* __restrict__ ob) {
  __shared__ float Ssht[64][68];
  __shared__ float QshT[64][65];
  __shared__ float part[64][4];
  int ch = blockIdx.x;
  int b = ch >> 9, h = (ch >> 5) & 15, c = ch & 31;
  int tid = threadIdx.x;
  int t = tid & 63, jg = tid >> 6;
  #pragma unroll
  for (int g = 0; g < 4; g++) {
    int idx = tid + g * 256;
    *(float4*)&Ssht[idx >> 4][(idx & 15) * 4] =
        *(const float4*)&Sbuf[(size_t)ch * 4096 + (size_t)idx * 4];
  }
  #pragma unroll
  for (int g = 0; g < 4; g++) {
    int idx = tid + g * 256;
    int row = idx >> 4, c4 = idx & 15;
    float4 qv = *(const float4*)&qn[((size_t)(b * T_ + c * 64 + row)) * D_ + h * 64 + c4 * 4];
    QshT[c4 * 4 + 0][row] = qv.x;
    QshT[c4 * 4 + 1][row] = qv.y;
    QshT[c4 * 4 + 2][row] = qv.z;
    QshT[c4 * 4 + 3][row] = qv.w;
  }
  float o[16];
  #pragma unroll
  for (int g = 0; g < 4; g++) {
    float4 o4 = *(const float4*)&O0buf[(size_t)ch * 4096 + t * 64 + jg * 16 + g * 4];
    o[4*g+0] = o4.x; o[4*g+1] = o4.y; o[4*g+2] = o4.z; o[4*g+3] = o4.w;
  }
  __syncthreads();
  for (int d4 = 0; d4 < 16; d4++) {
    float q0 = QshT[d4 * 4 + 0][t];
    float q1 = QshT[d4 * 4 + 1][t];
    float q2 = QshT[d4 * 4 + 2][t];
    float q3 = QshT[d4 * 4 + 3][t];
    #pragma unroll
    for (int r = 0; r < 16; r++) {
      float4 s4 = *(float4*)&Ssht[jg * 16 + r][d4 * 4];
      o[r] += q0 * s4.x + q1 * s4.y + q2 * s4.z + q3 * s4.w;
    }
  }
  float ss = 0.f;
  #pragma unroll
  for (int r = 0; r < 16; r++) ss += o[r] * o[r];
  part[t][jg] = ss;
  __syncthreads();
  float tot = part[t][0] + part[t][1] + part[t][2] + part[t][3];
  float sc = rsqrtf(tot * (1.f / 64.f) + 1e-6f);
  ushort* orow = &ob[((size_t)(b * T_ + c * 64 + t)) * D_ + h * 64];
  #pragma unroll
  for (int g = 0; g < 4; g++) {
    float4 g4 = *(const float4*)&rms_g[jg * 16 + g * 4];
    ushort4 r4;
    r4.x = f2bf(o[4*g+0] * sc * g4.x); r4.y = f2bf(o[4*g+1] * sc * g4.y);
    r4.z = f2bf(o[4*g+2] * sc * g4.z); r4.w = f2bf(o[4*g+3] * sc * g4.w);
    *(ushort4*)&orow[jg * 16 + g * 4] = r4;
  }
}

extern "C" void kernel_launch(void* const* d_in, const int* in_sizes, int n_in,
                              void* d_out, int out_size, void* d_ws, size_t ws_size,
                              hipStream_t stream) {
  const float* x  = (const float*)d_in[0];
  const float* Wq = (const float*)d_in[1];
  const float* Wk = (const float*)d_in[2];
  const float* Wv = (const float*)d_in[3];
  const float* Wb = (const float*)d_in[4];
  const float* cq = (const float*)d_in[5];
  const float* ck = (const float*)d_in[6];
  const float* cv = (const float*)d_in[7];
  const float* rg = (const float*)d_in[8];
  const float* Wo = (const float*)d_in[9];
  float* out = (float*)d_out;
  char* ws = (char*)d_ws;
  const size_t MiB = 1ull << 20;
  ushort* xb   = (ushort*)(ws + 0);         // dead after QKV gemm
  ushort* Wqt  = (ushort*)(ws + 8 * MiB);   // Wqt/Wkt/Wvt contiguous = [3072][1024] bf16
  ushort* Wkt  = (ushort*)(ws + 10 * MiB);
  ushort* Wvt  = (ushort*)(ws + 12 * MiB);
  ushort* Wot  = (ushort*)(ws + 14 * MiB);  // live to end
  float* qkv   = (float*)(ws + 16 * MiB);   // [4096][3072] fp32, dead after conv
  float* qn    = (float*)(ws + 64 * MiB);   // then Qeff in-place
  float* kn    = (float*)(ws + 80 * MiB);   // then Zt in-place
  float* vn    = (float*)(ws + 96 * MiB);   // dead after prep1
  float* beta  = (float*)(ws + 112 * MiB);  // 256 KiB
  float* WbT   = (float*)(ws + 112 * MiB + 256 * 1024);  // 64 KiB
  float* Wkbuf = (float*)(ws + 16 * MiB);   // over qkv (dead after conv)
  float* U0buf = (float*)(ws + 32 * MiB);
  float* Lbuf  = (float*)(ws + 48 * MiB);   // later P
  float* O0buf = (float*)(ws + 96 * MiB);   // over vn (after prep1)
  float* Sbuf  = (float*)(ws + 16 * MiB);   // over Wkbuf (dead after prep2c)
  ushort* ob   = (ushort*)(ws + 0);         // over xb (after QKV gemm)

  hipLaunchKernelGGL(cast_kernel, dim3(M_ * D_ / 4 / 256), dim3(256), 0, stream,
                     x, xb, M_ * D_ / 4);
  dim3 tb(32, 8);
  hipLaunchKernelGGL(transpose_cast_kernel, dim3(32, 32), tb, 0, stream, Wq, Wqt, D_, D_);
  hipLaunchKernelGGL(transpose_cast_kernel, dim3(32, 32), tb, 0, stream, Wk, Wkt, D_, D_);
  hipLaunchKernelGGL(transpose_cast_kernel, dim3(32, 32), tb, 0, stream, Wv, Wvt, D_, D_);
  hipLaunchKernelGGL(transpose_cast_kernel, dim3(32, 32), tb, 0, stream, Wo, Wot, D_, D_);
  hipLaunchKernelGGL(transpose_wb_kernel, dim3(64), dim3(256), 0, stream, Wb, WbT);

  hipLaunchKernelGGL(gemm128_kernel, dim3(M_ / 128, QKVN_ / 128), dim3(256), 0, stream,
                     xb, Wqt, qkv, M_, QKVN_, D_);

  hipLaunchKernelGGL(beta_kernel, dim3(M_), dim3(256), 0, stream, x, WbT, beta);
  hipLaunchKernelGGL(conv_kernel, dim3(M_), dim3(256), 0, stream,
                     qkv, cq, ck, cv, qn, kn, vn);

  hipLaunchKernelGGL(prep1_kernel, dim3(NCH_), dim3(256), 0, stream,
                     kn, vn, beta, Wkbuf, U0buf);
  hipLaunchKernelGGL(prep2a_kernel, dim3(NCH_), dim3(256), 0, stream, qn, kn, Lbuf);
  hipLaunchKernelGGL(prep2b_kernel, dim3(NCH_), dim3(256), 0, stream,
                     Lbuf, Wkbuf, U0buf, qn, O0buf);
  hipLaunchKernelGGL(prep2c_kernel, dim3(NCH_), dim3(256), 0, stream,
                     kn, Wkbuf, U0buf, Lbuf);
  hipLaunchKernelGGL(state_kernel, dim3(512), dim3(256), 0, stream,
                     kn, Lbuf, Sbuf);
  hipLaunchKernelGGL(ophase_kernel, dim3(NCH_), dim3(256), 0, stream,
                     qn, Sbuf, O0buf, rg, ob);
  hipLaunchKernelGGL(gemm128_kernel, dim3(M_ / 128, D_ / 128), dim3(256), 0, stream,
                     ob, Wot, out, M_, D_, D_);
}

// Round 5
// 398.812 us; speedup vs baseline: 1.1243x; 1.0192x over previous
//
#include <hip/hip_runtime.h>
#include <hip/hip_bf16.h>
#include <math.h>

#define B_ 2
#define T_ 2048
#define D_ 1024
#define H_ 16
#define DH_ 64
#define M_ (B_*T_)   // 4096 rows
#define NC_ 32       // chunks per sequence (T/64)
#define CS_ 64       // chunk size
#define NCH_ (B_*H_*NC_)  // 1024 chunk-heads
#define QKVN_ 3072   // fused QKV gemm N

typedef __attribute__((ext_vector_type(4))) float floatx4;
typedef __attribute__((ext_vector_type(8))) short short8;

__device__ __forceinline__ ushort f2bf(float f) {
  union { float f; unsigned u; } c; c.f = f;
  unsigned r = (c.u + 0x7FFFu + ((c.u >> 16) & 1u)) >> 16;  // RNE
  return (ushort)r;
}
__device__ __forceinline__ float siluf(float u) {
  return u / (1.f + __expf(-u));
}
__device__ __forceinline__ float f4get(const float4& v, int j) {
  return j == 0 ? v.x : j == 1 ? v.y : j == 2 ? v.z : v.w;
}
__device__ __forceinline__ float rdlane(float v, int l) {
  return __int_as_float(__builtin_amdgcn_readlane(__float_as_int(v), l));
}
// swizzled chunk index for K tiles: chunk c (0..15) of row r stored at c ^ (r>>4)
__device__ __forceinline__ int ksw(int r, int c) { return ((c ^ (r >> 4)) << 2); }

// split 8 consecutive fp32 into hi/lo bf16 fragments (x = hi + lo exactly to 2^-16)
__device__ __forceinline__ void frag_split(const float* src, short8& fh, short8& fl) {
  float4 va = *(const float4*)src;
  float4 vb = *(const float4*)(src + 4);
  float v[8] = {va.x, va.y, va.z, va.w, vb.x, vb.y, vb.z, vb.w};
  #pragma unroll
  for (int j = 0; j < 8; j++) {
    unsigned u = __float_as_uint(v[j]);
    fh[j] = (short)(u >> 16);                     // truncated bf16 hi
    float hif = __uint_as_float(u & 0xFFFF0000u);
    fl[j] = (short)(__float_as_uint(v[j] - hif) >> 16);   // residual as bf16
  }
}

// ---------- cast f32 -> bf16, n4 = n/4 ----------
__global__ void cast_kernel(const float* __restrict__ in, ushort* __restrict__ out, int n4) {
  int i = blockIdx.x * blockDim.x + threadIdx.x;
  if (i >= n4) return;
  float4 v = ((const float4*)in)[i];
  ushort4 o;
  o.x = f2bf(v.x); o.y = f2bf(v.y); o.z = f2bf(v.z); o.w = f2bf(v.w);
  ((ushort4*)out)[i] = o;
}

// ---------- transpose + cast: W[K][N] f32 -> Wt[N][K] bf16 ----------
__global__ void transpose_cast_kernel(const float* __restrict__ W, ushort* __restrict__ Wt,
                                      int K, int N) {
  __shared__ float tile[32][33];
  int tx = threadIdx.x, ty = threadIdx.y;
  int n0 = blockIdx.x * 32, k0 = blockIdx.y * 32;
  #pragma unroll
  for (int i = 0; i < 32; i += 8)
    tile[ty + i][tx] = W[(size_t)(k0 + ty + i) * N + n0 + tx];
  __syncthreads();
  #pragma unroll
  for (int i = 0; i < 32; i += 8)
    Wt[(size_t)(n0 + ty + i) * K + k0 + tx] = f2bf(tile[tx][ty + i]);
}

// ---------- transpose Wb[1024][16] -> WbT[16][1024] (fp32) ----------
__global__ void transpose_wb_kernel(const float* __restrict__ Wb, float* __restrict__ WbT) {
  int bk = blockIdx.x;
  int tid = threadIdx.x;
  int kl = tid >> 4, h = tid & 15;
  int k = bk * 16 + kl;
  WbT[(size_t)h * D_ + k] = Wb[(size_t)k * H_ + h];
}

// ---------- m97-style bf16 MFMA GEMM: C[M][N] = A[M][K]*B[K][N], Bt = B^T [N][K] ----------
__global__ __launch_bounds__(256) void gemm128_kernel(
    const ushort* __restrict__ A, const ushort* __restrict__ Bt,
    float* __restrict__ C, int M, int N, int K) {
  __shared__ ushort lA[128 * 32];
  __shared__ ushort lB[128 * 32];
  int tid = threadIdx.x;
  int wave = tid >> 6, lane = tid & 63;
  int wm = wave >> 1, wn = wave & 1;
  int m16 = lane & 15, q4 = lane >> 4;
  int bm = blockIdx.x, bn = blockIdx.y;
  floatx4 acc[4][4] = {};
  int srow = tid >> 2;
  int sk8 = tid & 3;
  const ushort* Ag = A + (size_t)(bm * 128 + srow) * K + sk8 * 8;
  const ushort* Bg = Bt + (size_t)(bn * 128 + srow) * K + sk8 * 8;
  ushort* lAp = lA + tid * 8;
  ushort* lBp = lB + tid * 8;
  for (int k0 = 0; k0 < K; k0 += 32) {
    __builtin_amdgcn_global_load_lds(
        (const __attribute__((address_space(1))) void*)(Ag + k0),
        (__attribute__((address_space(3))) void*)lAp, 16, 0, 0);
    __builtin_amdgcn_global_load_lds(
        (const __attribute__((address_space(1))) void*)(Ag + (size_t)64 * K + k0),
        (__attribute__((address_space(3))) void*)(lAp + 2048), 16, 0, 0);
    __builtin_amdgcn_global_load_lds(
        (const __attribute__((address_space(1))) void*)(Bg + k0),
        (__attribute__((address_space(3))) void*)lBp, 16, 0, 0);
    __builtin_amdgcn_global_load_lds(
        (const __attribute__((address_space(1))) void*)(Bg + (size_t)64 * K + k0),
        (__attribute__((address_space(3))) void*)(lBp + 2048), 16, 0, 0);
    __syncthreads();
    short8 af[4], bf[4];
    #pragma unroll
    for (int i = 0; i < 4; i++) {
      af[i] = *(short8*)&lA[(wm * 64 + i * 16 + m16) * 32 + q4 * 8];
      bf[i] = *(short8*)&lB[(wn * 64 + i * 16 + m16) * 32 + q4 * 8];
    }
    #pragma unroll
    for (int mi = 0; mi < 4; mi++)
      #pragma unroll
      for (int nj = 0; nj < 4; nj++)
        acc[mi][nj] = __builtin_amdgcn_mfma_f32_16x16x32_bf16(af[mi], bf[nj], acc[mi][nj], 0, 0, 0);
    __syncthreads();
  }
  float* Cb = C + (size_t)(bm * 128) * N + bn * 128;
  #pragma unroll
  for (int mi = 0; mi < 4; mi++) {
    #pragma unroll
    for (int nj = 0; nj < 4; nj++) {
      #pragma unroll
      for (int i = 0; i < 4; i++) {
        int row = wm * 64 + mi * 16 + q4 * 4 + i;
        int col = wn * 64 + nj * 16 + m16;
        Cb[(size_t)row * N + col] = acc[mi][nj][i];
      }
    }
  }
}

// ---------- beta = sigmoid(x @ Wb), WbT[16][1024], conflict-free ----------
__global__ __launch_bounds__(256) void beta_kernel(const float* __restrict__ x,
                                                   const float* __restrict__ WbT,
                                                   float* __restrict__ beta) {
  __shared__ __align__(16) float xs[D_];
  int row = blockIdx.x;
  int tid = threadIdx.x;
  ((float4*)xs)[tid] = ((const float4*)(x + (size_t)row * D_))[tid];
  __syncthreads();
  int h = tid >> 4;
  int seg = tid & 15;
  const float4* wrow = (const float4*)(WbT + (size_t)h * D_) + seg * 16;
  const float4* xsrow = (const float4*)xs + seg * 16;
  float s = 0.f;
  #pragma unroll
  for (int j = 0; j < 16; j++) {
    int jj = (j + seg) & 15;
    float4 xv = xsrow[jj];
    float4 wv = wrow[jj];
    s += xv.x * wv.x + xv.y * wv.y + xv.z * wv.z + xv.w * wv.w;
  }
  #pragma unroll
  for (int off = 8; off; off >>= 1) s += __shfl_down(s, off, 16);
  if (seg == 0) beta[(size_t)row * H_ + h] = 1.f / (1.f + __expf(-s));
}

// ---------- causal depthwise conv(K=4) + silu, l2norm for q,k ----------
__global__ __launch_bounds__(256) void conv_kernel(
    const float* __restrict__ qkv,
    const float* __restrict__ cq, const float* __restrict__ ck, const float* __restrict__ cv,
    float* __restrict__ qo, float* __restrict__ ko, float* __restrict__ vo) {
  int row = blockIdx.x;
  int t = row & (T_ - 1);
  int tid = threadIdx.x;
  int c0 = tid * 4;
  float4 zf = {0.f, 0.f, 0.f, 0.f};
  float4 xq[4], xk[4], xv[4];
  #pragma unroll
  for (int i = 0; i < 4; i++) {
    int tt = t - 3 + i;
    if (tt >= 0) {
      const float* rp = qkv + (size_t)(row - 3 + i) * QKVN_;
      xq[i] = *(const float4*)(rp + c0);
      xk[i] = *(const float4*)(rp + 1024 + c0);
      xv[i] = *(const float4*)(rp + 2048 + c0);
    } else { xq[i] = zf; xk[i] = zf; xv[i] = zf; }
  }
  float yq[4], yk[4], yv[4];
  float pq = 0.f, pk = 0.f;
  #pragma unroll
  for (int j = 0; j < 4; j++) {
    float4 wq = ((const float4*)cq)[c0 + j];
    float4 wk = ((const float4*)ck)[c0 + j];
    float4 wv = ((const float4*)cv)[c0 + j];
    float sq = 0.f, sk = 0.f, sv = 0.f;
    #pragma unroll
    for (int i = 0; i < 4; i++) {
      sq += f4get(wq, i) * f4get(xq[i], j);
      sk += f4get(wk, i) * f4get(xk[i], j);
      sv += f4get(wv, i) * f4get(xv[i], j);
    }
    yq[j] = siluf(sq); yk[j] = siluf(sk); yv[j] = siluf(sv);
    pq += yq[j] * yq[j]; pk += yk[j] * yk[j];
  }
  #pragma unroll
  for (int off = 1; off < 16; off <<= 1) {
    pq += __shfl_xor(pq, off, 16);
    pk += __shfl_xor(pk, off, 16);
  }
  float rq = rsqrtf(pq + 1e-6f), rk = rsqrtf(pk + 1e-6f);
  float4 oq = {yq[0]*rq, yq[1]*rq, yq[2]*rq, yq[3]*rq};
  float4 okk = {yk[0]*rk, yk[1]*rk, yk[2]*rk, yk[3]*rk};
  float4 ov = {yv[0], yv[1], yv[2], yv[3]};
  *(float4*)(qo + (size_t)row * D_ + c0) = oq;
  *(float4*)(ko + (size_t)row * D_ + c0) = okk;
  *(float4*)(vo + (size_t)row * D_ + c0) = ov;
}

// ================= chunked delta rule =================
// prep1: A = strict_tril(diag(b)KK^T); solve (I+A)Wk = diag(b)K and (I+A)U0 = diag(b)V
// A-compute via split-bf16 MFMA (x=hi+lo; x*y ~ hi*hi+hi*lo+lo*hi, err ~2^-17):
//   was 272 ds_read_b128/thread on the LDS pipe -> now 18 b128/wave + 24 MFMA/wave.
// Then blocked forward substitution (unchanged):
//   Phase A: each wave w inverts its 16x16 diag block T_ww = (I+A_ww)^-1  (parallel)
//   Phase B: wave w precomputes M_wk = A_wk * T_kk for k<w  (off critical path)
//   k-loop (4 steps): wave k publishes residual Y_k once; wave k applies T_kk*Y_k
//   (final output -> global), waves i>k apply Y_i -= M_ik*Y_k, all concurrently.
__global__ __launch_bounds__(256) void prep1_kernel(
    const float* __restrict__ kn, const float* __restrict__ vn,
    const float* __restrict__ beta,
    float* __restrict__ Wkbuf, float* __restrict__ U0buf) {
  __shared__ __align__(16) float Ash[64 * 68];   // A[t][s] row-major, stride 68
  __shared__ float bsh[64];
  // union region: Ksh (during A compute) aliased with Tsh/Msh/Xsh (after)
  __shared__ __align__(16) float uni[5312];
  float (*Ksh)[68] = (float (*)[68])uni;                    // 64x68 = 4352 floats (LINEAR)
  float (*Tsh)[16][20] = (float (*)[16][20])uni;            // [4][16][20] = 1280
  float (*Msh)[16][20] = (float (*)[16][20])(uni + 1280);   // [6][16][20] = 1920
  float (*Xsh)[132] = (float (*)[132])(uni + 3200);         // [16][132]  = 2112

  int ch = blockIdx.x;
  int b = ch >> 9, h = (ch >> 5) & 15, c = ch & 31;
  int tid = threadIdx.x;
  int t = tid >> 2, seg = tid & 3;
  int wave = tid >> 6, lane = tid & 63;
  int r = lane >> 2, q = lane & 3;   // r == t&15, q == seg
  int m16 = lane & 15, oct = lane >> 4;
  const float* krow = kn + ((size_t)(b * T_ + c * 64 + t)) * D_ + h * 64;
  #pragma unroll
  for (int g = 0; g < 4; g++)
    *(float4*)&Ksh[t][seg * 16 + 4 * g] = *(const float4*)&krow[seg * 16 + 4 * g];
  if (tid < 64) bsh[tid] = beta[((size_t)(b * T_ + c * 64 + tid)) * H_ + h];
  __syncthreads();
  // A[t][s] = (t>s) ? b_t * (k_t . k_s) : 0 — via MFMA, wave w owns row-tile w.
  // Fragment: lane holds row (tile*16 + m16), k-octet oct*8 within the 32-K step.
  {
    floatx4 acc[4] = {};
    #pragma unroll
    for (int ks = 0; ks < 2; ks++) {
      short8 fbh[4], fbl[4];
      #pragma unroll
      for (int rt = 0; rt < 4; rt++)
        frag_split(&Ksh[rt * 16 + m16][ks * 32 + oct * 8], fbh[rt], fbl[rt]);
      // this wave's A-operand fragment (runtime ADDRESS, static reg indices)
      short8 fah, fal;
      frag_split(&Ksh[wave * 16 + m16][ks * 32 + oct * 8], fah, fal);
      #pragma unroll
      for (int si = 0; si < 4; si++) {
        acc[si] = __builtin_amdgcn_mfma_f32_16x16x32_bf16(fah, fbh[si], acc[si], 0, 0, 0);
        acc[si] = __builtin_amdgcn_mfma_f32_16x16x32_bf16(fah, fbl[si], acc[si], 0, 0, 0);
        acc[si] = __builtin_amdgcn_mfma_f32_16x16x32_bf16(fal, fbh[si], acc[si], 0, 0, 0);
      }
    }
    // D layout: row = oct*4 + rr (within tile), col = m16; scale by b_row, strict tril
    #pragma unroll
    for (int rr = 0; rr < 4; rr++) {
      int row = wave * 16 + oct * 4 + rr;
      float bt = bsh[row];
      #pragma unroll
      for (int si = 0; si < 4; si++) {
        int col = si * 16 + m16;
        Ash[row * 68 + col] = (row > col) ? bt * acc[si][rr] : 0.f;
      }
    }
  }
  // RHS (residual Y) in registers: row t, 16 K-cols + 16 V-cols
  float xk[16], xv[16];
  {
    float bt = bsh[t];
    const float* vrow = vn + ((size_t)(b * T_ + c * 64 + t)) * D_ + h * 64;
    #pragma unroll
    for (int g = 0; g < 4; g++) {
      float4 kv = *(float4*)&Ksh[t][seg * 16 + 4 * g];
      float4 vv = *(const float4*)&vrow[seg * 16 + 4 * g];
      xk[4*g+0] = bt * kv.x; xk[4*g+1] = bt * kv.y; xk[4*g+2] = bt * kv.z; xk[4*g+3] = bt * kv.w;
      xv[4*g+0] = bt * vv.x; xv[4*g+1] = bt * vv.y; xv[4*g+2] = bt * vv.z; xv[4*g+3] = bt * vv.w;
    }
  }
  __syncthreads();   // Ash ready; Ksh dead -> Tsh/Msh/Xsh region live
  // Phase A: wave-parallel 16x16 diagonal-block inverse via fwd substitution on I
  {
    float a[16];
    #pragma unroll
    for (int i = 0; i < 16; i++) a[i] = Ash[(wave * 16 + r) * 68 + wave * 16 + i];
    float4 w4 = {0.f, 0.f, 0.f, 0.f};
    if ((r >> 2) == q) ((float*)&w4)[r & 3] = 1.f;
    #pragma unroll
    for (int i = 0; i < 15; i++) {
      int src = i * 4 + q;
      float4 wi;
      wi.x = __shfl(w4.x, src, 64);
      wi.y = __shfl(w4.y, src, 64);
      wi.z = __shfl(w4.z, src, 64);
      wi.w = __shfl(w4.w, src, 64);
      if (r > i) {
        w4.x -= a[i] * wi.x; w4.y -= a[i] * wi.y;
        w4.z -= a[i] * wi.z; w4.w -= a[i] * wi.w;
      }
    }
    *(float4*)&Tsh[wave][r][q * 4] = w4;
  }
  __syncthreads();   // Tsh visible to all waves
  // Phase B: M_wk = A_wk * T_kk (wave-local write, wave-local read)
  for (int k = 0; k < wave; k++) {
    float4 m4 = {0.f, 0.f, 0.f, 0.f};
    #pragma unroll
    for (int i = 0; i < 16; i++) {
      float aik = Ash[(wave * 16 + r) * 68 + k * 16 + i];
      float4 tk = *(float4*)&Tsh[k][i][q * 4];
      m4.x += aik * tk.x; m4.y += aik * tk.y;
      m4.z += aik * tk.z; m4.w += aik * tk.w;
    }
    int mi = wave * (wave - 1) / 2 + k;
    *(float4*)&Msh[mi][r][q * 4] = m4;
  }
  // Block substitution k-loop
  float* wkout = &Wkbuf[(size_t)ch * 4096 + t * 64];
  float* u0out = &U0buf[(size_t)ch * 4096 + t * 64];
  for (int k = 0; k < 4; k++) {
    if (wave == k) {   // publish residual Y_k
      #pragma unroll
      for (int g = 0; g < 4; g++) {
        float4 k4 = {xk[4*g+0], xk[4*g+1], xk[4*g+2], xk[4*g+3]};
        float4 v4 = {xv[4*g+0], xv[4*g+1], xv[4*g+2], xv[4*g+3]};
        *(float4*)&Xsh[r][seg * 16 + 4 * g] = k4;
        *(float4*)&Xsh[r][64 + seg * 16 + 4 * g] = v4;
      }
    }
    __syncthreads();
    if (wave == k) {
      // X_k = T_kk * Y_k -> final output, straight to global
      float nk[16], nv[16];
      #pragma unroll
      for (int i2 = 0; i2 < 16; i2++) { nk[i2] = 0.f; nv[i2] = 0.f; }
      #pragma unroll
      for (int i = 0; i < 16; i++) {
        float tc = Tsh[k][r][i];
        #pragma unroll
        for (int g = 0; g < 4; g++) {
          float4 yk = *(float4*)&Xsh[i][seg * 16 + 4 * g];
          float4 yv = *(float4*)&Xsh[i][64 + seg * 16 + 4 * g];
          nk[4*g+0] += tc * yk.x; nk[4*g+1] += tc * yk.y;
          nk[4*g+2] += tc * yk.z; nk[4*g+3] += tc * yk.w;
          nv[4*g+0] += tc * yv.x; nv[4*g+1] += tc * yv.y;
          nv[4*g+2] += tc * yv.z; nv[4*g+3] += tc * yv.w;
        }
      }
      #pragma unroll
      for (int g = 0; g < 4; g++) {
        float4 k4 = {nk[4*g+0], nk[4*g+1], nk[4*g+2], nk[4*g+3]};
        float4 v4 = {nv[4*g+0], nv[4*g+1], nv[4*g+2], nv[4*g+3]};
        *(float4*)&wkout[seg * 16 + 4 * g] = k4;
        *(float4*)&u0out[seg * 16 + 4 * g] = v4;
      }
    } else if (wave > k) {
      // Y_i -= M_ik * Y_k   (== A_ik * X_k)
      int mi = wave * (wave - 1) / 2 + k;
      #pragma unroll
      for (int i = 0; i < 16; i++) {
        float mc = Msh[mi][r][i];
        #pragma unroll
        for (int g = 0; g < 4; g++) {
          float4 yk = *(float4*)&Xsh[i][seg * 16 + 4 * g];
          float4 yv = *(float4*)&Xsh[i][64 + seg * 16 + 4 * g];
          xk[4*g+0] -= mc * yk.x; xk[4*g+1] -= mc * yk.y;
          xk[4*g+2] -= mc * yk.z; xk[4*g+3] -= mc * yk.w;
          xv[4*g+0] -= mc * yv.x; xv[4*g+1] -= mc * yv.y;
          xv[4*g+2] -= mc * yv.z; xv[4*g+3] -= mc * yv.w;
        }
      }
    }
    __syncthreads();
  }
}

// prep2a: L = tril(Q K^T) (incl diagonal); Ksh chunk-swizzled like before
__global__ __launch_bounds__(256) void prep2a_kernel(
    const float* __restrict__ qn, const float* __restrict__ kn,
    float* __restrict__ Lbuf) {
  __shared__ float Qsh[64][68];
  __shared__ float Ksh[64][68];   // swizzled
  int ch = blockIdx.x;
  int b = ch >> 9, h = (ch >> 5) & 15, c = ch & 31;
  int tid = threadIdx.x;
  int t = tid >> 2, seg = tid & 3;
  const float* qrow = qn + ((size_t)(b * T_ + c * 64 + t)) * D_ + h * 64;
  const float* krow = kn + ((size_t)(b * T_ + c * 64 + t)) * D_ + h * 64;
  #pragma unroll
  for (int g = 0; g < 4; g++) {
    *(float4*)&Qsh[t][seg * 16 + 4 * g] = *(const float4*)&qrow[seg * 16 + 4 * g];
    *(float4*)&Ksh[t][ksw(t, seg * 4 + g)] = *(const float4*)&krow[seg * 16 + 4 * g];
  }
  __syncthreads();
  int s0 = seg * 16;
  float acc[16];
  #pragma unroll
  for (int r = 0; r < 16; r++) acc[r] = 0.f;
  for (int d4 = 0; d4 < 16; d4++) {
    float4 qt = *(float4*)&Qsh[t][d4 * 4];
    #pragma unroll
    for (int r = 0; r < 16; r++) {
      float4 ks = *(float4*)&Ksh[s0 + r][((d4 ^ seg) << 2)];
      acc[r] += qt.x * ks.x + qt.y * ks.y + qt.z * ks.z + qt.w * ks.w;
    }
  }
  #pragma unroll
  for (int g = 0; g < 4; g++) {
    float4 ov;
    ov.x = (s0 + 4*g + 0 <= t) ? acc[4*g+0] : 0.f;
    ov.y = (s0 + 4*g + 1 <= t) ? acc[4*g+1] : 0.f;
    ov.z = (s0 + 4*g + 2 <= t) ? acc[4*g+2] : 0.f;
    ov.w = (s0 + 4*g + 3 <= t) ? acc[4*g+3] : 0.f;
    *(float4*)&Lbuf[(size_t)ch * 4096 + t * 64 + s0 + 4 * g] = ov;
  }
}

// prep2b: O0 = L U0 ; Qeff = Q - L Wk (in-place over qn)
__global__ __launch_bounds__(256) void prep2b_kernel(
    const float* __restrict__ Lbuf, const float* __restrict__ Wkbuf,
    const float* __restrict__ U0buf, float* qn,
    float* __restrict__ O0buf) {
  __shared__ float Lsh[64][68];
  __shared__ float Wksh[64][68];
  __shared__ float U0sh[64][68];
  int ch = blockIdx.x;
  int b = ch >> 9, h = (ch >> 5) & 15, c = ch & 31;
  int tid = threadIdx.x;
  int t = tid >> 2, seg = tid & 3;
  #pragma unroll
  for (int g = 0; g < 4; g++) {
    int o = t * 64 + seg * 16 + 4 * g;
    *(float4*)&Lsh[t][seg * 16 + 4 * g]  = *(const float4*)&Lbuf[(size_t)ch * 4096 + o];
    *(float4*)&Wksh[t][seg * 16 + 4 * g] = *(const float4*)&Wkbuf[(size_t)ch * 4096 + o];
    *(float4*)&U0sh[t][seg * 16 + 4 * g] = *(const float4*)&U0buf[(size_t)ch * 4096 + o];
  }
  __syncthreads();
  int j0 = seg * 16;
  float o0[16], lw[16];
  #pragma unroll
  for (int r = 0; r < 16; r++) { o0[r] = 0.f; lw[r] = 0.f; }
  for (int s = 0; s <= t; s++) {
    float l = Lsh[t][s];
    #pragma unroll
    for (int g = 0; g < 4; g++) {
      float4 u = *(float4*)&U0sh[s][j0 + 4 * g];
      float4 w = *(float4*)&Wksh[s][j0 + 4 * g];
      o0[4*g+0] += l * u.x; o0[4*g+1] += l * u.y; o0[4*g+2] += l * u.z; o0[4*g+3] += l * u.w;
      lw[4*g+0] += l * w.x; lw[4*g+1] += l * w.y; lw[4*g+2] += l * w.z; lw[4*g+3] += l * w.w;
    }
  }
  float* qrow = qn + ((size_t)(b * T_ + c * 64 + t)) * D_ + h * 64;
  #pragma unroll
  for (int g = 0; g < 4; g++) {
    float4 qv = *(const float4*)&qrow[j0 + 4 * g];
    qv.x -= lw[4*g+0]; qv.y -= lw[4*g+1]; qv.z -= lw[4*g+2]; qv.w -= lw[4*g+3];
    *(float4*)&qrow[j0 + 4 * g] = qv;
    float4 ov = {o0[4*g+0], o0[4*g+1], o0[4*g+2], o0[4*g+3]};
    *(float4*)&O0buf[(size_t)ch * 4096 + t * 64 + j0 + 4 * g] = ov;
  }
}

// prep2c: P[d][e] = I - (K^T Wk)[d][e], stored SLOT-MAJOR for state_kernel:
//         float4 #(f*64+d) of chunk = P[d][4f..4f+3]  (so a wave reading slot f,
//         all rows d, is one contiguous 1KB block).
//         Zt[j][d] = (U0^T K)[j][d] -> kn rows j (coalesced), unchanged.
__global__ __launch_bounds__(256) void prep2c_kernel(
    float* kn, const float* __restrict__ Wkbuf,
    const float* __restrict__ U0buf, float* __restrict__ Pbuf) {
  __shared__ float Ksh[64][68];
  __shared__ float Wksh[64][68];
  __shared__ float U0sh[64][68];
  int ch = blockIdx.x;
  int b = ch >> 9, h = (ch >> 5) & 15, c = ch & 31;
  int tid = threadIdx.x;
  int t = tid >> 2, seg = tid & 3;   // t = output row (d for P, j for Zt)
  const float* krow = kn + ((size_t)(b * T_ + c * 64 + t)) * D_ + h * 64;
  #pragma unroll
  for (int g = 0; g < 4; g++) {
    int o = t * 64 + seg * 16 + 4 * g;
    *(float4*)&Ksh[t][seg * 16 + 4 * g]  = *(const float4*)&krow[seg * 16 + 4 * g];
    *(float4*)&Wksh[t][seg * 16 + 4 * g] = *(const float4*)&Wkbuf[(size_t)ch * 4096 + o];
    *(float4*)&U0sh[t][seg * 16 + 4 * g] = *(const float4*)&U0buf[(size_t)ch * 4096 + o];
  }
  __syncthreads();
  int d0 = seg * 16;
  float accP[16], accZ[16];
  #pragma unroll
  for (int r = 0; r < 16; r++) { accP[r] = 0.f; accZ[r] = 0.f; }
  for (int s = 0; s < 64; s++) {
    float kt = Ksh[s][t];    // scalar for P row d=t
    float u  = U0sh[s][t];   // scalar for Z row j=t
    #pragma unroll
    for (int g = 0; g < 4; g++) {
      float4 w4 = *(float4*)&Wksh[s][d0 + 4 * g];
      float4 k4 = *(float4*)&Ksh[s][d0 + 4 * g];
      accP[4*g+0] += kt * w4.x; accP[4*g+1] += kt * w4.y; accP[4*g+2] += kt * w4.z; accP[4*g+3] += kt * w4.w;
      accZ[4*g+0] += u * k4.x;  accZ[4*g+1] += u * k4.y;  accZ[4*g+2] += u * k4.z;  accZ[4*g+3] += u * k4.w;
    }
  }
  float* zrow = kn + ((size_t)(b * T_ + c * 64 + t)) * D_ + h * 64;
  #pragma unroll
  for (int g = 0; g < 4; g++) {
    float4 pv;
    pv.x = ((d0 + 4*g + 0) == t ? 1.f : 0.f) - accP[4*g+0];
    pv.y = ((d0 + 4*g + 1) == t ? 1.f : 0.f) - accP[4*g+1];
    pv.z = ((d0 + 4*g + 2) == t ? 1.f : 0.f) - accP[4*g+2];
    pv.w = ((d0 + 4*g + 3) == t ? 1.f : 0.f) - accP[4*g+3];
    // slot-major: slot f = seg*4+g, row d = t
    *(float4*)&Pbuf[(size_t)ch * 4096 + (size_t)(seg * 4 + g) * 256 + (size_t)t * 4] = pv;
    float4 zv = {accZ[4*g+0], accZ[4*g+1], accZ[4*g+2], accZ[4*g+3]};
    *(float4*)&zrow[d0 + 4 * g] = zv;
  }
}

// ---------- state scan: S_{c+1} = P_c S_c + Z_c; Sbuf transposed [ch][j][d] ----------
// 512 blocks = (bh, js), 256 threads = 4 waves; wave wv owns single column
// j0 = js*4 + wv; lane = d holds S[j0][d]. P_c staged ONCE per block into LDS
// (slot-major -> conflict-free contiguous b128 reads), double-buffered; the 4
// waves share it -> same L2 traffic as the 1-wave version but 2048 waves total
// (2 waves/SIMD) so ds_read/barrier stalls overlap across waves. One
// __syncthreads per chunk (its implicit vmcnt drain covers staging visibility).
// bh = bid&31 so the 16 block-sharers of a (b,h) land on the same XCD.
__global__ __launch_bounds__(256) void state_kernel(
    const float* __restrict__ kn /*Zt*/, const float* __restrict__ Pbuf /*slot-major*/,
    float* __restrict__ Sbuf) {
  __shared__ __align__(16) float Pl[2][4096];
  int bid = blockIdx.x;
  int bh = bid & 31, js = bid >> 5;
  int h = bh & 15, b = bh >> 4;
  int tid = threadIdx.x;
  int wv = tid >> 6, lane = tid & 63;   // lane = d
  int j0 = js * 4 + wv;                 // this wave's column
  float s0 = 0.f;
  const size_t bhNC = (size_t)bh * NC_;
  // prologue: stage P_0 into buf0 (256 threads x 16B x 4 passes = 16KB), load Z_0
  const float* Pg0 = Pbuf + bhNC * 4096;
  #pragma unroll
  for (int g = 0; g < 4; g++)
    __builtin_amdgcn_global_load_lds(
        (const __attribute__((address_space(1))) void*)(Pg0 + (g * 256 + tid) * 4),
        (__attribute__((address_space(3))) void*)&Pl[0][(g * 256 + tid) * 4], 16, 0, 0);
  float zn = kn[((size_t)(b * T_ + j0)) * D_ + h * 64 + lane];
  int cur = 0;
  #pragma unroll 1
  for (int c = 0; c < NC_; c++) {
    __syncthreads();            // implies vmcnt(0) drain: buf[cur] ready for all waves
    float z = zn;
    size_t ch = bhNC + c;
    // issue next-chunk staging into the other buffer + Z prefetch
    if (c + 1 < NC_) {
      const float* Pg = Pbuf + (ch + 1) * 4096;
      #pragma unroll
      for (int g = 0; g < 4; g++)
        __builtin_amdgcn_global_load_lds(
            (const __attribute__((address_space(1))) void*)(Pg + (g * 256 + tid) * 4),
            (__attribute__((address_space(3))) void*)&Pl[cur ^ 1][(g * 256 + tid) * 4], 16, 0, 0);
      zn = kn[((size_t)(b * T_ + (c + 1) * 64 + j0)) * D_ + h * 64 + lane];
    }
    // store S_c (pre-update), coalesced 256B per wave
    Sbuf[ch * 4096 + (size_t)j0 * 64 + lane] = s0;
    // S_{c+1}[j0][d=lane] = Z[j0][d] + sum_e P[d][e] * S_c[j0][e]
    float acc = z;
    #pragma unroll
    for (int f = 0; f < 16; f++) {
      floatx4 pv = *(floatx4*)&Pl[cur][f * 256 + lane * 4];
      acc += pv.x * rdlane(s0, f * 4 + 0);
      acc += pv.y * rdlane(s0, f * 4 + 1);
      acc += pv.z * rdlane(s0, f * 4 + 2);
      acc += pv.w * rdlane(s0, f * 4 + 3);
    }
    s0 = acc;
    cur ^= 1;
  }
}

// ---------- O = O0 + Qeff*S_c (S transposed layout), fused RMSNorm + bf16 cast ----------
__global__ __launch_bounds__(256) void ophase_kernel(
    const float* __restrict__ qn /*Qeff*/, const float* __restrict__ Sbuf,
    const float* __restrict__ O0buf, const float* __restrict__ rms_g,
    ushort* __restrict__ ob) {
  __shared__ float Ssht[64][68];
  __shared__ float QshT[64][65];
  __shared__ float part[64][4];
  int ch = blockIdx.x;
  int b = ch >> 9, h = (ch >> 5) & 15, c = ch & 31;
  int tid = threadIdx.x;
  int t = tid & 63, jg = tid >> 6;
  #pragma unroll
  for (int g = 0; g < 4; g++) {
    int idx = tid + g * 256;
    *(float4*)&Ssht[idx >> 4][(idx & 15) * 4] =
        *(const float4*)&Sbuf[(size_t)ch * 4096 + (size_t)idx * 4];
  }
  #pragma unroll
  for (int g = 0; g < 4; g++) {
    int idx = tid + g * 256;
    int row = idx >> 4, c4 = idx & 15;
    float4 qv = *(const float4*)&qn[((size_t)(b * T_ + c * 64 + row)) * D_ + h * 64 + c4 * 4];
    QshT[c4 * 4 + 0][row] = qv.x;
    QshT[c4 * 4 + 1][row] = qv.y;
    QshT[c4 * 4 + 2][row] = qv.z;
    QshT[c4 * 4 + 3][row] = qv.w;
  }
  float o[16];
  #pragma unroll
  for (int g = 0; g < 4; g++) {
    float4 o4 = *(const float4*)&O0buf[(size_t)ch * 4096 + t * 64 + jg * 16 + g * 4];
    o[4*g+0] = o4.x; o[4*g+1] = o4.y; o[4*g+2] = o4.z; o[4*g+3] = o4.w;
  }
  __syncthreads();
  for (int d4 = 0; d4 < 16; d4++) {
    float q0 = QshT[d4 * 4 + 0][t];
    float q1 = QshT[d4 * 4 + 1][t];
    float q2 = QshT[d4 * 4 + 2][t];
    float q3 = QshT[d4 * 4 + 3][t];
    #pragma unroll
    for (int r = 0; r < 16; r++) {
      float4 s4 = *(float4*)&Ssht[jg * 16 + r][d4 * 4];
      o[r] += q0 * s4.x + q1 * s4.y + q2 * s4.z + q3 * s4.w;
    }
  }
  float ss = 0.f;
  #pragma unroll
  for (int r = 0; r < 16; r++) ss += o[r] * o[r];
  part[t][jg] = ss;
  __syncthreads();
  float tot = part[t][0] + part[t][1] + part[t][2] + part[t][3];
  float sc = rsqrtf(tot * (1.f / 64.f) + 1e-6f);
  ushort* orow = &ob[((size_t)(b * T_ + c * 64 + t)) * D_ + h * 64];
  #pragma unroll
  for (int g = 0; g < 4; g++) {
    float4 g4 = *(const float4*)&rms_g[jg * 16 + g * 4];
    ushort4 r4;
    r4.x = f2bf(o[4*g+0] * sc * g4.x); r4.y = f2bf(o[4*g+1] * sc * g4.y);
    r4.z = f2bf(o[4*g+2] * sc * g4.z); r4.w = f2bf(o[4*g+3] * sc * g4.w);
    *(ushort4*)&orow[jg * 16 + g * 4] = r4;
  }
}

extern "C" void kernel_launch(void* const* d_in, const int* in_sizes, int n_in,
                              void* d_out, int out_size, void* d_ws, size_t ws_size,
                              hipStream_t stream) {
  const float* x  = (const float*)d_in[0];
  const float* Wq = (const float*)d_in[1];
  const float* Wk = (const float*)d_in[2];
  const float* Wv = (const float*)d_in[3];
  const float* Wb = (const float*)d_in[4];
  const float* cq = (const float*)d_in[5];
  const float* ck = (const float*)d_in[6];
  const float* cv = (const float*)d_in[7];
  const float* rg = (const float*)d_in[8];
  const float* Wo = (const float*)d_in[9];
  float* out = (float*)d_out;
  char* ws = (char*)d_ws;
  const size_t MiB = 1ull << 20;
  ushort* xb   = (ushort*)(ws + 0);         // dead after QKV gemm
  ushort* Wqt  = (ushort*)(ws + 8 * MiB);   // Wqt/Wkt/Wvt contiguous = [3072][1024] bf16
  ushort* Wkt  = (ushort*)(ws + 10 * MiB);
  ushort* Wvt  = (ushort*)(ws + 12 * MiB);
  ushort* Wot  = (ushort*)(ws + 14 * MiB);  // live to end
  float* qkv   = (float*)(ws + 16 * MiB);   // [4096][3072] fp32, dead after conv
  float* qn    = (float*)(ws + 64 * MiB);   // then Qeff in-place
  float* kn    = (float*)(ws + 80 * MiB);   // then Zt in-place
  float* vn    = (float*)(ws + 96 * MiB);   // dead after prep1
  float* beta  = (float*)(ws + 112 * MiB);  // 256 KiB
  float* WbT   = (float*)(ws + 112 * MiB + 256 * 1024);  // 64 KiB
  float* Wkbuf = (float*)(ws + 16 * MiB);   // over qkv (dead after conv)
  float* U0buf = (float*)(ws + 32 * MiB);
  float* Lbuf  = (float*)(ws + 48 * MiB);   // later P
  float* O0buf = (float*)(ws + 96 * MiB);   // over vn (after prep1)
  float* Sbuf  = (float*)(ws + 16 * MiB);   // over Wkbuf (dead after prep2c)
  ushort* ob   = (ushort*)(ws + 0);         // over xb (after QKV gemm)

  hipLaunchKernelGGL(cast_kernel, dim3(M_ * D_ / 4 / 256), dim3(256), 0, stream,
                     x, xb, M_ * D_ / 4);
  dim3 tb(32, 8);
  hipLaunchKernelGGL(transpose_cast_kernel, dim3(32, 32), tb, 0, stream, Wq, Wqt, D_, D_);
  hipLaunchKernelGGL(transpose_cast_kernel, dim3(32, 32), tb, 0, stream, Wk, Wkt, D_, D_);
  hipLaunchKernelGGL(transpose_cast_kernel, dim3(32, 32), tb, 0, stream, Wv, Wvt, D_, D_);
  hipLaunchKernelGGL(transpose_cast_kernel, dim3(32, 32), tb, 0, stream, Wo, Wot, D_, D_);
  hipLaunchKernelGGL(transpose_wb_kernel, dim3(64), dim3(256), 0, stream, Wb, WbT);

  hipLaunchKernelGGL(gemm128_kernel, dim3(M_ / 128, QKVN_ / 128), dim3(256), 0, stream,
                     xb, Wqt, qkv, M_, QKVN_, D_);

  hipLaunchKernelGGL(beta_kernel, dim3(M_), dim3(256), 0, stream, x, WbT, beta);
  hipLaunchKernelGGL(conv_kernel, dim3(M_), dim3(256), 0, stream,
                     qkv, cq, ck, cv, qn, kn, vn);

  hipLaunchKernelGGL(prep1_kernel, dim3(NCH_), dim3(256), 0, stream,
                     kn, vn, beta, Wkbuf, U0buf);
  hipLaunchKernelGGL(prep2a_kernel, dim3(NCH_), dim3(256), 0, stream, qn, kn, Lbuf);
  hipLaunchKernelGGL(prep2b_kernel, dim3(NCH_), dim3(256), 0, stream,
                     Lbuf, Wkbuf, U0buf, qn, O0buf);
  hipLaunchKernelGGL(prep2c_kernel, dim3(NCH_), dim3(256), 0, stream,
                     kn, Wkbuf, U0buf, Lbuf);
  hipLaunchKernelGGL(state_kernel, dim3(512), dim3(256), 0, stream,
                     kn, Lbuf, Sbuf);
  hipLaunchKernelGGL(ophase_kernel, dim3(NCH_), dim3(256), 0, stream,
                     qn, Sbuf, O0buf, rg, ob);
  hipLaunchKernelGGL(gemm128_kernel, dim3(M_ / 128, D_ / 128), dim3(256), 0, stream,
                     ob, Wot, out, M_, D_, D_);
}

// Round 6
// 397.606 us; speedup vs baseline: 1.1277x; 1.0030x over previous
//
#include <hip/hip_runtime.h>
#include <hip/hip_bf16.h>
#include <math.h>

#define B_ 2
#define T_ 2048
#define D_ 1024
#define H_ 16
#define DH_ 64
#define M_ (B_*T_)   // 4096 rows
#define NC_ 32       // chunks per sequence (T/64)
#define CS_ 64       // chunk size
#define NCH_ (B_*H_*NC_)  // 1024 chunk-heads
#define QKVN_ 3072   // fused QKV gemm N

typedef __attribute__((ext_vector_type(4))) float floatx4;
typedef __attribute__((ext_vector_type(8))) short short8;

__device__ __forceinline__ ushort f2bf(float f) {
  union { float f; unsigned u; } c; c.f = f;
  unsigned r = (c.u + 0x7FFFu + ((c.u >> 16) & 1u)) >> 16;  // RNE
  return (ushort)r;
}
__device__ __forceinline__ float siluf(float u) {
  return u / (1.f + __expf(-u));
}
__device__ __forceinline__ float f4get(const float4& v, int j) {
  return j == 0 ? v.x : j == 1 ? v.y : j == 2 ? v.z : v.w;
}
__device__ __forceinline__ float rdlane(float v, int l) {
  return __int_as_float(__builtin_amdgcn_readlane(__float_as_int(v), l));
}
// swizzled chunk index for K tiles: chunk c (0..15) of row r stored at c ^ (r>>4)
__device__ __forceinline__ int ksw(int r, int c) { return ((c ^ (r >> 4)) << 2); }

// ---------- cast f32 -> bf16, n4 = n/4 ----------
__global__ void cast_kernel(const float* __restrict__ in, ushort* __restrict__ out, int n4) {
  int i = blockIdx.x * blockDim.x + threadIdx.x;
  if (i >= n4) return;
  float4 v = ((const float4*)in)[i];
  ushort4 o;
  o.x = f2bf(v.x); o.y = f2bf(v.y); o.z = f2bf(v.z); o.w = f2bf(v.w);
  ((ushort4*)out)[i] = o;
}

// ---------- transpose + cast: W[K][N] f32 -> Wt[N][K] bf16 ----------
__global__ void transpose_cast_kernel(const float* __restrict__ W, ushort* __restrict__ Wt,
                                      int K, int N) {
  __shared__ float tile[32][33];
  int tx = threadIdx.x, ty = threadIdx.y;
  int n0 = blockIdx.x * 32, k0 = blockIdx.y * 32;
  #pragma unroll
  for (int i = 0; i < 32; i += 8)
    tile[ty + i][tx] = W[(size_t)(k0 + ty + i) * N + n0 + tx];
  __syncthreads();
  #pragma unroll
  for (int i = 0; i < 32; i += 8)
    Wt[(size_t)(n0 + ty + i) * K + k0 + tx] = f2bf(tile[tx][ty + i]);
}

// ---------- transpose Wb[1024][16] -> WbT[16][1024] (fp32) ----------
__global__ void transpose_wb_kernel(const float* __restrict__ Wb, float* __restrict__ WbT) {
  int bk = blockIdx.x;
  int tid = threadIdx.x;
  int kl = tid >> 4, h = tid & 15;
  int k = bk * 16 + kl;
  WbT[(size_t)h * D_ + k] = Wb[(size_t)k * H_ + h];
}

// ---------- m97-style bf16 MFMA GEMM: C[M][N] = A[M][K]*B[K][N], Bt = B^T [N][K] ----------
__global__ __launch_bounds__(256) void gemm128_kernel(
    const ushort* __restrict__ A, const ushort* __restrict__ Bt,
    float* __restrict__ C, int M, int N, int K) {
  __shared__ ushort lA[128 * 32];
  __shared__ ushort lB[128 * 32];
  int tid = threadIdx.x;
  int wave = tid >> 6, lane = tid & 63;
  int wm = wave >> 1, wn = wave & 1;
  int m16 = lane & 15, q4 = lane >> 4;
  int bm = blockIdx.x, bn = blockIdx.y;
  floatx4 acc[4][4] = {};
  int srow = tid >> 2;
  int sk8 = tid & 3;
  const ushort* Ag = A + (size_t)(bm * 128 + srow) * K + sk8 * 8;
  const ushort* Bg = Bt + (size_t)(bn * 128 + srow) * K + sk8 * 8;
  ushort* lAp = lA + tid * 8;
  ushort* lBp = lB + tid * 8;
  for (int k0 = 0; k0 < K; k0 += 32) {
    __builtin_amdgcn_global_load_lds(
        (const __attribute__((address_space(1))) void*)(Ag + k0),
        (__attribute__((address_space(3))) void*)lAp, 16, 0, 0);
    __builtin_amdgcn_global_load_lds(
        (const __attribute__((address_space(1))) void*)(Ag + (size_t)64 * K + k0),
        (__attribute__((address_space(3))) void*)(lAp + 2048), 16, 0, 0);
    __builtin_amdgcn_global_load_lds(
        (const __attribute__((address_space(1))) void*)(Bg + k0),
        (__attribute__((address_space(3))) void*)lBp, 16, 0, 0);
    __builtin_amdgcn_global_load_lds(
        (const __attribute__((address_space(1))) void*)(Bg + (size_t)64 * K + k0),
        (__attribute__((address_space(3))) void*)(lBp + 2048), 16, 0, 0);
    __syncthreads();
    short8 af[4], bf[4];
    #pragma unroll
    for (int i = 0; i < 4; i++) {
      af[i] = *(short8*)&lA[(wm * 64 + i * 16 + m16) * 32 + q4 * 8];
      bf[i] = *(short8*)&lB[(wn * 64 + i * 16 + m16) * 32 + q4 * 8];
    }
    #pragma unroll
    for (int mi = 0; mi < 4; mi++)
      #pragma unroll
      for (int nj = 0; nj < 4; nj++)
        acc[mi][nj] = __builtin_amdgcn_mfma_f32_16x16x32_bf16(af[mi], bf[nj], acc[mi][nj], 0, 0, 0);
    __syncthreads();
  }
  float* Cb = C + (size_t)(bm * 128) * N + bn * 128;
  #pragma unroll
  for (int mi = 0; mi < 4; mi++) {
    #pragma unroll
    for (int nj = 0; nj < 4; nj++) {
      #pragma unroll
      for (int i = 0; i < 4; i++) {
        int row = wm * 64 + mi * 16 + q4 * 4 + i;
        int col = wn * 64 + nj * 16 + m16;
        Cb[(size_t)row * N + col] = acc[mi][nj][i];
      }
    }
  }
}

// ---------- beta = sigmoid(x @ Wb), WbT[16][1024], conflict-free ----------
__global__ __launch_bounds__(256) void beta_kernel(const float* __restrict__ x,
                                                   const float* __restrict__ WbT,
                                                   float* __restrict__ beta) {
  __shared__ __align__(16) float xs[D_];
  int row = blockIdx.x;
  int tid = threadIdx.x;
  ((float4*)xs)[tid] = ((const float4*)(x + (size_t)row * D_))[tid];
  __syncthreads();
  int h = tid >> 4;
  int seg = tid & 15;
  const float4* wrow = (const float4*)(WbT + (size_t)h * D_) + seg * 16;
  const float4* xsrow = (const float4*)xs + seg * 16;
  float s = 0.f;
  #pragma unroll
  for (int j = 0; j < 16; j++) {
    int jj = (j + seg) & 15;
    float4 xv = xsrow[jj];
    float4 wv = wrow[jj];
    s += xv.x * wv.x + xv.y * wv.y + xv.z * wv.z + xv.w * wv.w;
  }
  #pragma unroll
  for (int off = 8; off; off >>= 1) s += __shfl_down(s, off, 16);
  if (seg == 0) beta[(size_t)row * H_ + h] = 1.f / (1.f + __expf(-s));
}

// ---------- causal depthwise conv(K=4) + silu, l2norm for q,k ----------
__global__ __launch_bounds__(256) void conv_kernel(
    const float* __restrict__ qkv,
    const float* __restrict__ cq, const float* __restrict__ ck, const float* __restrict__ cv,
    float* __restrict__ qo, float* __restrict__ ko, float* __restrict__ vo) {
  int row = blockIdx.x;
  int t = row & (T_ - 1);
  int tid = threadIdx.x;
  int c0 = tid * 4;
  float4 zf = {0.f, 0.f, 0.f, 0.f};
  float4 xq[4], xk[4], xv[4];
  #pragma unroll
  for (int i = 0; i < 4; i++) {
    int tt = t - 3 + i;
    if (tt >= 0) {
      const float* rp = qkv + (size_t)(row - 3 + i) * QKVN_;
      xq[i] = *(const float4*)(rp + c0);
      xk[i] = *(const float4*)(rp + 1024 + c0);
      xv[i] = *(const float4*)(rp + 2048 + c0);
    } else { xq[i] = zf; xk[i] = zf; xv[i] = zf; }
  }
  float yq[4], yk[4], yv[4];
  float pq = 0.f, pk = 0.f;
  #pragma unroll
  for (int j = 0; j < 4; j++) {
    float4 wq = ((const float4*)cq)[c0 + j];
    float4 wk = ((const float4*)ck)[c0 + j];
    float4 wv = ((const float4*)cv)[c0 + j];
    float sq = 0.f, sk = 0.f, sv = 0.f;
    #pragma unroll
    for (int i = 0; i < 4; i++) {
      sq += f4get(wq, i) * f4get(xq[i], j);
      sk += f4get(wk, i) * f4get(xk[i], j);
      sv += f4get(wv, i) * f4get(xv[i], j);
    }
    yq[j] = siluf(sq); yk[j] = siluf(sk); yv[j] = siluf(sv);
    pq += yq[j] * yq[j]; pk += yk[j] * yk[j];
  }
  #pragma unroll
  for (int off = 1; off < 16; off <<= 1) {
    pq += __shfl_xor(pq, off, 16);
    pk += __shfl_xor(pk, off, 16);
  }
  float rq = rsqrtf(pq + 1e-6f), rk = rsqrtf(pk + 1e-6f);
  float4 oq = {yq[0]*rq, yq[1]*rq, yq[2]*rq, yq[3]*rq};
  float4 okk = {yk[0]*rk, yk[1]*rk, yk[2]*rk, yk[3]*rk};
  float4 ov = {yv[0], yv[1], yv[2], yv[3]};
  *(float4*)(qo + (size_t)row * D_ + c0) = oq;
  *(float4*)(ko + (size_t)row * D_ + c0) = okk;
  *(float4*)(vo + (size_t)row * D_ + c0) = ov;
}

// ================= chunked delta rule =================
// prep1: A = strict_tril(diag(b)KK^T); solve (I+A)Wk = diag(b)K and (I+A)U0 = diag(b)V
// Blocked forward substitution (R3-verified version):
//   Phase A: each wave w inverts its 16x16 diag block T_ww = (I+A_ww)^-1  (parallel)
//   Phase B: wave w precomputes M_wk = A_wk * T_kk for k<w  (off critical path)
//   k-loop (4 steps): wave k publishes residual Y_k once; wave k applies T_kk*Y_k
//   (final output -> global), waves i>k apply Y_i -= M_ik*Y_k, all concurrently.
__global__ __launch_bounds__(256) void prep1_kernel(
    const float* __restrict__ kn, const float* __restrict__ vn,
    const float* __restrict__ beta,
    float* __restrict__ Wkbuf, float* __restrict__ U0buf) {
  __shared__ __align__(16) float Ash[64 * 68];   // A[t][s] row-major, stride 68
  __shared__ float bsh[64];
  // union region: Ksh (during A compute) aliased with Tsh/Msh/Xsh (after)
  __shared__ __align__(16) float uni[5312];
  float (*Ksh)[68] = (float (*)[68])uni;                    // 64x68 = 4352 floats
  float (*Tsh)[16][20] = (float (*)[16][20])uni;            // [4][16][20] = 1280
  float (*Msh)[16][20] = (float (*)[16][20])(uni + 1280);   // [6][16][20] = 1920
  float (*Xsh)[132] = (float (*)[132])(uni + 3200);         // [16][132]  = 2112

  int ch = blockIdx.x;
  int b = ch >> 9, h = (ch >> 5) & 15, c = ch & 31;
  int tid = threadIdx.x;
  int t = tid >> 2, seg = tid & 3;
  int wave = tid >> 6, lane = tid & 63;
  int r = lane >> 2, q = lane & 3;   // r == t&15, q == seg
  const float* krow = kn + ((size_t)(b * T_ + c * 64 + t)) * D_ + h * 64;
  #pragma unroll
  for (int g = 0; g < 4; g++)
    *(float4*)&Ksh[t][ksw(t, seg * 4 + g)] = *(const float4*)&krow[seg * 16 + 4 * g];
  if (tid < 64) bsh[tid] = beta[((size_t)(b * T_ + c * 64 + tid)) * H_ + h];
  __syncthreads();
  // A[t][s] = (t>s) ? b_t * (k_t . k_s) : 0
  {
    int s0 = seg * 16;
    float acc[16];
    #pragma unroll
    for (int rr = 0; rr < 16; rr++) acc[rr] = 0.f;
    for (int d4 = 0; d4 < 16; d4++) {
      float4 kt = *(float4*)&Ksh[t][ksw(t, d4)];
      #pragma unroll
      for (int rr = 0; rr < 16; rr++) {
        float4 ks = *(float4*)&Ksh[s0 + rr][((d4 ^ seg) << 2)];   // (s0+rr)>>4 == seg
        acc[rr] += kt.x * ks.x + kt.y * ks.y + kt.z * ks.z + kt.w * ks.w;
      }
    }
    float bt = bsh[t];
    #pragma unroll
    for (int g = 0; g < 4; g++) {
      float4 a4;
      a4.x = (t > s0 + 4*g + 0) ? bt * acc[4*g+0] : 0.f;
      a4.y = (t > s0 + 4*g + 1) ? bt * acc[4*g+1] : 0.f;
      a4.z = (t > s0 + 4*g + 2) ? bt * acc[4*g+2] : 0.f;
      a4.w = (t > s0 + 4*g + 3) ? bt * acc[4*g+3] : 0.f;
      *(float4*)&Ash[t * 68 + s0 + 4 * g] = a4;
    }
  }
  // RHS (residual Y) in registers: row t, 16 K-cols + 16 V-cols
  float xk[16], xv[16];
  {
    float bt = bsh[t];
    const float* vrow = vn + ((size_t)(b * T_ + c * 64 + t)) * D_ + h * 64;
    #pragma unroll
    for (int g = 0; g < 4; g++) {
      float4 kv = *(float4*)&Ksh[t][ksw(t, seg * 4 + g)];
      float4 vv = *(const float4*)&vrow[seg * 16 + 4 * g];
      xk[4*g+0] = bt * kv.x; xk[4*g+1] = bt * kv.y; xk[4*g+2] = bt * kv.z; xk[4*g+3] = bt * kv.w;
      xv[4*g+0] = bt * vv.x; xv[4*g+1] = bt * vv.y; xv[4*g+2] = bt * vv.z; xv[4*g+3] = bt * vv.w;
    }
  }
  __syncthreads();   // Ash ready; Ksh dead -> Tsh/Msh/Xsh region live
  // Phase A: wave-parallel 16x16 diagonal-block inverse via fwd substitution on I
  {
    float a[16];
    #pragma unroll
    for (int i = 0; i < 16; i++) a[i] = Ash[(wave * 16 + r) * 68 + wave * 16 + i];
    float4 w4 = {0.f, 0.f, 0.f, 0.f};
    if ((r >> 2) == q) ((float*)&w4)[r & 3] = 1.f;
    #pragma unroll
    for (int i = 0; i < 15; i++) {
      int src = i * 4 + q;
      float4 wi;
      wi.x = __shfl(w4.x, src, 64);
      wi.y = __shfl(w4.y, src, 64);
      wi.z = __shfl(w4.z, src, 64);
      wi.w = __shfl(w4.w, src, 64);
      if (r > i) {
        w4.x -= a[i] * wi.x; w4.y -= a[i] * wi.y;
        w4.z -= a[i] * wi.z; w4.w -= a[i] * wi.w;
      }
    }
    *(float4*)&Tsh[wave][r][q * 4] = w4;
  }
  __syncthreads();   // Tsh visible to all waves
  // Phase B: M_wk = A_wk * T_kk (wave-local write, wave-local read)
  for (int k = 0; k < wave; k++) {
    float4 m4 = {0.f, 0.f, 0.f, 0.f};
    #pragma unroll
    for (int i = 0; i < 16; i++) {
      float aik = Ash[(wave * 16 + r) * 68 + k * 16 + i];
      float4 tk = *(float4*)&Tsh[k][i][q * 4];
      m4.x += aik * tk.x; m4.y += aik * tk.y;
      m4.z += aik * tk.z; m4.w += aik * tk.w;
    }
    int mi = wave * (wave - 1) / 2 + k;
    *(float4*)&Msh[mi][r][q * 4] = m4;
  }
  // Block substitution k-loop
  float* wkout = &Wkbuf[(size_t)ch * 4096 + t * 64];
  float* u0out = &U0buf[(size_t)ch * 4096 + t * 64];
  for (int k = 0; k < 4; k++) {
    if (wave == k) {   // publish residual Y_k
      #pragma unroll
      for (int g = 0; g < 4; g++) {
        float4 k4 = {xk[4*g+0], xk[4*g+1], xk[4*g+2], xk[4*g+3]};
        float4 v4 = {xv[4*g+0], xv[4*g+1], xv[4*g+2], xv[4*g+3]};
        *(float4*)&Xsh[r][seg * 16 + 4 * g] = k4;
        *(float4*)&Xsh[r][64 + seg * 16 + 4 * g] = v4;
      }
    }
    __syncthreads();
    if (wave == k) {
      // X_k = T_kk * Y_k -> final output, straight to global
      float nk[16], nv[16];
      #pragma unroll
      for (int i2 = 0; i2 < 16; i2++) { nk[i2] = 0.f; nv[i2] = 0.f; }
      #pragma unroll
      for (int i = 0; i < 16; i++) {
        float tc = Tsh[k][r][i];
        #pragma unroll
        for (int g = 0; g < 4; g++) {
          float4 yk = *(float4*)&Xsh[i][seg * 16 + 4 * g];
          float4 yv = *(float4*)&Xsh[i][64 + seg * 16 + 4 * g];
          nk[4*g+0] += tc * yk.x; nk[4*g+1] += tc * yk.y;
          nk[4*g+2] += tc * yk.z; nk[4*g+3] += tc * yk.w;
          nv[4*g+0] += tc * yv.x; nv[4*g+1] += tc * yv.y;
          nv[4*g+2] += tc * yv.z; nv[4*g+3] += tc * yv.w;
        }
      }
      #pragma unroll
      for (int g = 0; g < 4; g++) {
        float4 k4 = {nk[4*g+0], nk[4*g+1], nk[4*g+2], nk[4*g+3]};
        float4 v4 = {nv[4*g+0], nv[4*g+1], nv[4*g+2], nv[4*g+3]};
        *(float4*)&wkout[seg * 16 + 4 * g] = k4;
        *(float4*)&u0out[seg * 16 + 4 * g] = v4;
      }
    } else if (wave > k) {
      // Y_i -= M_ik * Y_k   (== A_ik * X_k)
      int mi = wave * (wave - 1) / 2 + k;
      #pragma unroll
      for (int i = 0; i < 16; i++) {
        float mc = Msh[mi][r][i];
        #pragma unroll
        for (int g = 0; g < 4; g++) {
          float4 yk = *(float4*)&Xsh[i][seg * 16 + 4 * g];
          float4 yv = *(float4*)&Xsh[i][64 + seg * 16 + 4 * g];
          xk[4*g+0] -= mc * yk.x; xk[4*g+1] -= mc * yk.y;
          xk[4*g+2] -= mc * yk.z; xk[4*g+3] -= mc * yk.w;
          xv[4*g+0] -= mc * yv.x; xv[4*g+1] -= mc * yv.y;
          xv[4*g+2] -= mc * yv.z; xv[4*g+3] -= mc * yv.w;
        }
      }
    }
    __syncthreads();
  }
}

// prep2ab: fused prep2a+prep2b. Phase 1: L = tril(Q K^T) -> Lsh (LDS, no HBM
// roundtrip). Phase 2: reuse Qsh/Ksh LDS space for Wk/U0 staging, then
// O0 = L U0 ; Qeff = Q - L Wk (identical arithmetic order to the old kernels).
// Saves: 32 MB Lbuf HBM roundtrip + one launch + one redundant staging pass.
__global__ __launch_bounds__(256) void prep2ab_kernel(
    float* qn, const float* __restrict__ kn,
    const float* __restrict__ Wkbuf, const float* __restrict__ U0buf,
    float* __restrict__ O0buf) {
  __shared__ float Qsh[64][68];   // phase 2: Wksh
  __shared__ float Ksh[64][68];   // swizzled; phase 2: U0sh
  __shared__ float Lsh[64][68];
  float (*Wksh)[68] = Qsh;
  float (*U0sh)[68] = Ksh;
  int ch = blockIdx.x;
  int b = ch >> 9, h = (ch >> 5) & 15, c = ch & 31;
  int tid = threadIdx.x;
  int t = tid >> 2, seg = tid & 3;
  const float* qrow = qn + ((size_t)(b * T_ + c * 64 + t)) * D_ + h * 64;
  const float* krow = kn + ((size_t)(b * T_ + c * 64 + t)) * D_ + h * 64;
  #pragma unroll
  for (int g = 0; g < 4; g++) {
    *(float4*)&Qsh[t][seg * 16 + 4 * g] = *(const float4*)&qrow[seg * 16 + 4 * g];
    *(float4*)&Ksh[t][ksw(t, seg * 4 + g)] = *(const float4*)&krow[seg * 16 + 4 * g];
  }
  __syncthreads();
  // phase 1: L = tril(Q K^T), written to Lsh
  {
    int s0 = seg * 16;
    float acc[16];
    #pragma unroll
    for (int r = 0; r < 16; r++) acc[r] = 0.f;
    for (int d4 = 0; d4 < 16; d4++) {
      float4 qt = *(float4*)&Qsh[t][d4 * 4];
      #pragma unroll
      for (int r = 0; r < 16; r++) {
        float4 ks = *(float4*)&Ksh[s0 + r][((d4 ^ seg) << 2)];
        acc[r] += qt.x * ks.x + qt.y * ks.y + qt.z * ks.z + qt.w * ks.w;
      }
    }
    #pragma unroll
    for (int g = 0; g < 4; g++) {
      float4 ov;
      ov.x = (s0 + 4*g + 0 <= t) ? acc[4*g+0] : 0.f;
      ov.y = (s0 + 4*g + 1 <= t) ? acc[4*g+1] : 0.f;
      ov.z = (s0 + 4*g + 2 <= t) ? acc[4*g+2] : 0.f;
      ov.w = (s0 + 4*g + 3 <= t) ? acc[4*g+3] : 0.f;
      *(float4*)&Lsh[t][s0 + 4 * g] = ov;
    }
  }
  __syncthreads();   // L done; Qsh/Ksh dead -> stage Wk/U0 into their space
  #pragma unroll
  for (int g = 0; g < 4; g++) {
    int o = t * 64 + seg * 16 + 4 * g;
    *(float4*)&Wksh[t][seg * 16 + 4 * g] = *(const float4*)&Wkbuf[(size_t)ch * 4096 + o];
    *(float4*)&U0sh[t][seg * 16 + 4 * g] = *(const float4*)&U0buf[(size_t)ch * 4096 + o];
  }
  __syncthreads();
  // phase 2: O0 = L U0 ; Qeff = Q - L Wk (identical to old prep2b)
  int j0 = seg * 16;
  float o0[16], lw[16];
  #pragma unroll
  for (int r = 0; r < 16; r++) { o0[r] = 0.f; lw[r] = 0.f; }
  for (int s = 0; s <= t; s++) {
    float l = Lsh[t][s];
    #pragma unroll
    for (int g = 0; g < 4; g++) {
      float4 u = *(float4*)&U0sh[s][j0 + 4 * g];
      float4 w = *(float4*)&Wksh[s][j0 + 4 * g];
      o0[4*g+0] += l * u.x; o0[4*g+1] += l * u.y; o0[4*g+2] += l * u.z; o0[4*g+3] += l * u.w;
      lw[4*g+0] += l * w.x; lw[4*g+1] += l * w.y; lw[4*g+2] += l * w.z; lw[4*g+3] += l * w.w;
    }
  }
  float* qwrow = qn + ((size_t)(b * T_ + c * 64 + t)) * D_ + h * 64;
  #pragma unroll
  for (int g = 0; g < 4; g++) {
    float4 qv = *(const float4*)&qwrow[j0 + 4 * g];
    qv.x -= lw[4*g+0]; qv.y -= lw[4*g+1]; qv.z -= lw[4*g+2]; qv.w -= lw[4*g+3];
    *(float4*)&qwrow[j0 + 4 * g] = qv;
    float4 ov = {o0[4*g+0], o0[4*g+1], o0[4*g+2], o0[4*g+3]};
    *(float4*)&O0buf[(size_t)ch * 4096 + t * 64 + j0 + 4 * g] = ov;
  }
}

// prep2c: P[d][e] = I - (K^T Wk)[d][e], stored SLOT-MAJOR for state_kernel:
//         float4 #(f*64+d) of chunk = P[d][4f..4f+3]  (so a wave reading slot f,
//         all rows d, is one contiguous 1KB block).
//         Zt[j][d] = (U0^T K)[j][d] -> kn rows j (coalesced), unchanged.
__global__ __launch_bounds__(256) void prep2c_kernel(
    float* kn, const float* __restrict__ Wkbuf,
    const float* __restrict__ U0buf, float* __restrict__ Pbuf) {
  __shared__ float Ksh[64][68];
  __shared__ float Wksh[64][68];
  __shared__ float U0sh[64][68];
  int ch = blockIdx.x;
  int b = ch >> 9, h = (ch >> 5) & 15, c = ch & 31;
  int tid = threadIdx.x;
  int t = tid >> 2, seg = tid & 3;   // t = output row (d for P, j for Zt)
  const float* krow = kn + ((size_t)(b * T_ + c * 64 + t)) * D_ + h * 64;
  #pragma unroll
  for (int g = 0; g < 4; g++) {
    int o = t * 64 + seg * 16 + 4 * g;
    *(float4*)&Ksh[t][seg * 16 + 4 * g]  = *(const float4*)&krow[seg * 16 + 4 * g];
    *(float4*)&Wksh[t][seg * 16 + 4 * g] = *(const float4*)&Wkbuf[(size_t)ch * 4096 + o];
    *(float4*)&U0sh[t][seg * 16 + 4 * g] = *(const float4*)&U0buf[(size_t)ch * 4096 + o];
  }
  __syncthreads();
  int d0 = seg * 16;
  float accP[16], accZ[16];
  #pragma unroll
  for (int r = 0; r < 16; r++) { accP[r] = 0.f; accZ[r] = 0.f; }
  for (int s = 0; s < 64; s++) {
    float kt = Ksh[s][t];    // scalar for P row d=t
    float u  = U0sh[s][t];   // scalar for Z row j=t
    #pragma unroll
    for (int g = 0; g < 4; g++) {
      float4 w4 = *(float4*)&Wksh[s][d0 + 4 * g];
      float4 k4 = *(float4*)&Ksh[s][d0 + 4 * g];
      accP[4*g+0] += kt * w4.x; accP[4*g+1] += kt * w4.y; accP[4*g+2] += kt * w4.z; accP[4*g+3] += kt * w4.w;
      accZ[4*g+0] += u * k4.x;  accZ[4*g+1] += u * k4.y;  accZ[4*g+2] += u * k4.z;  accZ[4*g+3] += u * k4.w;
    }
  }
  float* zrow = kn + ((size_t)(b * T_ + c * 64 + t)) * D_ + h * 64;
  #pragma unroll
  for (int g = 0; g < 4; g++) {
    float4 pv;
    pv.x = ((d0 + 4*g + 0) == t ? 1.f : 0.f) - accP[4*g+0];
    pv.y = ((d0 + 4*g + 1) == t ? 1.f : 0.f) - accP[4*g+1];
    pv.z = ((d0 + 4*g + 2) == t ? 1.f : 0.f) - accP[4*g+2];
    pv.w = ((d0 + 4*g + 3) == t ? 1.f : 0.f) - accP[4*g+3];
    // slot-major: slot f = seg*4+g, row d = t
    *(float4*)&Pbuf[(size_t)ch * 4096 + (size_t)(seg * 4 + g) * 256 + (size_t)t * 4] = pv;
    float4 zv = {accZ[4*g+0], accZ[4*g+1], accZ[4*g+2], accZ[4*g+3]};
    *(float4*)&zrow[d0 + 4 * g] = zv;
  }
}

// ---------- state scan: S_{c+1} = P_c S_c + Z_c; Sbuf transposed [ch][j][d] ----------
// 512 blocks = (bh, js), 256 threads = 4 waves; wave wv owns single column
// j0 = js*4 + wv; lane = d holds S[j0][d]. P_c staged ONCE per block into LDS
// (slot-major -> conflict-free contiguous b128 reads), double-buffered; the 4
// waves share it -> same L2 traffic as the 1-wave version but 2048 waves total
// (2 waves/SIMD) so ds_read/barrier stalls overlap across waves. One
// __syncthreads per chunk (its implicit vmcnt drain covers staging visibility).
// bh = bid&31 so the 16 block-sharers of a (b,h) land on the same XCD.
__global__ __launch_bounds__(256) void state_kernel(
    const float* __restrict__ kn /*Zt*/, const float* __restrict__ Pbuf /*slot-major*/,
    float* __restrict__ Sbuf) {
  __shared__ __align__(16) float Pl[2][4096];
  int bid = blockIdx.x;
  int bh = bid & 31, js = bid >> 5;
  int h = bh & 15, b = bh >> 4;
  int tid = threadIdx.x;
  int wv = tid >> 6, lane = tid & 63;   // lane = d
  int j0 = js * 4 + wv;                 // this wave's column
  float s0 = 0.f;
  const size_t bhNC = (size_t)bh * NC_;
  // prologue: stage P_0 into buf0 (256 threads x 16B x 4 passes = 16KB), load Z_0
  const float* Pg0 = Pbuf + bhNC * 4096;
  #pragma unroll
  for (int g = 0; g < 4; g++)
    __builtin_amdgcn_global_load_lds(
        (const __attribute__((address_space(1))) void*)(Pg0 + (g * 256 + tid) * 4),
        (__attribute__((address_space(3))) void*)&Pl[0][(g * 256 + tid) * 4], 16, 0, 0);
  float zn = kn[((size_t)(b * T_ + j0)) * D_ + h * 64 + lane];
  int cur = 0;
  #pragma unroll 1
  for (int c = 0; c < NC_; c++) {
    __syncthreads();            // implies vmcnt(0) drain: buf[cur] ready for all waves
    float z = zn;
    size_t ch = bhNC + c;
    // issue next-chunk staging into the other buffer + Z prefetch
    if (c + 1 < NC_) {
      const float* Pg = Pbuf + (ch + 1) * 4096;
      #pragma unroll
      for (int g = 0; g < 4; g++)
        __builtin_amdgcn_global_load_lds(
            (const __attribute__((address_space(1))) void*)(Pg + (g * 256 + tid) * 4),
            (__attribute__((address_space(3))) void*)&Pl[cur ^ 1][(g * 256 + tid) * 4], 16, 0, 0);
      zn = kn[((size_t)(b * T_ + (c + 1) * 64 + j0)) * D_ + h * 64 + lane];
    }
    // store S_c (pre-update), coalesced 256B per wave
    Sbuf[ch * 4096 + (size_t)j0 * 64 + lane] = s0;
    // S_{c+1}[j0][d=lane] = Z[j0][d] + sum_e P[d][e] * S_c[j0][e]
    float acc = z;
    #pragma unroll
    for (int f = 0; f < 16; f++) {
      floatx4 pv = *(floatx4*)&Pl[cur][f * 256 + lane * 4];
      acc += pv.x * rdlane(s0, f * 4 + 0);
      acc += pv.y * rdlane(s0, f * 4 + 1);
      acc += pv.z * rdlane(s0, f * 4 + 2);
      acc += pv.w * rdlane(s0, f * 4 + 3);
    }
    s0 = acc;
    cur ^= 1;
  }
}

// ---------- O = O0 + Qeff*S_c (S transposed layout), fused RMSNorm + bf16 cast ----------
__global__ __launch_bounds__(256) void ophase_kernel(
    const float* __restrict__ qn /*Qeff*/, const float* __restrict__ Sbuf,
    const float* __restrict__ O0buf, const float* __restrict__ rms_g,
    ushort* __restrict__ ob) {
  __shared__ float Ssht[64][68];
  __shared__ float QshT[64][65];
  __shared__ float part[64][4];
  int ch = blockIdx.x;
  int b = ch >> 9, h = (ch >> 5) & 15, c = ch & 31;
  int tid = threadIdx.x;
  int t = tid & 63, jg = tid >> 6;
  #pragma unroll
  for (int g = 0; g < 4; g++) {
    int idx = tid + g * 256;
    *(float4*)&Ssht[idx >> 4][(idx & 15) * 4] =
        *(const float4*)&Sbuf[(size_t)ch * 4096 + (size_t)idx * 4];
  }
  #pragma unroll
  for (int g = 0; g < 4; g++) {
    int idx = tid + g * 256;
    int row = idx >> 4, c4 = idx & 15;
    float4 qv = *(const float4*)&qn[((size_t)(b * T_ + c * 64 + row)) * D_ + h * 64 + c4 * 4];
    QshT[c4 * 4 + 0][row] = qv.x;
    QshT[c4 * 4 + 1][row] = qv.y;
    QshT[c4 * 4 + 2][row] = qv.z;
    QshT[c4 * 4 + 3][row] = qv.w;
  }
  float o[16];
  #pragma unroll
  for (int g = 0; g < 4; g++) {
    float4 o4 = *(const float4*)&O0buf[(size_t)ch * 4096 + t * 64 + jg * 16 + g * 4];
    o[4*g+0] = o4.x; o[4*g+1] = o4.y; o[4*g+2] = o4.z; o[4*g+3] = o4.w;
  }
  __syncthreads();
  for (int d4 = 0; d4 < 16; d4++) {
    float q0 = QshT[d4 * 4 + 0][t];
    float q1 = QshT[d4 * 4 + 1][t];
    float q2 = QshT[d4 * 4 + 2][t];
    float q3 = QshT[d4 * 4 + 3][t];
    #pragma unroll
    for (int r = 0; r < 16; r++) {
      float4 s4 = *(float4*)&Ssht[jg * 16 + r][d4 * 4];
      o[r] += q0 * s4.x + q1 * s4.y + q2 * s4.z + q3 * s4.w;
    }
  }
  float ss = 0.f;
  #pragma unroll
  for (int r = 0; r < 16; r++) ss += o[r] * o[r];
  part[t][jg] = ss;
  __syncthreads();
  float tot = part[t][0] + part[t][1] + part[t][2] + part[t][3];
  float sc = rsqrtf(tot * (1.f / 64.f) + 1e-6f);
  ushort* orow = &ob[((size_t)(b * T_ + c * 64 + t)) * D_ + h * 64];
  #pragma unroll
  for (int g = 0; g < 4; g++) {
    float4 g4 = *(const float4*)&rms_g[jg * 16 + g * 4];
    ushort4 r4;
    r4.x = f2bf(o[4*g+0] * sc * g4.x); r4.y = f2bf(o[4*g+1] * sc * g4.y);
    r4.z = f2bf(o[4*g+2] * sc * g4.z); r4.w = f2bf(o[4*g+3] * sc * g4.w);
    *(ushort4*)&orow[jg * 16 + g * 4] = r4;
  }
}

extern "C" void kernel_launch(void* const* d_in, const int* in_sizes, int n_in,
                              void* d_out, int out_size, void* d_ws, size_t ws_size,
                              hipStream_t stream) {
  const float* x  = (const float*)d_in[0];
  const float* Wq = (const float*)d_in[1];
  const float* Wk = (const float*)d_in[2];
  const float* Wv = (const float*)d_in[3];
  const float* Wb = (const float*)d_in[4];
  const float* cq = (const float*)d_in[5];
  const float* ck = (const float*)d_in[6];
  const float* cv = (const float*)d_in[7];
  const float* rg = (const float*)d_in[8];
  const float* Wo = (const float*)d_in[9];
  float* out = (float*)d_out;
  char* ws = (char*)d_ws;
  const size_t MiB = 1ull << 20;
  ushort* xb   = (ushort*)(ws + 0);         // dead after QKV gemm
  ushort* Wqt  = (ushort*)(ws + 8 * MiB);   // Wqt/Wkt/Wvt contiguous = [3072][1024] bf16
  ushort* Wkt  = (ushort*)(ws + 10 * MiB);
  ushort* Wvt  = (ushort*)(ws + 12 * MiB);
  ushort* Wot  = (ushort*)(ws + 14 * MiB);  // live to end
  float* qkv   = (float*)(ws + 16 * MiB);   // [4096][3072] fp32, dead after conv
  float* qn    = (float*)(ws + 64 * MiB);   // then Qeff in-place
  float* kn    = (float*)(ws + 80 * MiB);   // then Zt in-place
  float* vn    = (float*)(ws + 96 * MiB);   // dead after prep1
  float* beta  = (float*)(ws + 112 * MiB);  // 256 KiB
  float* WbT   = (float*)(ws + 112 * MiB + 256 * 1024);  // 64 KiB
  float* Wkbuf = (float*)(ws + 16 * MiB);   // over qkv (dead after conv)
  float* U0buf = (float*)(ws + 32 * MiB);
  float* Pbuf  = (float*)(ws + 48 * MiB);   // P (prep2c out, state in)
  float* O0buf = (float*)(ws + 96 * MiB);   // over vn (after prep1)
  float* Sbuf  = (float*)(ws + 16 * MiB);   // over Wkbuf (dead after prep2c)
  ushort* ob   = (ushort*)(ws + 0);         // over xb (after QKV gemm)

  hipLaunchKernelGGL(cast_kernel, dim3(M_ * D_ / 4 / 256), dim3(256), 0, stream,
                     x, xb, M_ * D_ / 4);
  dim3 tb(32, 8);
  hipLaunchKernelGGL(transpose_cast_kernel, dim3(32, 32), tb, 0, stream, Wq, Wqt, D_, D_);
  hipLaunchKernelGGL(transpose_cast_kernel, dim3(32, 32), tb, 0, stream, Wk, Wkt, D_, D_);
  hipLaunchKernelGGL(transpose_cast_kernel, dim3(32, 32), tb, 0, stream, Wv, Wvt, D_, D_);
  hipLaunchKernelGGL(transpose_cast_kernel, dim3(32, 32), tb, 0, stream, Wo, Wot, D_, D_);
  hipLaunchKernelGGL(transpose_wb_kernel, dim3(64), dim3(256), 0, stream, Wb, WbT);

  hipLaunchKernelGGL(gemm128_kernel, dim3(M_ / 128, QKVN_ / 128), dim3(256), 0, stream,
                     xb, Wqt, qkv, M_, QKVN_, D_);

  hipLaunchKernelGGL(beta_kernel, dim3(M_), dim3(256), 0, stream, x, WbT, beta);
  hipLaunchKernelGGL(conv_kernel, dim3(M_), dim3(256), 0, stream,
                     qkv, cq, ck, cv, qn, kn, vn);

  hipLaunchKernelGGL(prep1_kernel, dim3(NCH_), dim3(256), 0, stream,
                     kn, vn, beta, Wkbuf, U0buf);
  hipLaunchKernelGGL(prep2ab_kernel, dim3(NCH_), dim3(256), 0, stream,
                     qn, kn, Wkbuf, U0buf, O0buf);
  hipLaunchKernelGGL(prep2c_kernel, dim3(NCH_), dim3(256), 0, stream,
                     kn, Wkbuf, U0buf, Pbuf);
  hipLaunchKernelGGL(state_kernel, dim3(512), dim3(256), 0, stream,
                     kn, Pbuf, Sbuf);
  hipLaunchKernelGGL(ophase_kernel, dim3(NCH_), dim3(256), 0, stream,
                     qn, Sbuf, O0buf, rg, ob);
  hipLaunchKernelGGL(gemm128_kernel, dim3(M_ / 128, D_ / 128), dim3(256), 0, stream,
                     ob, Wot, out, M_, D_, D_);
}

// Round 7
// 396.700 us; speedup vs baseline: 1.1303x; 1.0023x over previous
//
#include <hip/hip_runtime.h>
#include <hip/hip_bf16.h>
#include <math.h>

#define B_ 2
#define T_ 2048
#define D_ 1024
#define H_ 16
#define DH_ 64
#define M_ (B_*T_)   // 4096 rows
#define NC_ 32       // chunks per sequence (T/64)
#define CS_ 64       // chunk size
#define NCH_ (B_*H_*NC_)  // 1024 chunk-heads
#define QKVN_ 3072   // fused QKV gemm N

typedef __attribute__((ext_vector_type(4))) float floatx4;
typedef __attribute__((ext_vector_type(8))) short short8;

__device__ __forceinline__ ushort f2bf(float f) {
  union { float f; unsigned u; } c; c.f = f;
  unsigned r = (c.u + 0x7FFFu + ((c.u >> 16) & 1u)) >> 16;  // RNE
  return (ushort)r;
}
__device__ __forceinline__ float siluf(float u) {
  return u / (1.f + __expf(-u));
}
__device__ __forceinline__ float f4get(const float4& v, int j) {
  return j == 0 ? v.x : j == 1 ? v.y : j == 2 ? v.z : v.w;
}
__device__ __forceinline__ float rdlane(float v, int l) {
  return __int_as_float(__builtin_amdgcn_readlane(__float_as_int(v), l));
}
// swizzled chunk index for K tiles: chunk c (0..15) of row r stored at c ^ (r>>4)
__device__ __forceinline__ int ksw(int r, int c) { return ((c ^ (r >> 4)) << 2); }

// ---------- cast f32 -> bf16, n4 = n/4 ----------
__global__ void cast_kernel(const float* __restrict__ in, ushort* __restrict__ out, int n4) {
  int i = blockIdx.x * blockDim.x + threadIdx.x;
  if (i >= n4) return;
  float4 v = ((const float4*)in)[i];
  ushort4 o;
  o.x = f2bf(v.x); o.y = f2bf(v.y); o.z = f2bf(v.z); o.w = f2bf(v.w);
  ((ushort4*)out)[i] = o;
}

// ---------- transpose + cast: W[K][N] f32 -> Wt[N][K] bf16 ----------
__global__ void transpose_cast_kernel(const float* __restrict__ W, ushort* __restrict__ Wt,
                                      int K, int N) {
  __shared__ float tile[32][33];
  int tx = threadIdx.x, ty = threadIdx.y;
  int n0 = blockIdx.x * 32, k0 = blockIdx.y * 32;
  #pragma unroll
  for (int i = 0; i < 32; i += 8)
    tile[ty + i][tx] = W[(size_t)(k0 + ty + i) * N + n0 + tx];
  __syncthreads();
  #pragma unroll
  for (int i = 0; i < 32; i += 8)
    Wt[(size_t)(n0 + ty + i) * K + k0 + tx] = f2bf(tile[tx][ty + i]);
}

// ---------- transpose Wb[1024][16] -> WbT[16][1024] (fp32) ----------
__global__ void transpose_wb_kernel(const float* __restrict__ Wb, float* __restrict__ WbT) {
  int bk = blockIdx.x;
  int tid = threadIdx.x;
  int kl = tid >> 4, h = tid & 15;
  int k = bk * 16 + kl;
  WbT[(size_t)h * D_ + k] = Wb[(size_t)k * H_ + h];
}

// ---------- m97-style bf16 MFMA GEMM: C[M][N] = A[M][K]*B[K][N], Bt = B^T [N][K] ----------
__global__ __launch_bounds__(256) void gemm128_kernel(
    const ushort* __restrict__ A, const ushort* __restrict__ Bt,
    float* __restrict__ C, int M, int N, int K) {
  __shared__ ushort lA[128 * 32];
  __shared__ ushort lB[128 * 32];
  int tid = threadIdx.x;
  int wave = tid >> 6, lane = tid & 63;
  int wm = wave >> 1, wn = wave & 1;
  int m16 = lane & 15, q4 = lane >> 4;
  int bm = blockIdx.x, bn = blockIdx.y;
  floatx4 acc[4][4] = {};
  int srow = tid >> 2;
  int sk8 = tid & 3;
  const ushort* Ag = A + (size_t)(bm * 128 + srow) * K + sk8 * 8;
  const ushort* Bg = Bt + (size_t)(bn * 128 + srow) * K + sk8 * 8;
  ushort* lAp = lA + tid * 8;
  ushort* lBp = lB + tid * 8;
  for (int k0 = 0; k0 < K; k0 += 32) {
    __builtin_amdgcn_global_load_lds(
        (const __attribute__((address_space(1))) void*)(Ag + k0),
        (__attribute__((address_space(3))) void*)lAp, 16, 0, 0);
    __builtin_amdgcn_global_load_lds(
        (const __attribute__((address_space(1))) void*)(Ag + (size_t)64 * K + k0),
        (__attribute__((address_space(3))) void*)(lAp + 2048), 16, 0, 0);
    __builtin_amdgcn_global_load_lds(
        (const __attribute__((address_space(1))) void*)(Bg + k0),
        (__attribute__((address_space(3))) void*)lBp, 16, 0, 0);
    __builtin_amdgcn_global_load_lds(
        (const __attribute__((address_space(1))) void*)(Bg + (size_t)64 * K + k0),
        (__attribute__((address_space(3))) void*)(lBp + 2048), 16, 0, 0);
    __syncthreads();
    short8 af[4], bf[4];
    #pragma unroll
    for (int i = 0; i < 4; i++) {
      af[i] = *(short8*)&lA[(wm * 64 + i * 16 + m16) * 32 + q4 * 8];
      bf[i] = *(short8*)&lB[(wn * 64 + i * 16 + m16) * 32 + q4 * 8];
    }
    #pragma unroll
    for (int mi = 0; mi < 4; mi++)
      #pragma unroll
      for (int nj = 0; nj < 4; nj++)
        acc[mi][nj] = __builtin_amdgcn_mfma_f32_16x16x32_bf16(af[mi], bf[nj], acc[mi][nj], 0, 0, 0);
    __syncthreads();
  }
  float* Cb = C + (size_t)(bm * 128) * N + bn * 128;
  #pragma unroll
  for (int mi = 0; mi < 4; mi++) {
    #pragma unroll
    for (int nj = 0; nj < 4; nj++) {
      #pragma unroll
      for (int i = 0; i < 4; i++) {
        int row = wm * 64 + mi * 16 + q4 * 4 + i;
        int col = wn * 64 + nj * 16 + m16;
        Cb[(size_t)row * N + col] = acc[mi][nj][i];
      }
    }
  }
}

// ---------- beta = sigmoid(x @ Wb), WbT[16][1024], conflict-free ----------
__global__ __launch_bounds__(256) void beta_kernel(const float* __restrict__ x,
                                                   const float* __restrict__ WbT,
                                                   float* __restrict__ beta) {
  __shared__ __align__(16) float xs[D_];
  int row = blockIdx.x;
  int tid = threadIdx.x;
  ((float4*)xs)[tid] = ((const float4*)(x + (size_t)row * D_))[tid];
  __syncthreads();
  int h = tid >> 4;
  int seg = tid & 15;
  const float4* wrow = (const float4*)(WbT + (size_t)h * D_) + seg * 16;
  const float4* xsrow = (const float4*)xs + seg * 16;
  float s = 0.f;
  #pragma unroll
  for (int j = 0; j < 16; j++) {
    int jj = (j + seg) & 15;
    float4 xv = xsrow[jj];
    float4 wv = wrow[jj];
    s += xv.x * wv.x + xv.y * wv.y + xv.z * wv.z + xv.w * wv.w;
  }
  #pragma unroll
  for (int off = 8; off; off >>= 1) s += __shfl_down(s, off, 16);
  if (seg == 0) beta[(size_t)row * H_ + h] = 1.f / (1.f + __expf(-s));
}

// ---------- causal depthwise conv(K=4) + silu, l2norm for q,k ----------
__global__ __launch_bounds__(256) void conv_kernel(
    const float* __restrict__ qkv,
    const float* __restrict__ cq, const float* __restrict__ ck, const float* __restrict__ cv,
    float* __restrict__ qo, float* __restrict__ ko, float* __restrict__ vo) {
  int row = blockIdx.x;
  int t = row & (T_ - 1);
  int tid = threadIdx.x;
  int c0 = tid * 4;
  float4 zf = {0.f, 0.f, 0.f, 0.f};
  float4 xq[4], xk[4], xv[4];
  #pragma unroll
  for (int i = 0; i < 4; i++) {
    int tt = t - 3 + i;
    if (tt >= 0) {
      const float* rp = qkv + (size_t)(row - 3 + i) * QKVN_;
      xq[i] = *(const float4*)(rp + c0);
      xk[i] = *(const float4*)(rp + 1024 + c0);
      xv[i] = *(const float4*)(rp + 2048 + c0);
    } else { xq[i] = zf; xk[i] = zf; xv[i] = zf; }
  }
  float yq[4], yk[4], yv[4];
  float pq = 0.f, pk = 0.f;
  #pragma unroll
  for (int j = 0; j < 4; j++) {
    float4 wq = ((const float4*)cq)[c0 + j];
    float4 wk = ((const float4*)ck)[c0 + j];
    float4 wv = ((const float4*)cv)[c0 + j];
    float sq = 0.f, sk = 0.f, sv = 0.f;
    #pragma unroll
    for (int i = 0; i < 4; i++) {
      sq += f4get(wq, i) * f4get(xq[i], j);
      sk += f4get(wk, i) * f4get(xk[i], j);
      sv += f4get(wv, i) * f4get(xv[i], j);
    }
    yq[j] = siluf(sq); yk[j] = siluf(sk); yv[j] = siluf(sv);
    pq += yq[j] * yq[j]; pk += yk[j] * yk[j];
  }
  #pragma unroll
  for (int off = 1; off < 16; off <<= 1) {
    pq += __shfl_xor(pq, off, 16);
    pk += __shfl_xor(pk, off, 16);
  }
  float rq = rsqrtf(pq + 1e-6f), rk = rsqrtf(pk + 1e-6f);
  float4 oq = {yq[0]*rq, yq[1]*rq, yq[2]*rq, yq[3]*rq};
  float4 okk = {yk[0]*rk, yk[1]*rk, yk[2]*rk, yk[3]*rk};
  float4 ov = {yv[0], yv[1], yv[2], yv[3]};
  *(float4*)(qo + (size_t)row * D_ + c0) = oq;
  *(float4*)(ko + (size_t)row * D_ + c0) = okk;
  *(float4*)(vo + (size_t)row * D_ + c0) = ov;
}

// ================= chunked delta rule =================
// prep1: A = strict_tril(diag(b)KK^T); solve (I+A)Wk = diag(b)K and (I+A)U0 = diag(b)V
// A-phase uses 4x4 register output tiling: per d4 step 8 float4 LDS reads for 64
// FMAs (was 17 reads) -> ~2.1x less LDS-pipe traffic, same per-element f32
// accumulation order. Then blocked forward substitution (R3-verified):
//   Phase A: each wave w inverts its 16x16 diag block T_ww = (I+A_ww)^-1  (parallel)
//   Phase B: wave w precomputes M_wk = A_wk * T_kk for k<w  (off critical path)
//   k-loop (4 steps): wave k publishes residual Y_k once; wave k applies T_kk*Y_k
//   (final output -> global), waves i>k apply Y_i -= M_ik*Y_k, all concurrently.
__global__ __launch_bounds__(256) void prep1_kernel(
    const float* __restrict__ kn, const float* __restrict__ vn,
    const float* __restrict__ beta,
    float* __restrict__ Wkbuf, float* __restrict__ U0buf) {
  __shared__ __align__(16) float Ash[64 * 68];   // A[t][s] row-major, stride 68
  __shared__ float bsh[64];
  // union region: Ksh (during A compute) aliased with Tsh/Msh/Xsh (after)
  __shared__ __align__(16) float uni[5312];
  float (*Ksh)[68] = (float (*)[68])uni;                    // 64x68 = 4352 floats
  float (*Tsh)[16][20] = (float (*)[16][20])uni;            // [4][16][20] = 1280
  float (*Msh)[16][20] = (float (*)[16][20])(uni + 1280);   // [6][16][20] = 1920
  float (*Xsh)[132] = (float (*)[132])(uni + 3200);         // [16][132]  = 2112

  int ch = blockIdx.x;
  int b = ch >> 9, h = (ch >> 5) & 15, c = ch & 31;
  int tid = threadIdx.x;
  int t = tid >> 2, seg = tid & 3;
  int wave = tid >> 6, lane = tid & 63;
  int r = lane >> 2, q = lane & 3;   // r == t&15, q == seg
  const float* krow = kn + ((size_t)(b * T_ + c * 64 + t)) * D_ + h * 64;
  #pragma unroll
  for (int g = 0; g < 4; g++)
    *(float4*)&Ksh[t][ksw(t, seg * 4 + g)] = *(const float4*)&krow[seg * 16 + 4 * g];
  if (tid < 64) bsh[tid] = beta[((size_t)(b * T_ + c * 64 + tid)) * H_ + h];
  __syncthreads();
  // A[t][s] = (t>s) ? b_t * (k_t . k_s) : 0 — 4x4 register tile per thread
  {
    int qt = tid >> 4, qs = tid & 15;   // row quad, col quad
    int swt = qt >> 2, sws = qs >> 2;   // (row>>4) shared by all 4 rows of a quad
    float acc[4][4];
    #pragma unroll
    for (int i = 0; i < 4; i++)
      #pragma unroll
      for (int j = 0; j < 4; j++) acc[i][j] = 0.f;
    for (int d4 = 0; d4 < 16; d4++) {
      float4 kt[4], ks[4];
      #pragma unroll
      for (int i = 0; i < 4; i++) kt[i] = *(float4*)&Ksh[qt * 4 + i][((d4 ^ swt) << 2)];
      #pragma unroll
      for (int j = 0; j < 4; j++) ks[j] = *(float4*)&Ksh[qs * 4 + j][((d4 ^ sws) << 2)];
      #pragma unroll
      for (int i = 0; i < 4; i++)
        #pragma unroll
        for (int j = 0; j < 4; j++)
          acc[i][j] += kt[i].x * ks[j].x + kt[i].y * ks[j].y
                     + kt[i].z * ks[j].z + kt[i].w * ks[j].w;
    }
    #pragma unroll
    for (int i = 0; i < 4; i++) {
      int row = qt * 4 + i;
      float bt = bsh[row];
      float4 a4;
      a4.x = (row > qs * 4 + 0) ? bt * acc[i][0] : 0.f;
      a4.y = (row > qs * 4 + 1) ? bt * acc[i][1] : 0.f;
      a4.z = (row > qs * 4 + 2) ? bt * acc[i][2] : 0.f;
      a4.w = (row > qs * 4 + 3) ? bt * acc[i][3] : 0.f;
      *(float4*)&Ash[row * 68 + qs * 4] = a4;
    }
  }
  // RHS (residual Y) in registers: row t, 16 K-cols + 16 V-cols
  float xk[16], xv[16];
  {
    float bt = bsh[t];
    const float* vrow = vn + ((size_t)(b * T_ + c * 64 + t)) * D_ + h * 64;
    #pragma unroll
    for (int g = 0; g < 4; g++) {
      float4 kv = *(float4*)&Ksh[t][ksw(t, seg * 4 + g)];
      float4 vv = *(const float4*)&vrow[seg * 16 + 4 * g];
      xk[4*g+0] = bt * kv.x; xk[4*g+1] = bt * kv.y; xk[4*g+2] = bt * kv.z; xk[4*g+3] = bt * kv.w;
      xv[4*g+0] = bt * vv.x; xv[4*g+1] = bt * vv.y; xv[4*g+2] = bt * vv.z; xv[4*g+3] = bt * vv.w;
    }
  }
  __syncthreads();   // Ash ready; Ksh dead -> Tsh/Msh/Xsh region live
  // Phase A: wave-parallel 16x16 diagonal-block inverse via fwd substitution on I
  {
    float a[16];
    #pragma unroll
    for (int i = 0; i < 16; i++) a[i] = Ash[(wave * 16 + r) * 68 + wave * 16 + i];
    float4 w4 = {0.f, 0.f, 0.f, 0.f};
    if ((r >> 2) == q) ((float*)&w4)[r & 3] = 1.f;
    #pragma unroll
    for (int i = 0; i < 15; i++) {
      int src = i * 4 + q;
      float4 wi;
      wi.x = __shfl(w4.x, src, 64);
      wi.y = __shfl(w4.y, src, 64);
      wi.z = __shfl(w4.z, src, 64);
      wi.w = __shfl(w4.w, src, 64);
      if (r > i) {
        w4.x -= a[i] * wi.x; w4.y -= a[i] * wi.y;
        w4.z -= a[i] * wi.z; w4.w -= a[i] * wi.w;
      }
    }
    *(float4*)&Tsh[wave][r][q * 4] = w4;
  }
  __syncthreads();   // Tsh visible to all waves
  // Phase B: M_wk = A_wk * T_kk (wave-local write, wave-local read)
  for (int k = 0; k < wave; k++) {
    float4 m4 = {0.f, 0.f, 0.f, 0.f};
    #pragma unroll
    for (int i = 0; i < 16; i++) {
      float aik = Ash[(wave * 16 + r) * 68 + k * 16 + i];
      float4 tk = *(float4*)&Tsh[k][i][q * 4];
      m4.x += aik * tk.x; m4.y += aik * tk.y;
      m4.z += aik * tk.z; m4.w += aik * tk.w;
    }
    int mi = wave * (wave - 1) / 2 + k;
    *(float4*)&Msh[mi][r][q * 4] = m4;
  }
  // Block substitution k-loop
  float* wkout = &Wkbuf[(size_t)ch * 4096 + t * 64];
  float* u0out = &U0buf[(size_t)ch * 4096 + t * 64];
  for (int k = 0; k < 4; k++) {
    if (wave == k) {   // publish residual Y_k
      #pragma unroll
      for (int g = 0; g < 4; g++) {
        float4 k4 = {xk[4*g+0], xk[4*g+1], xk[4*g+2], xk[4*g+3]};
        float4 v4 = {xv[4*g+0], xv[4*g+1], xv[4*g+2], xv[4*g+3]};
        *(float4*)&Xsh[r][seg * 16 + 4 * g] = k4;
        *(float4*)&Xsh[r][64 + seg * 16 + 4 * g] = v4;
      }
    }
    __syncthreads();
    if (wave == k) {
      // X_k = T_kk * Y_k -> final output, straight to global
      float nk[16], nv[16];
      #pragma unroll
      for (int i2 = 0; i2 < 16; i2++) { nk[i2] = 0.f; nv[i2] = 0.f; }
      #pragma unroll
      for (int i = 0; i < 16; i++) {
        float tc = Tsh[k][r][i];
        #pragma unroll
        for (int g = 0; g < 4; g++) {
          float4 yk = *(float4*)&Xsh[i][seg * 16 + 4 * g];
          float4 yv = *(float4*)&Xsh[i][64 + seg * 16 + 4 * g];
          nk[4*g+0] += tc * yk.x; nk[4*g+1] += tc * yk.y;
          nk[4*g+2] += tc * yk.z; nk[4*g+3] += tc * yk.w;
          nv[4*g+0] += tc * yv.x; nv[4*g+1] += tc * yv.y;
          nv[4*g+2] += tc * yv.z; nv[4*g+3] += tc * yv.w;
        }
      }
      #pragma unroll
      for (int g = 0; g < 4; g++) {
        float4 k4 = {nk[4*g+0], nk[4*g+1], nk[4*g+2], nk[4*g+3]};
        float4 v4 = {nv[4*g+0], nv[4*g+1], nv[4*g+2], nv[4*g+3]};
        *(float4*)&wkout[seg * 16 + 4 * g] = k4;
        *(float4*)&u0out[seg * 16 + 4 * g] = v4;
      }
    } else if (wave > k) {
      // Y_i -= M_ik * Y_k   (== A_ik * X_k)
      int mi = wave * (wave - 1) / 2 + k;
      #pragma unroll
      for (int i = 0; i < 16; i++) {
        float mc = Msh[mi][r][i];
        #pragma unroll
        for (int g = 0; g < 4; g++) {
          float4 yk = *(float4*)&Xsh[i][seg * 16 + 4 * g];
          float4 yv = *(float4*)&Xsh[i][64 + seg * 16 + 4 * g];
          xk[4*g+0] -= mc * yk.x; xk[4*g+1] -= mc * yk.y;
          xk[4*g+2] -= mc * yk.z; xk[4*g+3] -= mc * yk.w;
          xv[4*g+0] -= mc * yv.x; xv[4*g+1] -= mc * yv.y;
          xv[4*g+2] -= mc * yv.z; xv[4*g+3] -= mc * yv.w;
        }
      }
    }
    __syncthreads();
  }
}

// prep2ab: fused prep2a+prep2b. Phase 1: L = tril(Q K^T) -> Lsh (LDS, no HBM
// roundtrip), with 4x4 register output tiling (8 float4 reads / 64 FMAs per d4).
// Phase 2: reuse Qsh/Ksh LDS space for Wk/U0 staging, then
// O0 = L U0 ; Qeff = Q - L Wk (identical arithmetic order to the old kernels).
__global__ __launch_bounds__(256) void prep2ab_kernel(
    float* qn, const float* __restrict__ kn,
    const float* __restrict__ Wkbuf, const float* __restrict__ U0buf,
    float* __restrict__ O0buf) {
  __shared__ float Qsh[64][68];   // phase 2: Wksh
  __shared__ float Ksh[64][68];   // swizzled; phase 2: U0sh
  __shared__ float Lsh[64][68];
  float (*Wksh)[68] = Qsh;
  float (*U0sh)[68] = Ksh;
  int ch = blockIdx.x;
  int b = ch >> 9, h = (ch >> 5) & 15, c = ch & 31;
  int tid = threadIdx.x;
  int t = tid >> 2, seg = tid & 3;
  const float* qrow = qn + ((size_t)(b * T_ + c * 64 + t)) * D_ + h * 64;
  const float* krow = kn + ((size_t)(b * T_ + c * 64 + t)) * D_ + h * 64;
  #pragma unroll
  for (int g = 0; g < 4; g++) {
    *(float4*)&Qsh[t][seg * 16 + 4 * g] = *(const float4*)&qrow[seg * 16 + 4 * g];
    *(float4*)&Ksh[t][ksw(t, seg * 4 + g)] = *(const float4*)&krow[seg * 16 + 4 * g];
  }
  __syncthreads();
  // phase 1: L = tril(Q K^T) -> Lsh, 4x4 register tile per thread
  {
    int qt = tid >> 4, qs = tid & 15;
    int sws = qs >> 2;
    float acc[4][4];
    #pragma unroll
    for (int i = 0; i < 4; i++)
      #pragma unroll
      for (int j = 0; j < 4; j++) acc[i][j] = 0.f;
    for (int d4 = 0; d4 < 16; d4++) {
      float4 qv[4], ks[4];
      #pragma unroll
      for (int i = 0; i < 4; i++) qv[i] = *(float4*)&Qsh[qt * 4 + i][d4 * 4];
      #pragma unroll
      for (int j = 0; j < 4; j++) ks[j] = *(float4*)&Ksh[qs * 4 + j][((d4 ^ sws) << 2)];
      #pragma unroll
      for (int i = 0; i < 4; i++)
        #pragma unroll
        for (int j = 0; j < 4; j++)
          acc[i][j] += qv[i].x * ks[j].x + qv[i].y * ks[j].y
                     + qv[i].z * ks[j].z + qv[i].w * ks[j].w;
    }
    #pragma unroll
    for (int i = 0; i < 4; i++) {
      int row = qt * 4 + i;
      float4 ov;
      ov.x = (qs * 4 + 0 <= row) ? acc[i][0] : 0.f;
      ov.y = (qs * 4 + 1 <= row) ? acc[i][1] : 0.f;
      ov.z = (qs * 4 + 2 <= row) ? acc[i][2] : 0.f;
      ov.w = (qs * 4 + 3 <= row) ? acc[i][3] : 0.f;
      *(float4*)&Lsh[row][qs * 4] = ov;
    }
  }
  __syncthreads();   // L done; Qsh/Ksh dead -> stage Wk/U0 into their space
  #pragma unroll
  for (int g = 0; g < 4; g++) {
    int o = t * 64 + seg * 16 + 4 * g;
    *(float4*)&Wksh[t][seg * 16 + 4 * g] = *(const float4*)&Wkbuf[(size_t)ch * 4096 + o];
    *(float4*)&U0sh[t][seg * 16 + 4 * g] = *(const float4*)&U0buf[(size_t)ch * 4096 + o];
  }
  __syncthreads();
  // phase 2: O0 = L U0 ; Qeff = Q - L Wk (identical to old prep2b)
  int j0 = seg * 16;
  float o0[16], lw[16];
  #pragma unroll
  for (int r = 0; r < 16; r++) { o0[r] = 0.f; lw[r] = 0.f; }
  for (int s = 0; s <= t; s++) {
    float l = Lsh[t][s];
    #pragma unroll
    for (int g = 0; g < 4; g++) {
      float4 u = *(float4*)&U0sh[s][j0 + 4 * g];
      float4 w = *(float4*)&Wksh[s][j0 + 4 * g];
      o0[4*g+0] += l * u.x; o0[4*g+1] += l * u.y; o0[4*g+2] += l * u.z; o0[4*g+3] += l * u.w;
      lw[4*g+0] += l * w.x; lw[4*g+1] += l * w.y; lw[4*g+2] += l * w.z; lw[4*g+3] += l * w.w;
    }
  }
  float* qwrow = qn + ((size_t)(b * T_ + c * 64 + t)) * D_ + h * 64;
  #pragma unroll
  for (int g = 0; g < 4; g++) {
    float4 qv = *(const float4*)&qwrow[j0 + 4 * g];
    qv.x -= lw[4*g+0]; qv.y -= lw[4*g+1]; qv.z -= lw[4*g+2]; qv.w -= lw[4*g+3];
    *(float4*)&qwrow[j0 + 4 * g] = qv;
    float4 ov = {o0[4*g+0], o0[4*g+1], o0[4*g+2], o0[4*g+3]};
    *(float4*)&O0buf[(size_t)ch * 4096 + t * 64 + j0 + 4 * g] = ov;
  }
}

// prep2c: P[d][e] = I - (K^T Wk)[d][e], stored SLOT-MAJOR for state_kernel:
//         float4 #(f*64+d) of chunk = P[d][4f..4f+3]  (so a wave reading slot f,
//         all rows d, is one contiguous 1KB block).
//         Zt[j][d] = (U0^T K)[j][d] -> kn rows j (coalesced), unchanged.
__global__ __launch_bounds__(256) void prep2c_kernel(
    float* kn, const float* __restrict__ Wkbuf,
    const float* __restrict__ U0buf, float* __restrict__ Pbuf) {
  __shared__ float Ksh[64][68];
  __shared__ float Wksh[64][68];
  __shared__ float U0sh[64][68];
  int ch = blockIdx.x;
  int b = ch >> 9, h = (ch >> 5) & 15, c = ch & 31;
  int tid = threadIdx.x;
  int t = tid >> 2, seg = tid & 3;   // t = output row (d for P, j for Zt)
  const float* krow = kn + ((size_t)(b * T_ + c * 64 + t)) * D_ + h * 64;
  #pragma unroll
  for (int g = 0; g < 4; g++) {
    int o = t * 64 + seg * 16 + 4 * g;
    *(float4*)&Ksh[t][seg * 16 + 4 * g]  = *(const float4*)&krow[seg * 16 + 4 * g];
    *(float4*)&Wksh[t][seg * 16 + 4 * g] = *(const float4*)&Wkbuf[(size_t)ch * 4096 + o];
    *(float4*)&U0sh[t][seg * 16 + 4 * g] = *(const float4*)&U0buf[(size_t)ch * 4096 + o];
  }
  __syncthreads();
  int d0 = seg * 16;
  float accP[16], accZ[16];
  #pragma unroll
  for (int r = 0; r < 16; r++) { accP[r] = 0.f; accZ[r] = 0.f; }
  for (int s = 0; s < 64; s++) {
    float kt = Ksh[s][t];    // scalar for P row d=t
    float u  = U0sh[s][t];   // scalar for Z row j=t
    #pragma unroll
    for (int g = 0; g < 4; g++) {
      float4 w4 = *(float4*)&Wksh[s][d0 + 4 * g];
      float4 k4 = *(float4*)&Ksh[s][d0 + 4 * g];
      accP[4*g+0] += kt * w4.x; accP[4*g+1] += kt * w4.y; accP[4*g+2] += kt * w4.z; accP[4*g+3] += kt * w4.w;
      accZ[4*g+0] += u * k4.x;  accZ[4*g+1] += u * k4.y;  accZ[4*g+2] += u * k4.z;  accZ[4*g+3] += u * k4.w;
    }
  }
  float* zrow = kn + ((size_t)(b * T_ + c * 64 + t)) * D_ + h * 64;
  #pragma unroll
  for (int g = 0; g < 4; g++) {
    float4 pv;
    pv.x = ((d0 + 4*g + 0) == t ? 1.f : 0.f) - accP[4*g+0];
    pv.y = ((d0 + 4*g + 1) == t ? 1.f : 0.f) - accP[4*g+1];
    pv.z = ((d0 + 4*g + 2) == t ? 1.f : 0.f) - accP[4*g+2];
    pv.w = ((d0 + 4*g + 3) == t ? 1.f : 0.f) - accP[4*g+3];
    // slot-major: slot f = seg*4+g, row d = t
    *(float4*)&Pbuf[(size_t)ch * 4096 + (size_t)(seg * 4 + g) * 256 + (size_t)t * 4] = pv;
    float4 zv = {accZ[4*g+0], accZ[4*g+1], accZ[4*g+2], accZ[4*g+3]};
    *(float4*)&zrow[d0 + 4 * g] = zv;
  }
}

// ---------- state scan: S_{c+1} = P_c S_c + Z_c; Sbuf transposed [ch][j][d] ----------
// 512 blocks = (bh, js), 256 threads = 4 waves; wave wv owns single column
// j0 = js*4 + wv; lane = d holds S[j0][d]. P_c staged ONCE per block into LDS
// (slot-major -> conflict-free contiguous b128 reads), double-buffered; the 4
// waves share it -> same L2 traffic as the 1-wave version but 2048 waves total
// (2 waves/SIMD) so ds_read/barrier stalls overlap across waves. One
// __syncthreads per chunk (its implicit vmcnt drain covers staging visibility).
// bh = bid&31 so the 16 block-sharers of a (b,h) land on the same XCD.
__global__ __launch_bounds__(256) void state_kernel(
    const float* __restrict__ kn /*Zt*/, const float* __restrict__ Pbuf /*slot-major*/,
    float* __restrict__ Sbuf) {
  __shared__ __align__(16) float Pl[2][4096];
  int bid = blockIdx.x;
  int bh = bid & 31, js = bid >> 5;
  int h = bh & 15, b = bh >> 4;
  int tid = threadIdx.x;
  int wv = tid >> 6, lane = tid & 63;   // lane = d
  int j0 = js * 4 + wv;                 // this wave's column
  float s0 = 0.f;
  const size_t bhNC = (size_t)bh * NC_;
  // prologue: stage P_0 into buf0 (256 threads x 16B x 4 passes = 16KB), load Z_0
  const float* Pg0 = Pbuf + bhNC * 4096;
  #pragma unroll
  for (int g = 0; g < 4; g++)
    __builtin_amdgcn_global_load_lds(
        (const __attribute__((address_space(1))) void*)(Pg0 + (g * 256 + tid) * 4),
        (__attribute__((address_space(3))) void*)&Pl[0][(g * 256 + tid) * 4], 16, 0, 0);
  float zn = kn[((size_t)(b * T_ + j0)) * D_ + h * 64 + lane];
  int cur = 0;
  #pragma unroll 1
  for (int c = 0; c < NC_; c++) {
    __syncthreads();            // implies vmcnt(0) drain: buf[cur] ready for all waves
    float z = zn;
    size_t ch = bhNC + c;
    // issue next-chunk staging into the other buffer + Z prefetch
    if (c + 1 < NC_) {
      const float* Pg = Pbuf + (ch + 1) * 4096;
      #pragma unroll
      for (int g = 0; g < 4; g++)
        __builtin_amdgcn_global_load_lds(
            (const __attribute__((address_space(1))) void*)(Pg + (g * 256 + tid) * 4),
            (__attribute__((address_space(3))) void*)&Pl[cur ^ 1][(g * 256 + tid) * 4], 16, 0, 0);
      zn = kn[((size_t)(b * T_ + (c + 1) * 64 + j0)) * D_ + h * 64 + lane];
    }
    // store S_c (pre-update), coalesced 256B per wave
    Sbuf[ch * 4096 + (size_t)j0 * 64 + lane] = s0;
    // S_{c+1}[j0][d=lane] = Z[j0][d] + sum_e P[d][e] * S_c[j0][e]
    float acc = z;
    #pragma unroll
    for (int f = 0; f < 16; f++) {
      floatx4 pv = *(floatx4*)&Pl[cur][f * 256 + lane * 4];
      acc += pv.x * rdlane(s0, f * 4 + 0);
      acc += pv.y * rdlane(s0, f * 4 + 1);
      acc += pv.z * rdlane(s0, f * 4 + 2);
      acc += pv.w * rdlane(s0, f * 4 + 3);
    }
    s0 = acc;
    cur ^= 1;
  }
}

// ---------- O = O0 + Qeff*S_c (S transposed layout), fused RMSNorm + bf16 cast ----------
__global__ __launch_bounds__(256) void ophase_kernel(
    const float* __restrict__ qn /*Qeff*/, const float* __restrict__ Sbuf,
    const float* __restrict__ O0buf, const float* __restrict__ rms_g,
    ushort* __restrict__ ob) {
  __shared__ float Ssht[64][68];
  __shared__ float QshT[64][65];
  __shared__ float part[64][4];
  int ch = blockIdx.x;
  int b = ch >> 9, h = (ch >> 5) & 15, c = ch & 31;
  int tid = threadIdx.x;
  int t = tid & 63, jg = tid >> 6;
  #pragma unroll
  for (int g = 0; g < 4; g++) {
    int idx = tid + g * 256;
    *(float4*)&Ssht[idx >> 4][(idx & 15) * 4] =
        *(const float4*)&Sbuf[(size_t)ch * 4096 + (size_t)idx * 4];
  }
  #pragma unroll
  for (int g = 0; g < 4; g++) {
    int idx = tid + g * 256;
    int row = idx >> 4, c4 = idx & 15;
    float4 qv = *(const float4*)&qn[((size_t)(b * T_ + c * 64 + row)) * D_ + h * 64 + c4 * 4];
    QshT[c4 * 4 + 0][row] = qv.x;
    QshT[c4 * 4 + 1][row] = qv.y;
    QshT[c4 * 4 + 2][row] = qv.z;
    QshT[c4 * 4 + 3][row] = qv.w;
  }
  float o[16];
  #pragma unroll
  for (int g = 0; g < 4; g++) {
    float4 o4 = *(const float4*)&O0buf[(size_t)ch * 4096 + t * 64 + jg * 16 + g * 4];
    o[4*g+0] = o4.x; o[4*g+1] = o4.y; o[4*g+2] = o4.z; o[4*g+3] = o4.w;
  }
  __syncthreads();
  for (int d4 = 0; d4 < 16; d4++) {
    float q0 = QshT[d4 * 4 + 0][t];
    float q1 = QshT[d4 * 4 + 1][t];
    float q2 = QshT[d4 * 4 + 2][t];
    float q3 = QshT[d4 * 4 + 3][t];
    #pragma unroll
    for (int r = 0; r < 16; r++) {
      float4 s4 = *(float4*)&Ssht[jg * 16 + r][d4 * 4];
      o[r] += q0 * s4.x + q1 * s4.y + q2 * s4.z + q3 * s4.w;
    }
  }
  float ss = 0.f;
  #pragma unroll
  for (int r = 0; r < 16; r++) ss += o[r] * o[r];
  part[t][jg] = ss;
  __syncthreads();
  float tot = part[t][0] + part[t][1] + part[t][2] + part[t][3];
  float sc = rsqrtf(tot * (1.f / 64.f) + 1e-6f);
  ushort* orow = &ob[((size_t)(b * T_ + c * 64 + t)) * D_ + h * 64];
  #pragma unroll
  for (int g = 0; g < 4; g++) {
    float4 g4 = *(const float4*)&rms_g[jg * 16 + g * 4];
    ushort4 r4;
    r4.x = f2bf(o[4*g+0] * sc * g4.x); r4.y = f2bf(o[4*g+1] * sc * g4.y);
    r4.z = f2bf(o[4*g+2] * sc * g4.z); r4.w = f2bf(o[4*g+3] * sc * g4.w);
    *(ushort4*)&orow[jg * 16 + g * 4] = r4;
  }
}

extern "C" void kernel_launch(void* const* d_in, const int* in_sizes, int n_in,
                              void* d_out, int out_size, void* d_ws, size_t ws_size,
                              hipStream_t stream) {
  const float* x  = (const float*)d_in[0];
  const float* Wq = (const float*)d_in[1];
  const float* Wk = (const float*)d_in[2];
  const float* Wv = (const float*)d_in[3];
  const float* Wb = (const float*)d_in[4];
  const float* cq = (const float*)d_in[5];
  const float* ck = (const float*)d_in[6];
  const float* cv = (const float*)d_in[7];
  const float* rg = (const float*)d_in[8];
  const float* Wo = (const float*)d_in[9];
  float* out = (float*)d_out;
  char* ws = (char*)d_ws;
  const size_t MiB = 1ull << 20;
  ushort* xb   = (ushort*)(ws + 0);         // dead after QKV gemm
  ushort* Wqt  = (ushort*)(ws + 8 * MiB);   // Wqt/Wkt/Wvt contiguous = [3072][1024] bf16
  ushort* Wkt  = (ushort*)(ws + 10 * MiB);
  ushort* Wvt  = (ushort*)(ws + 12 * MiB);
  ushort* Wot  = (ushort*)(ws + 14 * MiB);  // live to end
  float* qkv   = (float*)(ws + 16 * MiB);   // [4096][3072] fp32, dead after conv
  float* qn    = (float*)(ws + 64 * MiB);   // then Qeff in-place
  float* kn    = (float*)(ws + 80 * MiB);   // then Zt in-place
  float* vn    = (float*)(ws + 96 * MiB);   // dead after prep1
  float* beta  = (float*)(ws + 112 * MiB);  // 256 KiB
  float* WbT   = (float*)(ws + 112 * MiB + 256 * 1024);  // 64 KiB
  float* Wkbuf = (float*)(ws + 16 * MiB);   // over qkv (dead after conv)
  float* U0buf = (float*)(ws + 32 * MiB);
  float* Pbuf  = (float*)(ws + 48 * MiB);   // P (prep2c out, state in)
  float* O0buf = (float*)(ws + 96 * MiB);   // over vn (after prep1)
  float* Sbuf  = (float*)(ws + 16 * MiB);   // over Wkbuf (dead after prep2c)
  ushort* ob   = (ushort*)(ws + 0);         // over xb (after QKV gemm)

  hipLaunchKernelGGL(cast_kernel, dim3(M_ * D_ / 4 / 256), dim3(256), 0, stream,
                     x, xb, M_ * D_ / 4);
  dim3 tb(32, 8);
  hipLaunchKernelGGL(transpose_cast_kernel, dim3(32, 32), tb, 0, stream, Wq, Wqt, D_, D_);
  hipLaunchKernelGGL(transpose_cast_kernel, dim3(32, 32), tb, 0, stream, Wk, Wkt, D_, D_);
  hipLaunchKernelGGL(transpose_cast_kernel, dim3(32, 32), tb, 0, stream, Wv, Wvt, D_, D_);
  hipLaunchKernelGGL(transpose_cast_kernel, dim3(32, 32), tb, 0, stream, Wo, Wot, D_, D_);
  hipLaunchKernelGGL(transpose_wb_kernel, dim3(64), dim3(256), 0, stream, Wb, WbT);

  hipLaunchKernelGGL(gemm128_kernel, dim3(M_ / 128, QKVN_ / 128), dim3(256), 0, stream,
                     xb, Wqt, qkv, M_, QKVN_, D_);

  hipLaunchKernelGGL(beta_kernel, dim3(M_), dim3(256), 0, stream, x, WbT, beta);
  hipLaunchKernelGGL(conv_kernel, dim3(M_), dim3(256), 0, stream,
                     qkv, cq, ck, cv, qn, kn, vn);

  hipLaunchKernelGGL(prep1_kernel, dim3(NCH_), dim3(256), 0, stream,
                     kn, vn, beta, Wkbuf, U0buf);
  hipLaunchKernelGGL(prep2ab_kernel, dim3(NCH_), dim3(256), 0, stream,
                     qn, kn, Wkbuf, U0buf, O0buf);
  hipLaunchKernelGGL(prep2c_kernel, dim3(NCH_), dim3(256), 0, stream,
                     kn, Wkbuf, U0buf, Pbuf);
  hipLaunchKernelGGL(state_kernel, dim3(512), dim3(256), 0, stream,
                     kn, Pbuf, Sbuf);
  hipLaunchKernelGGL(ophase_kernel, dim3(NCH_), dim3(256), 0, stream,
                     qn, Sbuf, O0buf, rg, ob);
  hipLaunchKernelGGL(gemm128_kernel, dim3(M_ / 128, D_ / 128), dim3(256), 0, stream,
                     ob, Wot, out, M_, D_, D_);
}

// Round 8
// 378.733 us; speedup vs baseline: 1.1839x; 1.0474x over previous
//
#include <hip/hip_runtime.h>
#include <hip/hip_bf16.h>
#include <math.h>

#define B_ 2
#define T_ 2048
#define D_ 1024
#define H_ 16
#define DH_ 64
#define M_ (B_*T_)   // 4096 rows
#define NC_ 32       // chunks per sequence (T/64)
#define CS_ 64       // chunk size
#define NCH_ (B_*H_*NC_)  // 1024 chunk-heads
#define QKVN_ 3072   // fused QKV gemm N

typedef __attribute__((ext_vector_type(4))) float floatx4;
typedef __attribute__((ext_vector_type(8))) short short8;

__device__ __forceinline__ ushort f2bf(float f) {
  union { float f; unsigned u; } c; c.f = f;
  unsigned r = (c.u + 0x7FFFu + ((c.u >> 16) & 1u)) >> 16;  // RNE
  return (ushort)r;
}
__device__ __forceinline__ float siluf(float u) {
  return u / (1.f + __expf(-u));
}
__device__ __forceinline__ float f4get(const float4& v, int j) {
  return j == 0 ? v.x : j == 1 ? v.y : j == 2 ? v.z : v.w;
}
__device__ __forceinline__ float rdlane(float v, int l) {
  return __int_as_float(__builtin_amdgcn_readlane(__float_as_int(v), l));
}
// swizzled chunk index for K tiles: chunk c (0..15) of row r stored at c ^ (r>>4)
__device__ __forceinline__ int ksw(int r, int c) { return ((c ^ (r >> 4)) << 2); }

// ---------- cast f32 -> bf16, n4 = n/4 ----------
__global__ void cast_kernel(const float* __restrict__ in, ushort* __restrict__ out, int n4) {
  int i = blockIdx.x * blockDim.x + threadIdx.x;
  if (i >= n4) return;
  float4 v = ((const float4*)in)[i];
  ushort4 o;
  o.x = f2bf(v.x); o.y = f2bf(v.y); o.z = f2bf(v.z); o.w = f2bf(v.w);
  ((ushort4*)out)[i] = o;
}

// ---------- transpose + cast: W[K][N] f32 -> Wt[N][K] bf16 ----------
__global__ void transpose_cast_kernel(const float* __restrict__ W, ushort* __restrict__ Wt,
                                      int K, int N) {
  __shared__ float tile[32][33];
  int tx = threadIdx.x, ty = threadIdx.y;
  int n0 = blockIdx.x * 32, k0 = blockIdx.y * 32;
  #pragma unroll
  for (int i = 0; i < 32; i += 8)
    tile[ty + i][tx] = W[(size_t)(k0 + ty + i) * N + n0 + tx];
  __syncthreads();
  #pragma unroll
  for (int i = 0; i < 32; i += 8)
    Wt[(size_t)(n0 + ty + i) * K + k0 + tx] = f2bf(tile[tx][ty + i]);
}

// ---------- transpose Wb[1024][16] -> WbT[16][1024] (fp32) ----------
__global__ void transpose_wb_kernel(const float* __restrict__ Wb, float* __restrict__ WbT) {
  int bk = blockIdx.x;
  int tid = threadIdx.x;
  int kl = tid >> 4, h = tid & 15;
  int k = bk * 16 + kl;
  WbT[(size_t)h * D_ + k] = Wb[(size_t)k * H_ + h];
}

// ---------- bf16 MFMA GEMM, 2-phase counted-vmcnt pipeline + XCD supertile swizzle ----------
// C[M][N] = A[M][K]*B[K][N], Bt = B^T [N][K].
// K-loop: STAGE(next buf) issued BEFORE vmcnt(4) wait -> next tile's 4 loads stay
// in flight across the barrier (T3/T4 minimum recipe); bar1 after own-wave vmcnt
// makes buf[cur] visible; bar2 after MFMA ensures all waves done reading before
// re-stage (race-free). Grid swizzle: XCD-contiguous ranges + 8x8 block
// supertiles -> per-XCD L2 working set ~3.5MB (8 A-panels + 8 B-panels).
// Requires gridDim.x%8==0 && gridDim.y%8==0 (holds for 32x24 and 32x8).
__global__ __launch_bounds__(256) void gemm128_kernel(
    const ushort* __restrict__ A, const ushort* __restrict__ Bt,
    float* __restrict__ C, int M, int N, int K) {
  __shared__ ushort lA[2][128 * 32];
  __shared__ ushort lB[2][128 * 32];
  int tid = threadIdx.x;
  int wave = tid >> 6, lane = tid & 63;
  int wm = wave >> 1, wn = wave & 1;
  int m16 = lane & 15, q4 = lane >> 4;
  // XCD-aware bijective swizzle with 8x8 supertiles
  int nbm = gridDim.x, nbn = gridDim.y;
  int lin = blockIdx.y * nbm + blockIdx.x;
  int cpx = (nbm * nbn) >> 3;
  int swz = (lin & 7) * cpx + (lin >> 3);
  int stn = nbn >> 3;
  int st = swz >> 6, in_ = swz & 63;
  int stm = st / stn, soff = st - stm * stn;
  int bm = stm * 8 + (in_ & 7);
  int bn = soff * 8 + (in_ >> 3);
  floatx4 acc[4][4] = {};
  int srow = tid >> 2;
  int sk8 = tid & 3;
  const ushort* Ag = A + (size_t)(bm * 128 + srow) * K + sk8 * 8;
  const ushort* Bg = Bt + (size_t)(bn * 128 + srow) * K + sk8 * 8;
  int nks = K >> 5;

#define GSTAGE(bufi, kk0)                                                       \
  {                                                                             \
    __builtin_amdgcn_global_load_lds(                                           \
        (const __attribute__((address_space(1))) void*)(Ag + (kk0)),            \
        (__attribute__((address_space(3))) void*)&lA[bufi][tid * 8], 16, 0, 0); \
    __builtin_amdgcn_global_load_lds(                                           \
        (const __attribute__((address_space(1))) void*)(Ag + (size_t)64 * K + (kk0)), \
        (__attribute__((address_space(3))) void*)&lA[bufi][tid * 8 + 2048], 16, 0, 0); \
    __builtin_amdgcn_global_load_lds(                                           \
        (const __attribute__((address_space(1))) void*)(Bg + (kk0)),            \
        (__attribute__((address_space(3))) void*)&lB[bufi][tid * 8], 16, 0, 0); \
    __builtin_amdgcn_global_load_lds(                                           \
        (const __attribute__((address_space(1))) void*)(Bg + (size_t)64 * K + (kk0)), \
        (__attribute__((address_space(3))) void*)&lB[bufi][tid * 8 + 2048], 16, 0, 0); \
  }

  GSTAGE(0, 0);
  int cur = 0;
  #pragma unroll 1
  for (int ks = 0; ks < nks; ++ks) {
    if (ks + 1 < nks) {
      GSTAGE(cur ^ 1, (ks + 1) * 32);
      asm volatile("s_waitcnt vmcnt(4)" ::: "memory");
    } else {
      asm volatile("s_waitcnt vmcnt(0)" ::: "memory");
    }
    __builtin_amdgcn_s_barrier();       // buf[cur] staged & visible
    __builtin_amdgcn_sched_barrier(0);
    short8 af[4], bf[4];
    #pragma unroll
    for (int i = 0; i < 4; i++) {
      af[i] = *(short8*)&lA[cur][(wm * 64 + i * 16 + m16) * 32 + q4 * 8];
      bf[i] = *(short8*)&lB[cur][(wn * 64 + i * 16 + m16) * 32 + q4 * 8];
    }
    #pragma unroll
    for (int mi = 0; mi < 4; mi++)
      #pragma unroll
      for (int nj = 0; nj < 4; nj++)
        acc[mi][nj] = __builtin_amdgcn_mfma_f32_16x16x32_bf16(af[mi], bf[nj], acc[mi][nj], 0, 0, 0);
    __builtin_amdgcn_s_barrier();       // all waves done reading buf[cur]
    cur ^= 1;
  }
#undef GSTAGE
  float* Cb = C + (size_t)(bm * 128) * N + bn * 128;
  #pragma unroll
  for (int mi = 0; mi < 4; mi++) {
    #pragma unroll
    for (int nj = 0; nj < 4; nj++) {
      #pragma unroll
      for (int i = 0; i < 4; i++) {
        int row = wm * 64 + mi * 16 + q4 * 4 + i;
        int col = wn * 64 + nj * 16 + m16;
        Cb[(size_t)row * N + col] = acc[mi][nj][i];
      }
    }
  }
}

// ---------- beta = sigmoid(x @ Wb), WbT[16][1024], conflict-free ----------
__global__ __launch_bounds__(256) void beta_kernel(const float* __restrict__ x,
                                                   const float* __restrict__ WbT,
                                                   float* __restrict__ beta) {
  __shared__ __align__(16) float xs[D_];
  int row = blockIdx.x;
  int tid = threadIdx.x;
  ((float4*)xs)[tid] = ((const float4*)(x + (size_t)row * D_))[tid];
  __syncthreads();
  int h = tid >> 4;
  int seg = tid & 15;
  const float4* wrow = (const float4*)(WbT + (size_t)h * D_) + seg * 16;
  const float4* xsrow = (const float4*)xs + seg * 16;
  float s = 0.f;
  #pragma unroll
  for (int j = 0; j < 16; j++) {
    int jj = (j + seg) & 15;
    float4 xv = xsrow[jj];
    float4 wv = wrow[jj];
    s += xv.x * wv.x + xv.y * wv.y + xv.z * wv.z + xv.w * wv.w;
  }
  #pragma unroll
  for (int off = 8; off; off >>= 1) s += __shfl_down(s, off, 16);
  if (seg == 0) beta[(size_t)row * H_ + h] = 1.f / (1.f + __expf(-s));
}

// ---------- causal depthwise conv(K=4) + silu, l2norm for q,k ----------
__global__ __launch_bounds__(256) void conv_kernel(
    const float* __restrict__ qkv,
    const float* __restrict__ cq, const float* __restrict__ ck, const float* __restrict__ cv,
    float* __restrict__ qo, float* __restrict__ ko, float* __restrict__ vo) {
  int row = blockIdx.x;
  int t = row & (T_ - 1);
  int tid = threadIdx.x;
  int c0 = tid * 4;
  float4 zf = {0.f, 0.f, 0.f, 0.f};
  float4 xq[4], xk[4], xv[4];
  #pragma unroll
  for (int i = 0; i < 4; i++) {
    int tt = t - 3 + i;
    if (tt >= 0) {
      const float* rp = qkv + (size_t)(row - 3 + i) * QKVN_;
      xq[i] = *(const float4*)(rp + c0);
      xk[i] = *(const float4*)(rp + 1024 + c0);
      xv[i] = *(const float4*)(rp + 2048 + c0);
    } else { xq[i] = zf; xk[i] = zf; xv[i] = zf; }
  }
  float yq[4], yk[4], yv[4];
  float pq = 0.f, pk = 0.f;
  #pragma unroll
  for (int j = 0; j < 4; j++) {
    float4 wq = ((const float4*)cq)[c0 + j];
    float4 wk = ((const float4*)ck)[c0 + j];
    float4 wv = ((const float4*)cv)[c0 + j];
    float sq = 0.f, sk = 0.f, sv = 0.f;
    #pragma unroll
    for (int i = 0; i < 4; i++) {
      sq += f4get(wq, i) * f4get(xq[i], j);
      sk += f4get(wk, i) * f4get(xk[i], j);
      sv += f4get(wv, i) * f4get(xv[i], j);
    }
    yq[j] = siluf(sq); yk[j] = siluf(sk); yv[j] = siluf(sv);
    pq += yq[j] * yq[j]; pk += yk[j] * yk[j];
  }
  #pragma unroll
  for (int off = 1; off < 16; off <<= 1) {
    pq += __shfl_xor(pq, off, 16);
    pk += __shfl_xor(pk, off, 16);
  }
  float rq = rsqrtf(pq + 1e-6f), rk = rsqrtf(pk + 1e-6f);
  float4 oq = {yq[0]*rq, yq[1]*rq, yq[2]*rq, yq[3]*rq};
  float4 okk = {yk[0]*rk, yk[1]*rk, yk[2]*rk, yk[3]*rk};
  float4 ov = {yv[0], yv[1], yv[2], yv[3]};
  *(float4*)(qo + (size_t)row * D_ + c0) = oq;
  *(float4*)(ko + (size_t)row * D_ + c0) = okk;
  *(float4*)(vo + (size_t)row * D_ + c0) = ov;
}

// ================= chunked delta rule =================
// prep1: A = strict_tril(diag(b)KK^T); solve (I+A)Wk = diag(b)K and (I+A)U0 = diag(b)V
// A-phase uses 4x4 register output tiling: per d4 step 8 float4 LDS reads for 64
// FMAs (was 17 reads) -> ~2.1x less LDS-pipe traffic, same per-element f32
// accumulation order. Then blocked forward substitution (R3-verified):
//   Phase A: each wave w inverts its 16x16 diag block T_ww = (I+A_ww)^-1  (parallel)
//   Phase B: wave w precomputes M_wk = A_wk * T_kk for k<w  (off critical path)
//   k-loop (4 steps): wave k publishes residual Y_k once; wave k applies T_kk*Y_k
//   (final output -> global), waves i>k apply Y_i -= M_ik*Y_k, all concurrently.
__global__ __launch_bounds__(256) void prep1_kernel(
    const float* __restrict__ kn, const float* __restrict__ vn,
    const float* __restrict__ beta,
    float* __restrict__ Wkbuf, float* __restrict__ U0buf) {
  __shared__ __align__(16) float Ash[64 * 68];   // A[t][s] row-major, stride 68
  __shared__ float bsh[64];
  // union region: Ksh (during A compute) aliased with Tsh/Msh/Xsh (after)
  __shared__ __align__(16) float uni[5312];
  float (*Ksh)[68] = (float (*)[68])uni;                    // 64x68 = 4352 floats
  float (*Tsh)[16][20] = (float (*)[16][20])uni;            // [4][16][20] = 1280
  float (*Msh)[16][20] = (float (*)[16][20])(uni + 1280);   // [6][16][20] = 1920
  float (*Xsh)[132] = (float (*)[132])(uni + 3200);         // [16][132]  = 2112

  int ch = blockIdx.x;
  int b = ch >> 9, h = (ch >> 5) & 15, c = ch & 31;
  int tid = threadIdx.x;
  int t = tid >> 2, seg = tid & 3;
  int wave = tid >> 6, lane = tid & 63;
  int r = lane >> 2, q = lane & 3;   // r == t&15, q == seg
  const float* krow = kn + ((size_t)(b * T_ + c * 64 + t)) * D_ + h * 64;
  #pragma unroll
  for (int g = 0; g < 4; g++)
    *(float4*)&Ksh[t][ksw(t, seg * 4 + g)] = *(const float4*)&krow[seg * 16 + 4 * g];
  if (tid < 64) bsh[tid] = beta[((size_t)(b * T_ + c * 64 + tid)) * H_ + h];
  __syncthreads();
  // A[t][s] = (t>s) ? b_t * (k_t . k_s) : 0 — 4x4 register tile per thread
  {
    int qt = tid >> 4, qs = tid & 15;   // row quad, col quad
    int swt = qt >> 2, sws = qs >> 2;   // (row>>4) shared by all 4 rows of a quad
    float acc[4][4];
    #pragma unroll
    for (int i = 0; i < 4; i++)
      #pragma unroll
      for (int j = 0; j < 4; j++) acc[i][j] = 0.f;
    for (int d4 = 0; d4 < 16; d4++) {
      float4 kt[4], ks[4];
      #pragma unroll
      for (int i = 0; i < 4; i++) kt[i] = *(float4*)&Ksh[qt * 4 + i][((d4 ^ swt) << 2)];
      #pragma unroll
      for (int j = 0; j < 4; j++) ks[j] = *(float4*)&Ksh[qs * 4 + j][((d4 ^ sws) << 2)];
      #pragma unroll
      for (int i = 0; i < 4; i++)
        #pragma unroll
        for (int j = 0; j < 4; j++)
          acc[i][j] += kt[i].x * ks[j].x + kt[i].y * ks[j].y
                     + kt[i].z * ks[j].z + kt[i].w * ks[j].w;
    }
    #pragma unroll
    for (int i = 0; i < 4; i++) {
      int row = qt * 4 + i;
      float bt = bsh[row];
      float4 a4;
      a4.x = (row > qs * 4 + 0) ? bt * acc[i][0] : 0.f;
      a4.y = (row > qs * 4 + 1) ? bt * acc[i][1] : 0.f;
      a4.z = (row > qs * 4 + 2) ? bt * acc[i][2] : 0.f;
      a4.w = (row > qs * 4 + 3) ? bt * acc[i][3] : 0.f;
      *(float4*)&Ash[row * 68 + qs * 4] = a4;
    }
  }
  // RHS (residual Y) in registers: row t, 16 K-cols + 16 V-cols
  float xk[16], xv[16];
  {
    float bt = bsh[t];
    const float* vrow = vn + ((size_t)(b * T_ + c * 64 + t)) * D_ + h * 64;
    #pragma unroll
    for (int g = 0; g < 4; g++) {
      float4 kv = *(float4*)&Ksh[t][ksw(t, seg * 4 + g)];
      float4 vv = *(const float4*)&vrow[seg * 16 + 4 * g];
      xk[4*g+0] = bt * kv.x; xk[4*g+1] = bt * kv.y; xk[4*g+2] = bt * kv.z; xk[4*g+3] = bt * kv.w;
      xv[4*g+0] = bt * vv.x; xv[4*g+1] = bt * vv.y; xv[4*g+2] = bt * vv.z; xv[4*g+3] = bt * vv.w;
    }
  }
  __syncthreads();   // Ash ready; Ksh dead -> Tsh/Msh/Xsh region live
  // Phase A: wave-parallel 16x16 diagonal-block inverse via fwd substitution on I
  {
    float a[16];
    #pragma unroll
    for (int i = 0; i < 16; i++) a[i] = Ash[(wave * 16 + r) * 68 + wave * 16 + i];
    float4 w4 = {0.f, 0.f, 0.f, 0.f};
    if ((r >> 2) == q) ((float*)&w4)[r & 3] = 1.f;
    #pragma unroll
    for (int i = 0; i < 15; i++) {
      int src = i * 4 + q;
      float4 wi;
      wi.x = __shfl(w4.x, src, 64);
      wi.y = __shfl(w4.y, src, 64);
      wi.z = __shfl(w4.z, src, 64);
      wi.w = __shfl(w4.w, src, 64);
      if (r > i) {
        w4.x -= a[i] * wi.x; w4.y -= a[i] * wi.y;
        w4.z -= a[i] * wi.z; w4.w -= a[i] * wi.w;
      }
    }
    *(float4*)&Tsh[wave][r][q * 4] = w4;
  }
  __syncthreads();   // Tsh visible to all waves
  // Phase B: M_wk = A_wk * T_kk (wave-local write, wave-local read)
  for (int k = 0; k < wave; k++) {
    float4 m4 = {0.f, 0.f, 0.f, 0.f};
    #pragma unroll
    for (int i = 0; i < 16; i++) {
      float aik = Ash[(wave * 16 + r) * 68 + k * 16 + i];
      float4 tk = *(float4*)&Tsh[k][i][q * 4];
      m4.x += aik * tk.x; m4.y += aik * tk.y;
      m4.z += aik * tk.z; m4.w += aik * tk.w;
    }
    int mi = wave * (wave - 1) / 2 + k;
    *(float4*)&Msh[mi][r][q * 4] = m4;
  }
  // Block substitution k-loop
  float* wkout = &Wkbuf[(size_t)ch * 4096 + t * 64];
  float* u0out = &U0buf[(size_t)ch * 4096 + t * 64];
  for (int k = 0; k < 4; k++) {
    if (wave == k) {   // publish residual Y_k
      #pragma unroll
      for (int g = 0; g < 4; g++) {
        float4 k4 = {xk[4*g+0], xk[4*g+1], xk[4*g+2], xk[4*g+3]};
        float4 v4 = {xv[4*g+0], xv[4*g+1], xv[4*g+2], xv[4*g+3]};
        *(float4*)&Xsh[r][seg * 16 + 4 * g] = k4;
        *(float4*)&Xsh[r][64 + seg * 16 + 4 * g] = v4;
      }
    }
    __syncthreads();
    if (wave == k) {
      // X_k = T_kk * Y_k -> final output, straight to global
      float nk[16], nv[16];
      #pragma unroll
      for (int i2 = 0; i2 < 16; i2++) { nk[i2] = 0.f; nv[i2] = 0.f; }
      #pragma unroll
      for (int i = 0; i < 16; i++) {
        float tc = Tsh[k][r][i];
        #pragma unroll
        for (int g = 0; g < 4; g++) {
          float4 yk = *(float4*)&Xsh[i][seg * 16 + 4 * g];
          float4 yv = *(float4*)&Xsh[i][64 + seg * 16 + 4 * g];
          nk[4*g+0] += tc * yk.x; nk[4*g+1] += tc * yk.y;
          nk[4*g+2] += tc * yk.z; nk[4*g+3] += tc * yk.w;
          nv[4*g+0] += tc * yv.x; nv[4*g+1] += tc * yv.y;
          nv[4*g+2] += tc * yv.z; nv[4*g+3] += tc * yv.w;
        }
      }
      #pragma unroll
      for (int g = 0; g < 4; g++) {
        float4 k4 = {nk[4*g+0], nk[4*g+1], nk[4*g+2], nk[4*g+3]};
        float4 v4 = {nv[4*g+0], nv[4*g+1], nv[4*g+2], nv[4*g+3]};
        *(float4*)&wkout[seg * 16 + 4 * g] = k4;
        *(float4*)&u0out[seg * 16 + 4 * g] = v4;
      }
    } else if (wave > k) {
      // Y_i -= M_ik * Y_k   (== A_ik * X_k)
      int mi = wave * (wave - 1) / 2 + k;
      #pragma unroll
      for (int i = 0; i < 16; i++) {
        float mc = Msh[mi][r][i];
        #pragma unroll
        for (int g = 0; g < 4; g++) {
          float4 yk = *(float4*)&Xsh[i][seg * 16 + 4 * g];
          float4 yv = *(float4*)&Xsh[i][64 + seg * 16 + 4 * g];
          xk[4*g+0] -= mc * yk.x; xk[4*g+1] -= mc * yk.y;
          xk[4*g+2] -= mc * yk.z; xk[4*g+3] -= mc * yk.w;
          xv[4*g+0] -= mc * yv.x; xv[4*g+1] -= mc * yv.y;
          xv[4*g+2] -= mc * yv.z; xv[4*g+3] -= mc * yv.w;
        }
      }
    }
    __syncthreads();
  }
}

// prep2ab: fused prep2a+prep2b. Phase 1: L = tril(Q K^T) -> Lsh (LDS, no HBM
// roundtrip), with 4x4 register output tiling (8 float4 reads / 64 FMAs per d4).
// Phase 2: reuse Qsh/Ksh LDS space for Wk/U0 staging, then
// O0 = L U0 ; Qeff = Q - L Wk (identical arithmetic order to the old kernels).
__global__ __launch_bounds__(256) void prep2ab_kernel(
    float* qn, const float* __restrict__ kn,
    const float* __restrict__ Wkbuf, const float* __restrict__ U0buf,
    float* __restrict__ O0buf) {
  __shared__ float Qsh[64][68];   // phase 2: Wksh
  __shared__ float Ksh[64][68];   // swizzled; phase 2: U0sh
  __shared__ float Lsh[64][68];
  float (*Wksh)[68] = Qsh;
  float (*U0sh)[68] = Ksh;
  int ch = blockIdx.x;
  int b = ch >> 9, h = (ch >> 5) & 15, c = ch & 31;
  int tid = threadIdx.x;
  int t = tid >> 2, seg = tid & 3;
  const float* qrow = qn + ((size_t)(b * T_ + c * 64 + t)) * D_ + h * 64;
  const float* krow = kn + ((size_t)(b * T_ + c * 64 + t)) * D_ + h * 64;
  #pragma unroll
  for (int g = 0; g < 4; g++) {
    *(float4*)&Qsh[t][seg * 16 + 4 * g] = *(const float4*)&qrow[seg * 16 + 4 * g];
    *(float4*)&Ksh[t][ksw(t, seg * 4 + g)] = *(const float4*)&krow[seg * 16 + 4 * g];
  }
  __syncthreads();
  // phase 1: L = tril(Q K^T) -> Lsh, 4x4 register tile per thread
  {
    int qt = tid >> 4, qs = tid & 15;
    int sws = qs >> 2;
    float acc[4][4];
    #pragma unroll
    for (int i = 0; i < 4; i++)
      #pragma unroll
      for (int j = 0; j < 4; j++) acc[i][j] = 0.f;
    for (int d4 = 0; d4 < 16; d4++) {
      float4 qv[4], ks[4];
      #pragma unroll
      for (int i = 0; i < 4; i++) qv[i] = *(float4*)&Qsh[qt * 4 + i][d4 * 4];
      #pragma unroll
      for (int j = 0; j < 4; j++) ks[j] = *(float4*)&Ksh[qs * 4 + j][((d4 ^ sws) << 2)];
      #pragma unroll
      for (int i = 0; i < 4; i++)
        #pragma unroll
        for (int j = 0; j < 4; j++)
          acc[i][j] += qv[i].x * ks[j].x + qv[i].y * ks[j].y
                     + qv[i].z * ks[j].z + qv[i].w * ks[j].w;
    }
    #pragma unroll
    for (int i = 0; i < 4; i++) {
      int row = qt * 4 + i;
      float4 ov;
      ov.x = (qs * 4 + 0 <= row) ? acc[i][0] : 0.f;
      ov.y = (qs * 4 + 1 <= row) ? acc[i][1] : 0.f;
      ov.z = (qs * 4 + 2 <= row) ? acc[i][2] : 0.f;
      ov.w = (qs * 4 + 3 <= row) ? acc[i][3] : 0.f;
      *(float4*)&Lsh[row][qs * 4] = ov;
    }
  }
  __syncthreads();   // L done; Qsh/Ksh dead -> stage Wk/U0 into their space
  #pragma unroll
  for (int g = 0; g < 4; g++) {
    int o = t * 64 + seg * 16 + 4 * g;
    *(float4*)&Wksh[t][seg * 16 + 4 * g] = *(const float4*)&Wkbuf[(size_t)ch * 4096 + o];
    *(float4*)&U0sh[t][seg * 16 + 4 * g] = *(const float4*)&U0buf[(size_t)ch * 4096 + o];
  }
  __syncthreads();
  // phase 2: O0 = L U0 ; Qeff = Q - L Wk (identical to old prep2b)
  int j0 = seg * 16;
  float o0[16], lw[16];
  #pragma unroll
  for (int r = 0; r < 16; r++) { o0[r] = 0.f; lw[r] = 0.f; }
  for (int s = 0; s <= t; s++) {
    float l = Lsh[t][s];
    #pragma unroll
    for (int g = 0; g < 4; g++) {
      float4 u = *(float4*)&U0sh[s][j0 + 4 * g];
      float4 w = *(float4*)&Wksh[s][j0 + 4 * g];
      o0[4*g+0] += l * u.x; o0[4*g+1] += l * u.y; o0[4*g+2] += l * u.z; o0[4*g+3] += l * u.w;
      lw[4*g+0] += l * w.x; lw[4*g+1] += l * w.y; lw[4*g+2] += l * w.z; lw[4*g+3] += l * w.w;
    }
  }
  float* qwrow = qn + ((size_t)(b * T_ + c * 64 + t)) * D_ + h * 64;
  #pragma unroll
  for (int g = 0; g < 4; g++) {
    float4 qv = *(const float4*)&qwrow[j0 + 4 * g];
    qv.x -= lw[4*g+0]; qv.y -= lw[4*g+1]; qv.z -= lw[4*g+2]; qv.w -= lw[4*g+3];
    *(float4*)&qwrow[j0 + 4 * g] = qv;
    float4 ov = {o0[4*g+0], o0[4*g+1], o0[4*g+2], o0[4*g+3]};
    *(float4*)&O0buf[(size_t)ch * 4096 + t * 64 + j0 + 4 * g] = ov;
  }
}

// prep2c: P[d][e] = I - (K^T Wk)[d][e], stored SLOT-MAJOR for state_kernel:
//         float4 #(f*64+d) of chunk = P[d][4f..4f+3]  (so a wave reading slot f,
//         all rows d, is one contiguous 1KB block).
//         Zt[j][d] = (U0^T K)[j][d] -> kn rows j (coalesced), unchanged.
__global__ __launch_bounds__(256) void prep2c_kernel(
    float* kn, const float* __restrict__ Wkbuf,
    const float* __restrict__ U0buf, float* __restrict__ Pbuf) {
  __shared__ float Ksh[64][68];
  __shared__ float Wksh[64][68];
  __shared__ float U0sh[64][68];
  int ch = blockIdx.x;
  int b = ch >> 9, h = (ch >> 5) & 15, c = ch & 31;
  int tid = threadIdx.x;
  int t = tid >> 2, seg = tid & 3;   // t = output row (d for P, j for Zt)
  const float* krow = kn + ((size_t)(b * T_ + c * 64 + t)) * D_ + h * 64;
  #pragma unroll
  for (int g = 0; g < 4; g++) {
    int o = t * 64 + seg * 16 + 4 * g;
    *(float4*)&Ksh[t][seg * 16 + 4 * g]  = *(const float4*)&krow[seg * 16 + 4 * g];
    *(float4*)&Wksh[t][seg * 16 + 4 * g] = *(const float4*)&Wkbuf[(size_t)ch * 4096 + o];
    *(float4*)&U0sh[t][seg * 16 + 4 * g] = *(const float4*)&U0buf[(size_t)ch * 4096 + o];
  }
  __syncthreads();
  int d0 = seg * 16;
  float accP[16], accZ[16];
  #pragma unroll
  for (int r = 0; r < 16; r++) { accP[r] = 0.f; accZ[r] = 0.f; }
  for (int s = 0; s < 64; s++) {
    float kt = Ksh[s][t];    // scalar for P row d=t
    float u  = U0sh[s][t];   // scalar for Z row j=t
    #pragma unroll
    for (int g = 0; g < 4; g++) {
      float4 w4 = *(float4*)&Wksh[s][d0 + 4 * g];
      float4 k4 = *(float4*)&Ksh[s][d0 + 4 * g];
      accP[4*g+0] += kt * w4.x; accP[4*g+1] += kt * w4.y; accP[4*g+2] += kt * w4.z; accP[4*g+3] += kt * w4.w;
      accZ[4*g+0] += u * k4.x;  accZ[4*g+1] += u * k4.y;  accZ[4*g+2] += u * k4.z;  accZ[4*g+3] += u * k4.w;
    }
  }
  float* zrow = kn + ((size_t)(b * T_ + c * 64 + t)) * D_ + h * 64;
  #pragma unroll
  for (int g = 0; g < 4; g++) {
    float4 pv;
    pv.x = ((d0 + 4*g + 0) == t ? 1.f : 0.f) - accP[4*g+0];
    pv.y = ((d0 + 4*g + 1) == t ? 1.f : 0.f) - accP[4*g+1];
    pv.z = ((d0 + 4*g + 2) == t ? 1.f : 0.f) - accP[4*g+2];
    pv.w = ((d0 + 4*g + 3) == t ? 1.f : 0.f) - accP[4*g+3];
    // slot-major: slot f = seg*4+g, row d = t
    *(float4*)&Pbuf[(size_t)ch * 4096 + (size_t)(seg * 4 + g) * 256 + (size_t)t * 4] = pv;
    float4 zv = {accZ[4*g+0], accZ[4*g+1], accZ[4*g+2], accZ[4*g+3]};
    *(float4*)&zrow[d0 + 4 * g] = zv;
  }
}

// ---------- state scan: S_{c+1} = P_c S_c + Z_c; Sbuf transposed [ch][j][d] ----------
// 512 blocks = (bh, js), 256 threads = 4 waves; wave wv owns single column
// j0 = js*4 + wv; lane = d holds S[j0][d]. P_c staged ONCE per block into LDS
// (slot-major -> conflict-free contiguous b128 reads), double-buffered; the 4
// waves share it -> same L2 traffic as the 1-wave version but 2048 waves total
// (2 waves/SIMD) so ds_read/barrier stalls overlap across waves. One
// __syncthreads per chunk (its implicit vmcnt drain covers staging visibility).
// bh = bid&31 so the 16 block-sharers of a (b,h) land on the same XCD.
__global__ __launch_bounds__(256) void state_kernel(
    const float* __restrict__ kn /*Zt*/, const float* __restrict__ Pbuf /*slot-major*/,
    float* __restrict__ Sbuf) {
  __shared__ __align__(16) float Pl[2][4096];
  int bid = blockIdx.x;
  int bh = bid & 31, js = bid >> 5;
  int h = bh & 15, b = bh >> 4;
  int tid = threadIdx.x;
  int wv = tid >> 6, lane = tid & 63;   // lane = d
  int j0 = js * 4 + wv;                 // this wave's column
  float s0 = 0.f;
  const size_t bhNC = (size_t)bh * NC_;
  // prologue: stage P_0 into buf0 (256 threads x 16B x 4 passes = 16KB), load Z_0
  const float* Pg0 = Pbuf + bhNC * 4096;
  #pragma unroll
  for (int g = 0; g < 4; g++)
    __builtin_amdgcn_global_load_lds(
        (const __attribute__((address_space(1))) void*)(Pg0 + (g * 256 + tid) * 4),
        (__attribute__((address_space(3))) void*)&Pl[0][(g * 256 + tid) * 4], 16, 0, 0);
  float zn = kn[((size_t)(b * T_ + j0)) * D_ + h * 64 + lane];
  int cur = 0;
  #pragma unroll 1
  for (int c = 0; c < NC_; c++) {
    __syncthreads();            // implies vmcnt(0) drain: buf[cur] ready for all waves
    float z = zn;
    size_t ch = bhNC + c;
    // issue next-chunk staging into the other buffer + Z prefetch
    if (c + 1 < NC_) {
      const float* Pg = Pbuf + (ch + 1) * 4096;
      #pragma unroll
      for (int g = 0; g < 4; g++)
        __builtin_amdgcn_global_load_lds(
            (const __attribute__((address_space(1))) void*)(Pg + (g * 256 + tid) * 4),
            (__attribute__((address_space(3))) void*)&Pl[cur ^ 1][(g * 256 + tid) * 4], 16, 0, 0);
      zn = kn[((size_t)(b * T_ + (c + 1) * 64 + j0)) * D_ + h * 64 + lane];
    }
    // store S_c (pre-update), coalesced 256B per wave
    Sbuf[ch * 4096 + (size_t)j0 * 64 + lane] = s0;
    // S_{c+1}[j0][d=lane] = Z[j0][d] + sum_e P[d][e] * S_c[j0][e]
    float acc = z;
    #pragma unroll
    for (int f = 0; f < 16; f++) {
      floatx4 pv = *(floatx4*)&Pl[cur][f * 256 + lane * 4];
      acc += pv.x * rdlane(s0, f * 4 + 0);
      acc += pv.y * rdlane(s0, f * 4 + 1);
      acc += pv.z * rdlane(s0, f * 4 + 2);
      acc += pv.w * rdlane(s0, f * 4 + 3);
    }
    s0 = acc;
    cur ^= 1;
  }
}

// ---------- O = O0 + Qeff*S_c (S transposed layout), fused RMSNorm + bf16 cast ----------
__global__ __launch_bounds__(256) void ophase_kernel(
    const float* __restrict__ qn /*Qeff*/, const float* __restrict__ Sbuf,
    const float* __restrict__ O0buf, const float* __restrict__ rms_g,
    ushort* __restrict__ ob) {
  __shared__ float Ssht[64][68];
  __shared__ float QshT[64][65];
  __shared__ float part[64][4];
  int ch = blockIdx.x;
  int b = ch >> 9, h = (ch >> 5) & 15, c = ch & 31;
  int tid = threadIdx.x;
  int t = tid & 63, jg = tid >> 6;
  #pragma unroll
  for (int g = 0; g < 4; g++) {
    int idx = tid + g * 256;
    *(float4*)&Ssht[idx >> 4][(idx & 15) * 4] =
        *(const float4*)&Sbuf[(size_t)ch * 4096 + (size_t)idx * 4];
  }
  #pragma unroll
  for (int g = 0; g < 4; g++) {
    int idx = tid + g * 256;
    int row = idx >> 4, c4 = idx & 15;
    float4 qv = *(const float4*)&qn[((size_t)(b * T_ + c * 64 + row)) * D_ + h * 64 + c4 * 4];
    QshT[c4 * 4 + 0][row] = qv.x;
    QshT[c4 * 4 + 1][row] = qv.y;
    QshT[c4 * 4 + 2][row] = qv.z;
    QshT[c4 * 4 + 3][row] = qv.w;
  }
  float o[16];
  #pragma unroll
  for (int g = 0; g < 4; g++) {
    float4 o4 = *(const float4*)&O0buf[(size_t)ch * 4096 + t * 64 + jg * 16 + g * 4];
    o[4*g+0] = o4.x; o[4*g+1] = o4.y; o[4*g+2] = o4.z; o[4*g+3] = o4.w;
  }
  __syncthreads();
  for (int d4 = 0; d4 < 16; d4++) {
    float q0 = QshT[d4 * 4 + 0][t];
    float q1 = QshT[d4 * 4 + 1][t];
    float q2 = QshT[d4 * 4 + 2][t];
    float q3 = QshT[d4 * 4 + 3][t];
    #pragma unroll
    for (int r = 0; r < 16; r++) {
      float4 s4 = *(float4*)&Ssht[jg * 16 + r][d4 * 4];
      o[r] += q0 * s4.x + q1 * s4.y + q2 * s4.z + q3 * s4.w;
    }
  }
  float ss = 0.f;
  #pragma unroll
  for (int r = 0; r < 16; r++) ss += o[r] * o[r];
  part[t][jg] = ss;
  __syncthreads();
  float tot = part[t][0] + part[t][1] + part[t][2] + part[t][3];
  float sc = rsqrtf(tot * (1.f / 64.f) + 1e-6f);
  ushort* orow = &ob[((size_t)(b * T_ + c * 64 + t)) * D_ + h * 64];
  #pragma unroll
  for (int g = 0; g < 4; g++) {
    float4 g4 = *(const float4*)&rms_g[jg * 16 + g * 4];
    ushort4 r4;
    r4.x = f2bf(o[4*g+0] * sc * g4.x); r4.y = f2bf(o[4*g+1] * sc * g4.y);
    r4.z = f2bf(o[4*g+2] * sc * g4.z); r4.w = f2bf(o[4*g+3] * sc * g4.w);
    *(ushort4*)&orow[jg * 16 + g * 4] = r4;
  }
}

extern "C" void kernel_launch(void* const* d_in, const int* in_sizes, int n_in,
                              void* d_out, int out_size, void* d_ws, size_t ws_size,
                              hipStream_t stream) {
  const float* x  = (const float*)d_in[0];
  const float* Wq = (const float*)d_in[1];
  const float* Wk = (const float*)d_in[2];
  const float* Wv = (const float*)d_in[3];
  const float* Wb = (const float*)d_in[4];
  const float* cq = (const float*)d_in[5];
  const float* ck = (const float*)d_in[6];
  const float* cv = (const float*)d_in[7];
  const float* rg = (const float*)d_in[8];
  const float* Wo = (const float*)d_in[9];
  float* out = (float*)d_out;
  char* ws = (char*)d_ws;
  const size_t MiB = 1ull << 20;
  ushort* xb   = (ushort*)(ws + 0);         // dead after QKV gemm
  ushort* Wqt  = (ushort*)(ws + 8 * MiB);   // Wqt/Wkt/Wvt contiguous = [3072][1024] bf16
  ushort* Wkt  = (ushort*)(ws + 10 * MiB);
  ushort* Wvt  = (ushort*)(ws + 12 * MiB);
  ushort* Wot  = (ushort*)(ws + 14 * MiB);  // live to end
  float* qkv   = (float*)(ws + 16 * MiB);   // [4096][3072] fp32, dead after conv
  float* qn    = (float*)(ws + 64 * MiB);   // then Qeff in-place
  float* kn    = (float*)(ws + 80 * MiB);   // then Zt in-place
  float* vn    = (float*)(ws + 96 * MiB);   // dead after prep1
  float* beta  = (float*)(ws + 112 * MiB);  // 256 KiB
  float* WbT   = (float*)(ws + 112 * MiB + 256 * 1024);  // 64 KiB
  float* Wkbuf = (float*)(ws + 16 * MiB);   // over qkv (dead after conv)
  float* U0buf = (float*)(ws + 32 * MiB);
  float* Pbuf  = (float*)(ws + 48 * MiB);   // P (prep2c out, state in)
  float* O0buf = (float*)(ws + 96 * MiB);   // over vn (after prep1)
  float* Sbuf  = (float*)(ws + 16 * MiB);   // over Wkbuf (dead after prep2c)
  ushort* ob   = (ushort*)(ws + 0);         // over xb (after QKV gemm)

  hipLaunchKernelGGL(cast_kernel, dim3(M_ * D_ / 4 / 256), dim3(256), 0, stream,
                     x, xb, M_ * D_ / 4);
  dim3 tb(32, 8);
  hipLaunchKernelGGL(transpose_cast_kernel, dim3(32, 32), tb, 0, stream, Wq, Wqt, D_, D_);
  hipLaunchKernelGGL(transpose_cast_kernel, dim3(32, 32), tb, 0, stream, Wk, Wkt, D_, D_);
  hipLaunchKernelGGL(transpose_cast_kernel, dim3(32, 32), tb, 0, stream, Wv, Wvt, D_, D_);
  hipLaunchKernelGGL(transpose_cast_kernel, dim3(32, 32), tb, 0, stream, Wo, Wot, D_, D_);
  hipLaunchKernelGGL(transpose_wb_kernel, dim3(64), dim3(256), 0, stream, Wb, WbT);

  hipLaunchKernelGGL(gemm128_kernel, dim3(M_ / 128, QKVN_ / 128), dim3(256), 0, stream,
                     xb, Wqt, qkv, M_, QKVN_, D_);

  hipLaunchKernelGGL(beta_kernel, dim3(M_), dim3(256), 0, stream, x, WbT, beta);
  hipLaunchKernelGGL(conv_kernel, dim3(M_), dim3(256), 0, stream,
                     qkv, cq, ck, cv, qn, kn, vn);

  hipLaunchKernelGGL(prep1_kernel, dim3(NCH_), dim3(256), 0, stream,
                     kn, vn, beta, Wkbuf, U0buf);
  hipLaunchKernelGGL(prep2ab_kernel, dim3(NCH_), dim3(256), 0, stream,
                     qn, kn, Wkbuf, U0buf, O0buf);
  hipLaunchKernelGGL(prep2c_kernel, dim3(NCH_), dim3(256), 0, stream,
                     kn, Wkbuf, U0buf, Pbuf);
  hipLaunchKernelGGL(state_kernel, dim3(512), dim3(256), 0, stream,
                     kn, Pbuf, Sbuf);
  hipLaunchKernelGGL(ophase_kernel, dim3(NCH_), dim3(256), 0, stream,
                     qn, Sbuf, O0buf, rg, ob);
  hipLaunchKernelGGL(gemm128_kernel, dim3(M_ / 128, D_ / 128), dim3(256), 0, stream,
                     ob, Wot, out, M_, D_, D_);
}